// Round 12
// baseline (334.005 us; speedup 1.0000x reference)
//
#include <hip/hip_runtime.h>
#include <hip/hip_bf16.h>
#include <math.h>

#define N_NODES 50000
#define N_EDGES 800000
#define E_TOT   (N_EDGES + N_NODES)   // 850000 (with self-loops)
#define IN_CH 128
#define HID 32
#define HEADS 8
#define OUT_CH 64
#define NEG_SLOPE 0.2f
#define NBLK 196                      // ceil(50000/256)
#define M_BLK 64
#define GBLK 782                      // ceil(50000/64)
#define ABLK 12500                    // 50000/4 nodes per 256-thread block
#define LOG2E 1.4426950408889634f

__device__ __forceinline__ float lrelu(float x) { return x > 0.f ? x : NEG_SLOPE * x; }
// exp(lrelu(z)) = exp2(max(z*L, z*0.2L))  (branchless; valid since L>0)
__device__ __forceinline__ float explrelu(float z) {
    return exp2f(fmaxf(z * LOG2E, z * (NEG_SLOPE * LOG2E)));
}

__device__ __forceinline__ unsigned short f2bf(float f) {
    unsigned int u = __float_as_uint(f);
    unsigned int r = (u + 0x7FFFu + ((u >> 16) & 1u)) >> 16;   // round-nearest-even
    return (unsigned short)r;
}
__device__ __forceinline__ float bf2f(unsigned short u) {
    return __uint_as_float(((unsigned int)u) << 16);
}
__device__ __forceinline__ float bflo(unsigned int u) {       // low ushort -> float
    return __uint_as_float(u << 16);
}
__device__ __forceinline__ float bfhi(unsigned int u) {       // high ushort -> float
    return __uint_as_float(u & 0xFFFF0000u);
}

// ---------------- CSR build ----------------
__global__ void hist_kernel(const int* __restrict__ ei, int* __restrict__ deg) {
    int e = blockIdx.x * blockDim.x + threadIdx.x;
    if (e >= E_TOT) return;
    int d = (e < N_EDGES) ? ei[N_EDGES + e] : (e - N_EDGES);
    atomicAdd(&deg[d], 1);
}

__global__ void scan1_kernel(const int* __restrict__ deg, int* __restrict__ off,
                             int* __restrict__ bsum) {
    __shared__ int s[256];
    int b = blockIdx.x, t = threadIdx.x, g = b * 256 + t;
    int v = (g < N_NODES) ? deg[g] : 0;
    s[t] = v;
    __syncthreads();
    for (int d = 1; d < 256; d <<= 1) {
        int o = (t >= d) ? s[t - d] : 0;
        __syncthreads();
        s[t] += o;
        __syncthreads();
    }
    if (g < N_NODES) off[g] = s[t] - v;
    if (t == 255) bsum[b] = s[t];
}

__global__ void scan2_kernel(int* __restrict__ bsum, int nb) {
    __shared__ int s[256];
    int t = threadIdx.x;
    int v = (t < nb) ? bsum[t] : 0;
    s[t] = v;
    __syncthreads();
    for (int d = 1; d < 256; d <<= 1) {
        int o = (t >= d) ? s[t - d] : 0;
        __syncthreads();
        s[t] += o;
        __syncthreads();
    }
    if (t < nb) bsum[t] = s[t] - v;
}

__global__ void scan3_kernel(int* __restrict__ off, const int* __restrict__ bsum,
                             int* __restrict__ cur) {
    int b = blockIdx.x, t = threadIdx.x, g = b * 256 + t;
    if (g < N_NODES) {
        int v = off[g] + bsum[b];
        off[g] = v;
        cur[g] = v;
    }
    if (g == 0) off[N_NODES] = E_TOT;
}

__global__ void scatter_kernel(const int* __restrict__ ei, int* __restrict__ cur,
                               int* __restrict__ ssrc) {
    int e = blockIdx.x * blockDim.x + threadIdx.x;
    if (e >= E_TOT) return;
    int s, d;
    if (e < N_EDGES) { s = ei[e]; d = ei[N_EDGES + e]; }
    else             { s = d = e - N_EDGES; }
    int pos = atomicAdd(&cur[d], 1);
    ssrc[pos] = s;
}

// ---------------- GEMM1 (tiled, 64x256 tile) + alpha epilogue, bf16 h1 out ---
#define FMA4(accv, av, bv)                                                     \
    accv.x = fmaf(av, bv.x, accv.x); accv.y = fmaf(av, bv.y, accv.y);          \
    accv.z = fmaf(av, bv.z, accv.z); accv.w = fmaf(av, bv.w, accv.w);

__global__ __launch_bounds__(256) void gemm1_tiled(
    const float* __restrict__ x, const float* __restrict__ W1,
    const float* __restrict__ att_s, const float* __restrict__ att_d,
    unsigned short* __restrict__ h1b, float* __restrict__ as1, float* __restrict__ ad1) {
    __shared__ float As[M_BLK][IN_CH];   // 32 KB
    int t = threadIdx.x;
    int row0 = blockIdx.x * M_BLK;
#pragma unroll
    for (int i = 0; i < 8; ++i) {
        int f = t + i * 256;
        int r = f >> 5, c4 = (f & 31) * 4;
        int gr = row0 + r; if (gr >= N_NODES) gr = N_NODES - 1;
        *(float4*)&As[r][c4] = *(const float4*)&x[(size_t)gr * IN_CH + c4];
    }
    __syncthreads();
    int col0 = (t & 63) * 4;
    int rbase = (t >> 6) * 16;
    float4 acc[16];
#pragma unroll
    for (int m = 0; m < 16; ++m) acc[m] = make_float4(0.f, 0.f, 0.f, 0.f);

    for (int k = 0; k < IN_CH; k += 4) {
        float4 b0 = *(const float4*)&W1[(k + 0) * 256 + col0];
        float4 b1 = *(const float4*)&W1[(k + 1) * 256 + col0];
        float4 b2 = *(const float4*)&W1[(k + 2) * 256 + col0];
        float4 b3 = *(const float4*)&W1[(k + 3) * 256 + col0];
#pragma unroll
        for (int m = 0; m < 16; ++m) {
            float4 a = *(const float4*)&As[rbase + m][k];
            FMA4(acc[m], a.x, b0);
            FMA4(acc[m], a.y, b1);
            FMA4(acc[m], a.z, b2);
            FMA4(acc[m], a.w, b3);
        }
    }

    float4 s4 = *(const float4*)&att_s[col0];
    float4 d4 = *(const float4*)&att_d[col0];
    int head = col0 >> 5;
#pragma unroll
    for (int m = 0; m < 16; ++m) {
        int gr = row0 + rbase + m;
        if (gr < N_NODES) {
            ushort4 hb;
            hb.x = f2bf(acc[m].x); hb.y = f2bf(acc[m].y);
            hb.z = f2bf(acc[m].z); hb.w = f2bf(acc[m].w);
            *(ushort4*)&h1b[(size_t)gr * 256 + col0] = hb;
            float p = acc[m].x * s4.x + acc[m].y * s4.y + acc[m].z * s4.z + acc[m].w * s4.w;
            float q = acc[m].x * d4.x + acc[m].y * d4.y + acc[m].z * d4.z + acc[m].w * d4.w;
            p += __shfl_xor(p, 1); p += __shfl_xor(p, 2); p += __shfl_xor(p, 4);
            q += __shfl_xor(q, 1); q += __shfl_xor(q, 2); q += __shfl_xor(q, 4);
            if ((t & 7) == 0) {
                as1[gr * HEADS + head] = p;
                ad1[gr * HEADS + head] = q;
            }
        }
    }
}

// ---------------- Aggregate layer 1: 1 wave/node, masked 8-edge batches -----
// lane l: channels [l*4,l*4+4), head h = l>>3.
// Every batch (incl. the last partial one) computes all 64 (edge,head)
// weights with one as1 gather + one exp chain; a wave-uniform break skips
// invalid edges of the final batch. No serial per-edge tail.
__global__ __launch_bounds__(256) void agg1_kernel(
    const int* __restrict__ off, const int* __restrict__ ssrc,
    const unsigned short* __restrict__ h1b, const float* __restrict__ as1,
    const float* __restrict__ ad1, const float* __restrict__ b1,
    unsigned short* __restrict__ houtb) {
    int t = threadIdx.x;
    int lane = t & 63;
    int n = blockIdx.x * 4 + (t >> 6);
    int h = lane >> 3;
    int e8 = lane & 7;
    int c0 = lane * 4;
    int start = off[n], end = off[n + 1];
    float ad_w = ad1[n * HEADS + e8];
    float4 acc = make_float4(0.f, 0.f, 0.f, 0.f);
    float den = 0.f;
    int last = end - 1;
    for (int i = start; i < end; i += 8) {
        int cnt = end - i; if (cnt > 8) cnt = 8;          // wave-uniform
        int sv = ssrc[min(i + e8, last)];                 // clamped, always valid
        int se = __shfl(sv, h);
        float z = as1[se * HEADS + e8] + ad_w;
        float wv = explrelu(z);                           // 64 weights, one chain
#pragma unroll
        for (int j = 0; j < 8; ++j) {
            if (j >= cnt) break;                          // wave-uniform break
            float wj = __shfl(wv, j * 8 + h);
            int   sj = __shfl(sv, j);
            uint2 u = *(const uint2*)&h1b[(unsigned)sj * 256 + c0];
            den += wj;
            acc.x = fmaf(wj, bflo(u.x), acc.x);
            acc.y = fmaf(wj, bfhi(u.x), acc.y);
            acc.z = fmaf(wj, bflo(u.y), acc.z);
            acc.w = fmaf(wj, bfhi(u.y), acc.w);
        }
    }
    float r = __builtin_amdgcn_rcpf(den);
    float4 bv = *(const float4*)&b1[c0];
    float vx = fmaf(acc.x, r, bv.x);
    float vy = fmaf(acc.y, r, bv.y);
    float vz = fmaf(acc.z, r, bv.z);
    float vw = fmaf(acc.w, r, bv.w);
    vx = vx > 0.f ? vx : expm1f(vx);
    vy = vy > 0.f ? vy : expm1f(vy);
    vz = vz > 0.f ? vz : expm1f(vz);
    vw = vw > 0.f ? vw : expm1f(vw);
    ushort4 ob;
    ob.x = f2bf(vx); ob.y = f2bf(vy); ob.z = f2bf(vz); ob.w = f2bf(vw);
    *(ushort4*)&houtb[(unsigned)n * 256 + c0] = ob;
}

// ---------------- GEMM2 (tiled, 64x64 tile, bf16 in, 4x4 blocking) ----------
__global__ __launch_bounds__(256) void gemm2_tiled(
    const unsigned short* __restrict__ hinb, const float* __restrict__ W2,
    const float* __restrict__ att_s2, const float* __restrict__ att_d2,
    unsigned short* __restrict__ h2b, float* __restrict__ as2, float* __restrict__ ad2) {
    __shared__ float As[M_BLK][256];   // 64 KB
    int t = threadIdx.x;
    int row0 = blockIdx.x * M_BLK;
#pragma unroll
    for (int i = 0; i < 16; ++i) {
        int f = t + i * 256;
        int r = f >> 6, c4 = (f & 63) * 4;
        int gr = row0 + r; if (gr >= N_NODES) gr = N_NODES - 1;
        ushort4 u = *(const ushort4*)&hinb[(size_t)gr * 256 + c4];
        float4 v = make_float4(bf2f(u.x), bf2f(u.y), bf2f(u.z), bf2f(u.w));
        *(float4*)&As[r][c4] = v;
    }
    __syncthreads();
    int col0 = (t & 15) * 4;
    int rbase = (t >> 4) * 4;
    float4 acc[4];
#pragma unroll
    for (int m = 0; m < 4; ++m) acc[m] = make_float4(0.f, 0.f, 0.f, 0.f);

    for (int k = 0; k < 256; k += 4) {
        float4 b0 = *(const float4*)&W2[(k + 0) * 64 + col0];
        float4 b1 = *(const float4*)&W2[(k + 1) * 64 + col0];
        float4 b2 = *(const float4*)&W2[(k + 2) * 64 + col0];
        float4 b3 = *(const float4*)&W2[(k + 3) * 64 + col0];
#pragma unroll
        for (int m = 0; m < 4; ++m) {
            float4 a = *(const float4*)&As[rbase + m][k];
            FMA4(acc[m], a.x, b0);
            FMA4(acc[m], a.y, b1);
            FMA4(acc[m], a.z, b2);
            FMA4(acc[m], a.w, b3);
        }
    }

    float4 s4 = *(const float4*)&att_s2[col0];
    float4 d4 = *(const float4*)&att_d2[col0];
#pragma unroll
    for (int m = 0; m < 4; ++m) {
        int gr = row0 + rbase + m;
        if (gr < N_NODES) {
            ushort4 hb;
            hb.x = f2bf(acc[m].x); hb.y = f2bf(acc[m].y);
            hb.z = f2bf(acc[m].z); hb.w = f2bf(acc[m].w);
            *(ushort4*)&h2b[(size_t)gr * 64 + col0] = hb;
            float p = acc[m].x * s4.x + acc[m].y * s4.y + acc[m].z * s4.z + acc[m].w * s4.w;
            float q = acc[m].x * d4.x + acc[m].y * d4.y + acc[m].z * d4.z + acc[m].w * d4.w;
            p += __shfl_xor(p, 1); q += __shfl_xor(q, 1);
            p += __shfl_xor(p, 2); q += __shfl_xor(q, 2);
            p += __shfl_xor(p, 4); q += __shfl_xor(q, 4);
            p += __shfl_xor(p, 8); q += __shfl_xor(q, 8);
            if ((t & 15) == 0) { as2[gr] = p; ad2[gr] = q; }
        }
    }
}

// ---------------- Aggregate layer 2: 1 wave/node, masked 8-edge batches -----
__global__ __launch_bounds__(256) void agg2_kernel(
    const int* __restrict__ off, const int* __restrict__ ssrc,
    const unsigned short* __restrict__ h2b, const float* __restrict__ as2,
    const float* __restrict__ ad2, const float* __restrict__ b2,
    float* __restrict__ out) {
    int t = threadIdx.x;
    int lane = t & 63;
    int e8 = lane & 7;
    int n = blockIdx.x * 4 + (t >> 6);
    int start = off[n], end = off[n + 1];
    float adv = ad2[n];
    float acc = 0.f, den = 0.f;
    int last = end - 1;
    for (int i = start; i < end; i += 8) {
        int cnt = end - i; if (cnt > 8) cnt = 8;
        int sv = ssrc[min(i + e8, last)];
        float wv = explrelu(as2[sv] + adv);
#pragma unroll
        for (int j = 0; j < 8; ++j) {
            if (j >= cnt) break;                          // wave-uniform break
            float wj = __shfl(wv, j);
            int   sj = __shfl(sv, j);
            float v = bf2f(h2b[(unsigned)sj * 64 + lane]);
            den += wj;
            acc = fmaf(wj, v, acc);
        }
    }
    float r = __builtin_amdgcn_rcpf(den);
    out[(unsigned)n * 64 + lane] = fmaf(acc, r, b2[lane]);
}

extern "C" void kernel_launch(void* const* d_in, const int* in_sizes, int n_in,
                              void* d_out, int out_size, void* d_ws, size_t ws_size,
                              hipStream_t stream) {
    const float* x    = (const float*)d_in[0];
    const int*   ei   = (const int*)d_in[1];
    const float* W1   = (const float*)d_in[2];
    const float* ats1 = (const float*)d_in[3];
    const float* atd1 = (const float*)d_in[4];
    const float* b1   = (const float*)d_in[5];
    const float* W2   = (const float*)d_in[6];
    const float* ats2 = (const float*)d_in[7];
    const float* atd2 = (const float*)d_in[8];
    const float* b2   = (const float*)d_in[9];
    float* out = (float*)d_out;

    char* ws = (char*)d_ws;
    size_t o = 0;
    auto alloc = [&](size_t bytes) { size_t r = o; o = (o + bytes + 255) & ~255UL; return r; };
    unsigned short* h1b   = (unsigned short*)(ws + alloc((size_t)N_NODES * 256 * 2));
    unsigned short* h2inb = (unsigned short*)(ws + alloc((size_t)N_NODES * 256 * 2));
    unsigned short* h2b   = (unsigned short*)(ws + alloc((size_t)N_NODES * 64 * 2));
    float* as1  = (float*)(ws + alloc((size_t)N_NODES * HEADS * 4));
    float* ad1  = (float*)(ws + alloc((size_t)N_NODES * HEADS * 4));
    float* as2  = (float*)(ws + alloc((size_t)N_NODES * 4));
    float* ad2  = (float*)(ws + alloc((size_t)N_NODES * 4));
    int*   deg  = (int*)(ws + alloc((size_t)N_NODES * 4));
    int*   off  = (int*)(ws + alloc((size_t)(N_NODES + 1) * 4));
    int*   cur  = (int*)(ws + alloc((size_t)N_NODES * 4));
    int*   bsum = (int*)(ws + alloc(256 * 4));
    int*   ssrc = (int*)(ws + alloc((size_t)E_TOT * 4));

    (void)hipMemsetAsync(deg, 0, (size_t)N_NODES * 4, stream);
    int eblk = (E_TOT + 255) / 256;
    hist_kernel<<<eblk, 256, 0, stream>>>(ei, deg);
    scan1_kernel<<<NBLK, 256, 0, stream>>>(deg, off, bsum);
    scan2_kernel<<<1, 256, 0, stream>>>(bsum, NBLK);
    scan3_kernel<<<NBLK, 256, 0, stream>>>(off, bsum, cur);
    scatter_kernel<<<eblk, 256, 0, stream>>>(ei, cur, ssrc);

    gemm1_tiled<<<GBLK, 256, 0, stream>>>(x, W1, ats1, atd1, h1b, as1, ad1);
    agg1_kernel<<<ABLK, 256, 0, stream>>>(off, ssrc, h1b, as1, ad1, b1, h2inb);

    gemm2_tiled<<<GBLK, 256, 0, stream>>>(h2inb, W2, ats2, atd2, h2b, as2, ad2);
    agg2_kernel<<<ABLK, 256, 0, stream>>>(off, ssrc, h2b, as2, ad2, b2, out);
}

// Round 13
// 303.370 us; speedup vs baseline: 1.1010x; 1.1010x over previous
//
#include <hip/hip_runtime.h>
#include <hip/hip_bf16.h>
#include <math.h>

#define N_NODES 50000
#define N_EDGES 800000
#define E_TOT   (N_EDGES + N_NODES)   // 850000 (with self-loops)
#define IN_CH 128
#define HID 32
#define HEADS 8
#define OUT_CH 64
#define NEG_SLOPE 0.2f
#define NBLK 196                      // ceil(50000/256)
#define M_BLK 64
#define GBLK 782                      // ceil(50000/64)
#define ABLK 12500                    // 50000/4 nodes per 256-thread block
#define LOG2E 1.4426950408889634f

__device__ __forceinline__ float lrelu(float x) { return x > 0.f ? x : NEG_SLOPE * x; }
// exp(lrelu(z)) = exp2(max(z*L, z*0.2L))  (branchless; valid since L>0)
__device__ __forceinline__ float explrelu(float z) {
    return exp2f(fmaxf(z * LOG2E, z * (NEG_SLOPE * LOG2E)));
}

__device__ __forceinline__ unsigned short f2bf(float f) {
    unsigned int u = __float_as_uint(f);
    unsigned int r = (u + 0x7FFFu + ((u >> 16) & 1u)) >> 16;   // round-nearest-even
    return (unsigned short)r;
}
__device__ __forceinline__ float bf2f(unsigned short u) {
    return __uint_as_float(((unsigned int)u) << 16);
}
__device__ __forceinline__ float bflo(unsigned int u) {       // low ushort -> float
    return __uint_as_float(u << 16);
}
__device__ __forceinline__ float bfhi(unsigned int u) {       // high ushort -> float
    return __uint_as_float(u & 0xFFFF0000u);
}

// ---------------- CSR build ----------------
__global__ void hist_kernel(const int* __restrict__ ei, int* __restrict__ deg) {
    int e = blockIdx.x * blockDim.x + threadIdx.x;
    if (e >= E_TOT) return;
    int d = (e < N_EDGES) ? ei[N_EDGES + e] : (e - N_EDGES);
    atomicAdd(&deg[d], 1);
}

__global__ void scan1_kernel(const int* __restrict__ deg, int* __restrict__ off,
                             int* __restrict__ bsum) {
    __shared__ int s[256];
    int b = blockIdx.x, t = threadIdx.x, g = b * 256 + t;
    int v = (g < N_NODES) ? deg[g] : 0;
    s[t] = v;
    __syncthreads();
    for (int d = 1; d < 256; d <<= 1) {
        int o = (t >= d) ? s[t - d] : 0;
        __syncthreads();
        s[t] += o;
        __syncthreads();
    }
    if (g < N_NODES) off[g] = s[t] - v;
    if (t == 255) bsum[b] = s[t];
}

__global__ void scan2_kernel(int* __restrict__ bsum, int nb) {
    __shared__ int s[256];
    int t = threadIdx.x;
    int v = (t < nb) ? bsum[t] : 0;
    s[t] = v;
    __syncthreads();
    for (int d = 1; d < 256; d <<= 1) {
        int o = (t >= d) ? s[t - d] : 0;
        __syncthreads();
        s[t] += o;
        __syncthreads();
    }
    if (t < nb) bsum[t] = s[t] - v;
}

__global__ void scan3_kernel(int* __restrict__ off, const int* __restrict__ bsum,
                             int* __restrict__ cur) {
    int b = blockIdx.x, t = threadIdx.x, g = b * 256 + t;
    if (g < N_NODES) {
        int v = off[g] + bsum[b];
        off[g] = v;
        cur[g] = v;
    }
    if (g == 0) off[N_NODES] = E_TOT;
}

__global__ void scatter_kernel(const int* __restrict__ ei, int* __restrict__ cur,
                               int* __restrict__ ssrc) {
    int e = blockIdx.x * blockDim.x + threadIdx.x;
    if (e >= E_TOT) return;
    int s, d;
    if (e < N_EDGES) { s = ei[e]; d = ei[N_EDGES + e]; }
    else             { s = d = e - N_EDGES; }
    int pos = atomicAdd(&cur[d], 1);
    ssrc[pos] = s;
}

// ---------------- GEMM1 (tiled, 64x256 tile) + alpha epilogue, bf16 h1 out ---
#define FMA4(accv, av, bv)                                                     \
    accv.x = fmaf(av, bv.x, accv.x); accv.y = fmaf(av, bv.y, accv.y);          \
    accv.z = fmaf(av, bv.z, accv.z); accv.w = fmaf(av, bv.w, accv.w);

__global__ __launch_bounds__(256) void gemm1_tiled(
    const float* __restrict__ x, const float* __restrict__ W1,
    const float* __restrict__ att_s, const float* __restrict__ att_d,
    unsigned short* __restrict__ h1b, float* __restrict__ as1, float* __restrict__ ad1) {
    __shared__ float As[M_BLK][IN_CH];   // 32 KB
    int t = threadIdx.x;
    int row0 = blockIdx.x * M_BLK;
#pragma unroll
    for (int i = 0; i < 8; ++i) {
        int f = t + i * 256;
        int r = f >> 5, c4 = (f & 31) * 4;
        int gr = row0 + r; if (gr >= N_NODES) gr = N_NODES - 1;
        *(float4*)&As[r][c4] = *(const float4*)&x[(size_t)gr * IN_CH + c4];
    }
    __syncthreads();
    int col0 = (t & 63) * 4;
    int rbase = (t >> 6) * 16;
    float4 acc[16];
#pragma unroll
    for (int m = 0; m < 16; ++m) acc[m] = make_float4(0.f, 0.f, 0.f, 0.f);

    for (int k = 0; k < IN_CH; k += 4) {
        float4 b0 = *(const float4*)&W1[(k + 0) * 256 + col0];
        float4 b1 = *(const float4*)&W1[(k + 1) * 256 + col0];
        float4 b2 = *(const float4*)&W1[(k + 2) * 256 + col0];
        float4 b3 = *(const float4*)&W1[(k + 3) * 256 + col0];
#pragma unroll
        for (int m = 0; m < 16; ++m) {
            float4 a = *(const float4*)&As[rbase + m][k];
            FMA4(acc[m], a.x, b0);
            FMA4(acc[m], a.y, b1);
            FMA4(acc[m], a.z, b2);
            FMA4(acc[m], a.w, b3);
        }
    }

    float4 s4 = *(const float4*)&att_s[col0];
    float4 d4 = *(const float4*)&att_d[col0];
    int head = col0 >> 5;
#pragma unroll
    for (int m = 0; m < 16; ++m) {
        int gr = row0 + rbase + m;
        if (gr < N_NODES) {
            ushort4 hb;
            hb.x = f2bf(acc[m].x); hb.y = f2bf(acc[m].y);
            hb.z = f2bf(acc[m].z); hb.w = f2bf(acc[m].w);
            *(ushort4*)&h1b[(size_t)gr * 256 + col0] = hb;
            float p = acc[m].x * s4.x + acc[m].y * s4.y + acc[m].z * s4.z + acc[m].w * s4.w;
            float q = acc[m].x * d4.x + acc[m].y * d4.y + acc[m].z * d4.z + acc[m].w * d4.w;
            p += __shfl_xor(p, 1); p += __shfl_xor(p, 2); p += __shfl_xor(p, 4);
            q += __shfl_xor(q, 1); q += __shfl_xor(q, 2); q += __shfl_xor(q, 4);
            if ((t & 7) == 0) {
                as1[gr * HEADS + head] = p;
                ad1[gr * HEADS + head] = q;
            }
        }
    }
}

// ---------------- Aggregate layer 1: 1 wave/node, 8-edge batches, 2-deep pipe
// lane l: channels [l*4,l*4+4), head h = l>>3.
// Unconditional 8-gather batches (loads co-issue); next batch's ssrc and
// as1 gather are prefetched during the current batch's FMA block.
__global__ __launch_bounds__(256) void agg1_kernel(
    const int* __restrict__ off, const int* __restrict__ ssrc,
    const unsigned short* __restrict__ h1b, const float* __restrict__ as1,
    const float* __restrict__ ad1, const float* __restrict__ b1,
    unsigned short* __restrict__ houtb) {
    int t = threadIdx.x;
    int lane = t & 63;
    int n = blockIdx.x * 4 + (t >> 6);
    int h = lane >> 3;
    int e8 = lane & 7;
    int c0 = lane * 4;
    int start = off[n], end = off[n + 1];
    int last = end - 1;
    float ad_w = ad1[n * HEADS + e8];   // weight phase (lane computes head e8)
    float ad_h = ad1[n * HEADS + h];    // tail phase (lane consumes head h)
    float4 acc = make_float4(0.f, 0.f, 0.f, 0.f);
    float den = 0.f;
    int i = start;
    if (i + 8 <= end) {
        int sv = ssrc[i + e8];
        int se = __shfl(sv, h);
        float av = as1[se * HEADS + e8];
        while (i + 8 <= end) {
            int inext = i + 8;
            // prefetch next batch (clamped addresses always valid: deg >= 1)
            int sv_n = ssrc[min(inext + e8, last)];
            int se_n = __shfl(sv_n, h);
            float av_n = as1[se_n * HEADS + e8];
            float wv = explrelu(av + ad_w);           // 64 weights, one chain
#pragma unroll
            for (int j = 0; j < 8; ++j) {
                float wj = __shfl(wv, j * 8 + h);
                int   sj = __shfl(sv, j);
                uint2 u = *(const uint2*)&h1b[(unsigned)sj * 256 + c0];
                den += wj;
                acc.x = fmaf(wj, bflo(u.x), acc.x);
                acc.y = fmaf(wj, bfhi(u.x), acc.y);
                acc.z = fmaf(wj, bflo(u.y), acc.z);
                acc.w = fmaf(wj, bfhi(u.y), acc.w);
            }
            sv = sv_n; av = av_n;
            i = inext;
        }
    }
    for (; i < end; ++i) {                            // scalar tail (< 8 edges)
        int s0 = ssrc[i];
        float w0 = explrelu(as1[s0 * HEADS + h] + ad_h);
        uint2 u = *(const uint2*)&h1b[(unsigned)s0 * 256 + c0];
        den += w0;
        acc.x = fmaf(w0, bflo(u.x), acc.x);
        acc.y = fmaf(w0, bfhi(u.x), acc.y);
        acc.z = fmaf(w0, bflo(u.y), acc.z);
        acc.w = fmaf(w0, bfhi(u.y), acc.w);
    }
    float r = __builtin_amdgcn_rcpf(den);
    float4 bv = *(const float4*)&b1[c0];
    float vx = fmaf(acc.x, r, bv.x);
    float vy = fmaf(acc.y, r, bv.y);
    float vz = fmaf(acc.z, r, bv.z);
    float vw = fmaf(acc.w, r, bv.w);
    vx = vx > 0.f ? vx : expm1f(vx);
    vy = vy > 0.f ? vy : expm1f(vy);
    vz = vz > 0.f ? vz : expm1f(vz);
    vw = vw > 0.f ? vw : expm1f(vw);
    ushort4 ob;
    ob.x = f2bf(vx); ob.y = f2bf(vy); ob.z = f2bf(vz); ob.w = f2bf(vw);
    *(ushort4*)&houtb[(unsigned)n * 256 + c0] = ob;
}

// ---------------- GEMM2 (tiled, 64x64 tile, bf16 in, 4x4 blocking) ----------
__global__ __launch_bounds__(256) void gemm2_tiled(
    const unsigned short* __restrict__ hinb, const float* __restrict__ W2,
    const float* __restrict__ att_s2, const float* __restrict__ att_d2,
    unsigned short* __restrict__ h2b, float* __restrict__ as2, float* __restrict__ ad2) {
    __shared__ float As[M_BLK][256];   // 64 KB
    int t = threadIdx.x;
    int row0 = blockIdx.x * M_BLK;
#pragma unroll
    for (int i = 0; i < 16; ++i) {
        int f = t + i * 256;
        int r = f >> 6, c4 = (f & 63) * 4;
        int gr = row0 + r; if (gr >= N_NODES) gr = N_NODES - 1;
        ushort4 u = *(const ushort4*)&hinb[(size_t)gr * 256 + c4];
        float4 v = make_float4(bf2f(u.x), bf2f(u.y), bf2f(u.z), bf2f(u.w));
        *(float4*)&As[r][c4] = v;
    }
    __syncthreads();
    int col0 = (t & 15) * 4;
    int rbase = (t >> 4) * 4;
    float4 acc[4];
#pragma unroll
    for (int m = 0; m < 4; ++m) acc[m] = make_float4(0.f, 0.f, 0.f, 0.f);

    for (int k = 0; k < 256; k += 4) {
        float4 b0 = *(const float4*)&W2[(k + 0) * 64 + col0];
        float4 b1 = *(const float4*)&W2[(k + 1) * 64 + col0];
        float4 b2 = *(const float4*)&W2[(k + 2) * 64 + col0];
        float4 b3 = *(const float4*)&W2[(k + 3) * 64 + col0];
#pragma unroll
        for (int m = 0; m < 4; ++m) {
            float4 a = *(const float4*)&As[rbase + m][k];
            FMA4(acc[m], a.x, b0);
            FMA4(acc[m], a.y, b1);
            FMA4(acc[m], a.z, b2);
            FMA4(acc[m], a.w, b3);
        }
    }

    float4 s4 = *(const float4*)&att_s2[col0];
    float4 d4 = *(const float4*)&att_d2[col0];
#pragma unroll
    for (int m = 0; m < 4; ++m) {
        int gr = row0 + rbase + m;
        if (gr < N_NODES) {
            ushort4 hb;
            hb.x = f2bf(acc[m].x); hb.y = f2bf(acc[m].y);
            hb.z = f2bf(acc[m].z); hb.w = f2bf(acc[m].w);
            *(ushort4*)&h2b[(size_t)gr * 64 + col0] = hb;
            float p = acc[m].x * s4.x + acc[m].y * s4.y + acc[m].z * s4.z + acc[m].w * s4.w;
            float q = acc[m].x * d4.x + acc[m].y * d4.y + acc[m].z * d4.z + acc[m].w * d4.w;
            p += __shfl_xor(p, 1); q += __shfl_xor(q, 1);
            p += __shfl_xor(p, 2); q += __shfl_xor(q, 2);
            p += __shfl_xor(p, 4); q += __shfl_xor(q, 4);
            p += __shfl_xor(p, 8); q += __shfl_xor(q, 8);
            if ((t & 15) == 0) { as2[gr] = p; ad2[gr] = q; }
        }
    }
}

// ---------------- Aggregate layer 2: 1 wave/node, 8-edge batches, 2-deep pipe
__global__ __launch_bounds__(256) void agg2_kernel(
    const int* __restrict__ off, const int* __restrict__ ssrc,
    const unsigned short* __restrict__ h2b, const float* __restrict__ as2,
    const float* __restrict__ ad2, const float* __restrict__ b2,
    float* __restrict__ out) {
    int t = threadIdx.x;
    int lane = t & 63;
    int e8 = lane & 7;
    int n = blockIdx.x * 4 + (t >> 6);
    int start = off[n], end = off[n + 1];
    int last = end - 1;
    float adv = ad2[n];
    float acc = 0.f, den = 0.f;
    int i = start;
    if (i + 8 <= end) {
        int sv = ssrc[i + e8];
        float av = as2[sv];
        while (i + 8 <= end) {
            int inext = i + 8;
            int sv_n = ssrc[min(inext + e8, last)];
            float av_n = as2[sv_n];
            float wv = explrelu(av + adv);
#pragma unroll
            for (int j = 0; j < 8; ++j) {
                float wj = __shfl(wv, j);
                int   sj = __shfl(sv, j);
                float v = bf2f(h2b[(unsigned)sj * 64 + lane]);
                den += wj;
                acc = fmaf(wj, v, acc);
            }
            sv = sv_n; av = av_n;
            i = inext;
        }
    }
    for (; i < end; ++i) {
        int s0 = ssrc[i];
        float w0 = explrelu(as2[s0] + adv);
        den += w0;
        acc = fmaf(w0, bf2f(h2b[(unsigned)s0 * 64 + lane]), acc);
    }
    float r = __builtin_amdgcn_rcpf(den);
    out[(unsigned)n * 64 + lane] = fmaf(acc, r, b2[lane]);
}

extern "C" void kernel_launch(void* const* d_in, const int* in_sizes, int n_in,
                              void* d_out, int out_size, void* d_ws, size_t ws_size,
                              hipStream_t stream) {
    const float* x    = (const float*)d_in[0];
    const int*   ei   = (const int*)d_in[1];
    const float* W1   = (const float*)d_in[2];
    const float* ats1 = (const float*)d_in[3];
    const float* atd1 = (const float*)d_in[4];
    const float* b1   = (const float*)d_in[5];
    const float* W2   = (const float*)d_in[6];
    const float* ats2 = (const float*)d_in[7];
    const float* atd2 = (const float*)d_in[8];
    const float* b2   = (const float*)d_in[9];
    float* out = (float*)d_out;

    char* ws = (char*)d_ws;
    size_t o = 0;
    auto alloc = [&](size_t bytes) { size_t r = o; o = (o + bytes + 255) & ~255UL; return r; };
    unsigned short* h1b   = (unsigned short*)(ws + alloc((size_t)N_NODES * 256 * 2));
    unsigned short* h2inb = (unsigned short*)(ws + alloc((size_t)N_NODES * 256 * 2));
    unsigned short* h2b   = (unsigned short*)(ws + alloc((size_t)N_NODES * 64 * 2));
    float* as1  = (float*)(ws + alloc((size_t)N_NODES * HEADS * 4));
    float* ad1  = (float*)(ws + alloc((size_t)N_NODES * HEADS * 4));
    float* as2  = (float*)(ws + alloc((size_t)N_NODES * 4));
    float* ad2  = (float*)(ws + alloc((size_t)N_NODES * 4));
    int*   deg  = (int*)(ws + alloc((size_t)N_NODES * 4));
    int*   off  = (int*)(ws + alloc((size_t)(N_NODES + 1) * 4));
    int*   cur  = (int*)(ws + alloc((size_t)N_NODES * 4));
    int*   bsum = (int*)(ws + alloc(256 * 4));
    int*   ssrc = (int*)(ws + alloc((size_t)E_TOT * 4));

    (void)hipMemsetAsync(deg, 0, (size_t)N_NODES * 4, stream);
    int eblk = (E_TOT + 255) / 256;
    hist_kernel<<<eblk, 256, 0, stream>>>(ei, deg);
    scan1_kernel<<<NBLK, 256, 0, stream>>>(deg, off, bsum);
    scan2_kernel<<<1, 256, 0, stream>>>(bsum, NBLK);
    scan3_kernel<<<NBLK, 256, 0, stream>>>(off, bsum, cur);
    scatter_kernel<<<eblk, 256, 0, stream>>>(ei, cur, ssrc);

    gemm1_tiled<<<GBLK, 256, 0, stream>>>(x, W1, ats1, atd1, h1b, as1, ad1);
    agg1_kernel<<<ABLK, 256, 0, stream>>>(off, ssrc, h1b, as1, ad1, b1, h2inb);

    gemm2_tiled<<<GBLK, 256, 0, stream>>>(h2inb, W2, ats2, atd2, h2b, as2, ad2);
    agg2_kernel<<<ABLK, 256, 0, stream>>>(off, ssrc, h2b, as2, ad2, b2, out);
}

// Round 14
// 294.465 us; speedup vs baseline: 1.1343x; 1.0302x over previous
//
#include <hip/hip_runtime.h>
#include <hip/hip_bf16.h>
#include <math.h>

#define N_NODES 50000
#define N_EDGES 800000
#define E_TOT   (N_EDGES + N_NODES)   // 850000 (with self-loops)
#define IN_CH 128
#define HID 32
#define HEADS 8
#define OUT_CH 64
#define NEG_SLOPE 0.2f
#define NBLK 196                      // ceil(50000/256)
#define M_BLK 64
#define GBLK 782                      // ceil(50000/64)
#define ABLK 12500                    // 50000/4 nodes per 256-thread block
#define LOG2E 1.4426950408889634f

__device__ __forceinline__ float lrelu(float x) { return x > 0.f ? x : NEG_SLOPE * x; }
// exp(lrelu(z)) = exp2(max(z*L, z*0.2L))  (branchless; valid since L>0)
__device__ __forceinline__ float explrelu(float z) {
    return exp2f(fmaxf(z * LOG2E, z * (NEG_SLOPE * LOG2E)));
}

__device__ __forceinline__ unsigned short f2bf(float f) {
    unsigned int u = __float_as_uint(f);
    unsigned int r = (u + 0x7FFFu + ((u >> 16) & 1u)) >> 16;   // round-nearest-even
    return (unsigned short)r;
}
__device__ __forceinline__ float bf2f(unsigned short u) {
    return __uint_as_float(((unsigned int)u) << 16);
}
__device__ __forceinline__ float bflo(unsigned int u) {       // low ushort -> float
    return __uint_as_float(u << 16);
}
__device__ __forceinline__ float bfhi(unsigned int u) {       // high ushort -> float
    return __uint_as_float(u & 0xFFFF0000u);
}

// ---------------- CSR build ----------------
__global__ void hist_kernel(const int* __restrict__ ei, int* __restrict__ deg) {
    int e = blockIdx.x * blockDim.x + threadIdx.x;
    if (e >= E_TOT) return;
    int d = (e < N_EDGES) ? ei[N_EDGES + e] : (e - N_EDGES);
    atomicAdd(&deg[d], 1);
}

__global__ void scan1_kernel(const int* __restrict__ deg, int* __restrict__ off,
                             int* __restrict__ bsum) {
    __shared__ int s[256];
    int b = blockIdx.x, t = threadIdx.x, g = b * 256 + t;
    int v = (g < N_NODES) ? deg[g] : 0;
    s[t] = v;
    __syncthreads();
    for (int d = 1; d < 256; d <<= 1) {
        int o = (t >= d) ? s[t - d] : 0;
        __syncthreads();
        s[t] += o;
        __syncthreads();
    }
    if (g < N_NODES) off[g] = s[t] - v;
    if (t == 255) bsum[b] = s[t];
}

__global__ void scan2_kernel(int* __restrict__ bsum, int nb) {
    __shared__ int s[256];
    int t = threadIdx.x;
    int v = (t < nb) ? bsum[t] : 0;
    s[t] = v;
    __syncthreads();
    for (int d = 1; d < 256; d <<= 1) {
        int o = (t >= d) ? s[t - d] : 0;
        __syncthreads();
        s[t] += o;
        __syncthreads();
    }
    if (t < nb) bsum[t] = s[t] - v;
}

__global__ void scan3_kernel(int* __restrict__ off, const int* __restrict__ bsum,
                             int* __restrict__ cur) {
    int b = blockIdx.x, t = threadIdx.x, g = b * 256 + t;
    if (g < N_NODES) {
        int v = off[g] + bsum[b];
        off[g] = v;
        cur[g] = v;
    }
    if (g == 0) off[N_NODES] = E_TOT;
}

__global__ void scatter_kernel(const int* __restrict__ ei, int* __restrict__ cur,
                               int* __restrict__ ssrc) {
    int e = blockIdx.x * blockDim.x + threadIdx.x;
    if (e >= E_TOT) return;
    int s, d;
    if (e < N_EDGES) { s = ei[e]; d = ei[N_EDGES + e]; }
    else             { s = d = e - N_EDGES; }
    int pos = atomicAdd(&cur[d], 1);
    ssrc[pos] = s;
}

// ---------------- GEMM1 (tiled, 64x256 tile) + alpha epilogue, bf16 h1 out ---
#define FMA4(accv, av, bv)                                                     \
    accv.x = fmaf(av, bv.x, accv.x); accv.y = fmaf(av, bv.y, accv.y);          \
    accv.z = fmaf(av, bv.z, accv.z); accv.w = fmaf(av, bv.w, accv.w);

__global__ __launch_bounds__(256) void gemm1_tiled(
    const float* __restrict__ x, const float* __restrict__ W1,
    const float* __restrict__ att_s, const float* __restrict__ att_d,
    unsigned short* __restrict__ h1b, float* __restrict__ as1, float* __restrict__ ad1) {
    __shared__ float As[M_BLK][IN_CH];   // 32 KB
    int t = threadIdx.x;
    int row0 = blockIdx.x * M_BLK;
#pragma unroll
    for (int i = 0; i < 8; ++i) {
        int f = t + i * 256;
        int r = f >> 5, c4 = (f & 31) * 4;
        int gr = row0 + r; if (gr >= N_NODES) gr = N_NODES - 1;
        *(float4*)&As[r][c4] = *(const float4*)&x[(size_t)gr * IN_CH + c4];
    }
    __syncthreads();
    int col0 = (t & 63) * 4;
    int rbase = (t >> 6) * 16;
    float4 acc[16];
#pragma unroll
    for (int m = 0; m < 16; ++m) acc[m] = make_float4(0.f, 0.f, 0.f, 0.f);

    for (int k = 0; k < IN_CH; k += 4) {
        float4 b0 = *(const float4*)&W1[(k + 0) * 256 + col0];
        float4 b1 = *(const float4*)&W1[(k + 1) * 256 + col0];
        float4 b2 = *(const float4*)&W1[(k + 2) * 256 + col0];
        float4 b3 = *(const float4*)&W1[(k + 3) * 256 + col0];
#pragma unroll
        for (int m = 0; m < 16; ++m) {
            float4 a = *(const float4*)&As[rbase + m][k];
            FMA4(acc[m], a.x, b0);
            FMA4(acc[m], a.y, b1);
            FMA4(acc[m], a.z, b2);
            FMA4(acc[m], a.w, b3);
        }
    }

    float4 s4 = *(const float4*)&att_s[col0];
    float4 d4 = *(const float4*)&att_d[col0];
    int head = col0 >> 5;
#pragma unroll
    for (int m = 0; m < 16; ++m) {
        int gr = row0 + rbase + m;
        if (gr < N_NODES) {
            ushort4 hb;
            hb.x = f2bf(acc[m].x); hb.y = f2bf(acc[m].y);
            hb.z = f2bf(acc[m].z); hb.w = f2bf(acc[m].w);
            *(ushort4*)&h1b[(size_t)gr * 256 + col0] = hb;
            float p = acc[m].x * s4.x + acc[m].y * s4.y + acc[m].z * s4.z + acc[m].w * s4.w;
            float q = acc[m].x * d4.x + acc[m].y * d4.y + acc[m].z * d4.z + acc[m].w * d4.w;
            p += __shfl_xor(p, 1); p += __shfl_xor(p, 2); p += __shfl_xor(p, 4);
            q += __shfl_xor(q, 1); q += __shfl_xor(q, 2); q += __shfl_xor(q, 4);
            if ((t & 7) == 0) {
                as1[gr * HEADS + head] = p;
                ad1[gr * HEADS + head] = q;
            }
        }
    }
}

// ---------------- Aggregate layer 1: dual-edge wide gathers -----------------
// Weight phase per 8-edge batch: wv[l] = w(edge l>>3, head l&7), one exp chain.
// Gather phase: 4 steps; each step one uint4 gather covers 2 full rows
// (lanes 0-31 = even edge, 32-63 = odd edge). Duplicated 8-ch accumulators,
// combined by shfl_xor(32) at the end. Tail edges masked with w=0 (exact).
__global__ __launch_bounds__(256) void agg1_kernel(
    const int* __restrict__ off, const int* __restrict__ ssrc,
    const unsigned short* __restrict__ h1b, const float* __restrict__ as1,
    const float* __restrict__ ad1, const float* __restrict__ b1,
    unsigned short* __restrict__ houtb) {
    int t = threadIdx.x;
    int lane = t & 63;
    int n = blockIdx.x * 4 + (t >> 6);
    int h    = lane >> 3;     // weight-phase head
    int e8   = lane & 7;      // weight-phase edge slot
    int c    = lane & 31;     // channel group: ushorts [c*8, c*8+8)
    int hh   = c >> 2;        // head of my channel group
    int half = lane >> 5;     // 0: even edges, 1: odd edges
    int start = off[n], end = off[n + 1];
    int last = end - 1;
    float ad_w = ad1[n * HEADS + e8];
    float acc[8];
#pragma unroll
    for (int j = 0; j < 8; ++j) acc[j] = 0.f;
    float den = 0.f;
    int sv = ssrc[min(start + e8, last)];
    int se = __shfl(sv, h);
    float av = as1[se * HEADS + e8];
    for (int i = start; i < end; i += 8) {
        int inext = i + 8;
        int sv_n = ssrc[min(inext + e8, last)];          // prefetch next batch
        int se_n = __shfl(sv_n, h);
        float av_n = as1[se_n * HEADS + e8];
        float wv = explrelu(av + ad_w);                  // 64 weights, one chain
#pragma unroll
        for (int k = 0; k < 4; ++k) {
            int me = 2 * k + half;                       // my edge this step
            float wj = __shfl(wv, me * 8 + hh);
            int   sj = __shfl(sv, me);
            wj = (i + me < end) ? wj : 0.f;              // mask tail (exact)
            uint4 u = *(const uint4*)&h1b[(unsigned)sj * 256 + c * 8];
            den += wj;
            acc[0] = fmaf(wj, bflo(u.x), acc[0]);
            acc[1] = fmaf(wj, bfhi(u.x), acc[1]);
            acc[2] = fmaf(wj, bflo(u.y), acc[2]);
            acc[3] = fmaf(wj, bfhi(u.y), acc[3]);
            acc[4] = fmaf(wj, bflo(u.z), acc[4]);
            acc[5] = fmaf(wj, bfhi(u.z), acc[5]);
            acc[6] = fmaf(wj, bflo(u.w), acc[6]);
            acc[7] = fmaf(wj, bfhi(u.w), acc[7]);
        }
        sv = sv_n; av = av_n;
    }
#pragma unroll
    for (int j = 0; j < 8; ++j) acc[j] += __shfl_xor(acc[j], 32);
    den += __shfl_xor(den, 32);
    if (lane < 32) {
        float r = __builtin_amdgcn_rcpf(den);
        float4 b0 = *(const float4*)&b1[c * 8];
        float4 b4 = *(const float4*)&b1[c * 8 + 4];
        float v0 = fmaf(acc[0], r, b0.x);
        float v1 = fmaf(acc[1], r, b0.y);
        float v2 = fmaf(acc[2], r, b0.z);
        float v3 = fmaf(acc[3], r, b0.w);
        float v4 = fmaf(acc[4], r, b4.x);
        float v5 = fmaf(acc[5], r, b4.y);
        float v6 = fmaf(acc[6], r, b4.z);
        float v7 = fmaf(acc[7], r, b4.w);
        v0 = v0 > 0.f ? v0 : expm1f(v0);
        v1 = v1 > 0.f ? v1 : expm1f(v1);
        v2 = v2 > 0.f ? v2 : expm1f(v2);
        v3 = v3 > 0.f ? v3 : expm1f(v3);
        v4 = v4 > 0.f ? v4 : expm1f(v4);
        v5 = v5 > 0.f ? v5 : expm1f(v5);
        v6 = v6 > 0.f ? v6 : expm1f(v6);
        v7 = v7 > 0.f ? v7 : expm1f(v7);
        uint4 ob;
        ob.x = (unsigned)f2bf(v0) | ((unsigned)f2bf(v1) << 16);
        ob.y = (unsigned)f2bf(v2) | ((unsigned)f2bf(v3) << 16);
        ob.z = (unsigned)f2bf(v4) | ((unsigned)f2bf(v5) << 16);
        ob.w = (unsigned)f2bf(v6) | ((unsigned)f2bf(v7) << 16);
        *(uint4*)&houtb[(unsigned)n * 256 + c * 8] = ob;
    }
}

// ---------------- GEMM2 (tiled, 64x64 tile, bf16 in, 4x4 blocking) ----------
__global__ __launch_bounds__(256) void gemm2_tiled(
    const unsigned short* __restrict__ hinb, const float* __restrict__ W2,
    const float* __restrict__ att_s2, const float* __restrict__ att_d2,
    unsigned short* __restrict__ h2b, float* __restrict__ as2, float* __restrict__ ad2) {
    __shared__ float As[M_BLK][256];   // 64 KB
    int t = threadIdx.x;
    int row0 = blockIdx.x * M_BLK;
#pragma unroll
    for (int i = 0; i < 16; ++i) {
        int f = t + i * 256;
        int r = f >> 6, c4 = (f & 63) * 4;
        int gr = row0 + r; if (gr >= N_NODES) gr = N_NODES - 1;
        ushort4 u = *(const ushort4*)&hinb[(size_t)gr * 256 + c4];
        float4 v = make_float4(bf2f(u.x), bf2f(u.y), bf2f(u.z), bf2f(u.w));
        *(float4*)&As[r][c4] = v;
    }
    __syncthreads();
    int col0 = (t & 15) * 4;
    int rbase = (t >> 4) * 4;
    float4 acc[4];
#pragma unroll
    for (int m = 0; m < 4; ++m) acc[m] = make_float4(0.f, 0.f, 0.f, 0.f);

    for (int k = 0; k < 256; k += 4) {
        float4 b0 = *(const float4*)&W2[(k + 0) * 64 + col0];
        float4 b1 = *(const float4*)&W2[(k + 1) * 64 + col0];
        float4 b2 = *(const float4*)&W2[(k + 2) * 64 + col0];
        float4 b3 = *(const float4*)&W2[(k + 3) * 64 + col0];
#pragma unroll
        for (int m = 0; m < 4; ++m) {
            float4 a = *(const float4*)&As[rbase + m][k];
            FMA4(acc[m], a.x, b0);
            FMA4(acc[m], a.y, b1);
            FMA4(acc[m], a.z, b2);
            FMA4(acc[m], a.w, b3);
        }
    }

    float4 s4 = *(const float4*)&att_s2[col0];
    float4 d4 = *(const float4*)&att_d2[col0];
#pragma unroll
    for (int m = 0; m < 4; ++m) {
        int gr = row0 + rbase + m;
        if (gr < N_NODES) {
            ushort4 hb;
            hb.x = f2bf(acc[m].x); hb.y = f2bf(acc[m].y);
            hb.z = f2bf(acc[m].z); hb.w = f2bf(acc[m].w);
            *(ushort4*)&h2b[(size_t)gr * 64 + col0] = hb;
            float p = acc[m].x * s4.x + acc[m].y * s4.y + acc[m].z * s4.z + acc[m].w * s4.w;
            float q = acc[m].x * d4.x + acc[m].y * d4.y + acc[m].z * d4.z + acc[m].w * d4.w;
            p += __shfl_xor(p, 1); q += __shfl_xor(q, 1);
            p += __shfl_xor(p, 2); q += __shfl_xor(q, 2);
            p += __shfl_xor(p, 4); q += __shfl_xor(q, 4);
            p += __shfl_xor(p, 8); q += __shfl_xor(q, 8);
            if ((t & 15) == 0) { as2[gr] = p; ad2[gr] = q; }
        }
    }
}

// ---------------- Aggregate layer 2: quad-edge wide gathers -----------------
// One uint2 gather covers 4 full 128B rows (16 lanes each). 4-way duplicated
// 4-ch accumulators; 2-level xor reduce; lanes 0-15 store float4.
__global__ __launch_bounds__(256) void agg2_kernel(
    const int* __restrict__ off, const int* __restrict__ ssrc,
    const unsigned short* __restrict__ h2b, const float* __restrict__ as2,
    const float* __restrict__ ad2, const float* __restrict__ b2,
    float* __restrict__ out) {
    int t = threadIdx.x;
    int lane = t & 63;
    int e8 = lane & 7;
    int q = lane & 15;        // channels [q*4, q*4+4)
    int quarter = lane >> 4;  // which edge of the 4 per step
    int n = blockIdx.x * 4 + (t >> 6);
    int start = off[n], end = off[n + 1];
    int last = end - 1;
    float adv = ad2[n];
    float acc[4];
#pragma unroll
    for (int j = 0; j < 4; ++j) acc[j] = 0.f;
    float den = 0.f;
    int sv = ssrc[min(start + e8, last)];
    float av = as2[sv];
    for (int i = start; i < end; i += 8) {
        int inext = i + 8;
        int sv_n = ssrc[min(inext + e8, last)];
        float av_n = as2[sv_n];
        float wv = explrelu(av + adv);                   // wv[l] = w(edge l&7)
#pragma unroll
        for (int k = 0; k < 2; ++k) {
            int me = 4 * k + quarter;
            float wj = __shfl(wv, me);
            int   sj = __shfl(sv, me);
            wj = (i + me < end) ? wj : 0.f;              // mask tail (exact)
            uint2 u = *(const uint2*)&h2b[(unsigned)sj * 64 + q * 4];
            den += wj;
            acc[0] = fmaf(wj, bflo(u.x), acc[0]);
            acc[1] = fmaf(wj, bfhi(u.x), acc[1]);
            acc[2] = fmaf(wj, bflo(u.y), acc[2]);
            acc[3] = fmaf(wj, bfhi(u.y), acc[3]);
        }
        sv = sv_n; av = av_n;
    }
#pragma unroll
    for (int j = 0; j < 4; ++j) {
        acc[j] += __shfl_xor(acc[j], 16);
        acc[j] += __shfl_xor(acc[j], 32);
    }
    den += __shfl_xor(den, 16);
    den += __shfl_xor(den, 32);
    if (lane < 16) {
        float r = __builtin_amdgcn_rcpf(den);
        float4 bv = *(const float4*)&b2[q * 4];
        float4 o;
        o.x = fmaf(acc[0], r, bv.x);
        o.y = fmaf(acc[1], r, bv.y);
        o.z = fmaf(acc[2], r, bv.z);
        o.w = fmaf(acc[3], r, bv.w);
        *(float4*)&out[(unsigned)n * 64 + q * 4] = o;
    }
}

extern "C" void kernel_launch(void* const* d_in, const int* in_sizes, int n_in,
                              void* d_out, int out_size, void* d_ws, size_t ws_size,
                              hipStream_t stream) {
    const float* x    = (const float*)d_in[0];
    const int*   ei   = (const int*)d_in[1];
    const float* W1   = (const float*)d_in[2];
    const float* ats1 = (const float*)d_in[3];
    const float* atd1 = (const float*)d_in[4];
    const float* b1   = (const float*)d_in[5];
    const float* W2   = (const float*)d_in[6];
    const float* ats2 = (const float*)d_in[7];
    const float* atd2 = (const float*)d_in[8];
    const float* b2   = (const float*)d_in[9];
    float* out = (float*)d_out;

    char* ws = (char*)d_ws;
    size_t o = 0;
    auto alloc = [&](size_t bytes) { size_t r = o; o = (o + bytes + 255) & ~255UL; return r; };
    unsigned short* h1b   = (unsigned short*)(ws + alloc((size_t)N_NODES * 256 * 2));
    unsigned short* h2inb = (unsigned short*)(ws + alloc((size_t)N_NODES * 256 * 2));
    unsigned short* h2b   = (unsigned short*)(ws + alloc((size_t)N_NODES * 64 * 2));
    float* as1  = (float*)(ws + alloc((size_t)N_NODES * HEADS * 4));
    float* ad1  = (float*)(ws + alloc((size_t)N_NODES * HEADS * 4));
    float* as2  = (float*)(ws + alloc((size_t)N_NODES * 4));
    float* ad2  = (float*)(ws + alloc((size_t)N_NODES * 4));
    int*   deg  = (int*)(ws + alloc((size_t)N_NODES * 4));
    int*   off  = (int*)(ws + alloc((size_t)(N_NODES + 1) * 4));
    int*   cur  = (int*)(ws + alloc((size_t)N_NODES * 4));
    int*   bsum = (int*)(ws + alloc(256 * 4));
    int*   ssrc = (int*)(ws + alloc((size_t)E_TOT * 4));

    (void)hipMemsetAsync(deg, 0, (size_t)N_NODES * 4, stream);
    int eblk = (E_TOT + 255) / 256;
    hist_kernel<<<eblk, 256, 0, stream>>>(ei, deg);
    scan1_kernel<<<NBLK, 256, 0, stream>>>(deg, off, bsum);
    scan2_kernel<<<1, 256, 0, stream>>>(bsum, NBLK);
    scan3_kernel<<<NBLK, 256, 0, stream>>>(off, bsum, cur);
    scatter_kernel<<<eblk, 256, 0, stream>>>(ei, cur, ssrc);

    gemm1_tiled<<<GBLK, 256, 0, stream>>>(x, W1, ats1, atd1, h1b, as1, ad1);
    agg1_kernel<<<ABLK, 256, 0, stream>>>(off, ssrc, h1b, as1, ad1, b1, h2inb);

    gemm2_tiled<<<GBLK, 256, 0, stream>>>(h2inb, W2, ats2, atd2, h2b, as2, ad2);
    agg2_kernel<<<ABLK, 256, 0, stream>>>(off, ssrc, h2b, as2, ad2, b2, out);
}

// Round 15
// 288.057 us; speedup vs baseline: 1.1595x; 1.0222x over previous
//
#include <hip/hip_runtime.h>
#include <hip/hip_bf16.h>
#include <math.h>

#define N_NODES 50000
#define N_EDGES 800000
#define E_TOT   (N_EDGES + N_NODES)   // 850000 (with self-loops)
#define IN_CH 128
#define HID 32
#define HEADS 8
#define OUT_CH 64
#define NEG_SLOPE 0.2f
#define NBLK 196                      // ceil(50000/256)
#define M_BLK1 32
#define G1BLK 1563                    // ceil(50000/32)
#define M_BLK 64
#define GBLK 782                      // ceil(50000/64)
#define ABLK 12500                    // 50000/4 nodes per 256-thread block
#define LOG2E 1.4426950408889634f

__device__ __forceinline__ float lrelu(float x) { return x > 0.f ? x : NEG_SLOPE * x; }
// exp(lrelu(z)) = exp2(max(z*L, z*0.2L))  (branchless; valid since L>0)
__device__ __forceinline__ float explrelu(float z) {
    return exp2f(fmaxf(z * LOG2E, z * (NEG_SLOPE * LOG2E)));
}

__device__ __forceinline__ unsigned short f2bf(float f) {
    unsigned int u = __float_as_uint(f);
    unsigned int r = (u + 0x7FFFu + ((u >> 16) & 1u)) >> 16;   // round-nearest-even
    return (unsigned short)r;
}
__device__ __forceinline__ float bf2f(unsigned short u) {
    return __uint_as_float(((unsigned int)u) << 16);
}
__device__ __forceinline__ float bflo(unsigned int u) {       // low ushort -> float
    return __uint_as_float(u << 16);
}
__device__ __forceinline__ float bfhi(unsigned int u) {       // high ushort -> float
    return __uint_as_float(u & 0xFFFF0000u);
}

// ---------------- CSR build ----------------
__global__ void hist_kernel(const int* __restrict__ ei, int* __restrict__ deg) {
    int e = blockIdx.x * blockDim.x + threadIdx.x;
    if (e >= E_TOT) return;
    int d = (e < N_EDGES) ? ei[N_EDGES + e] : (e - N_EDGES);
    atomicAdd(&deg[d], 1);
}

__global__ void scan1_kernel(const int* __restrict__ deg, int* __restrict__ off,
                             int* __restrict__ bsum) {
    __shared__ int s[256];
    int b = blockIdx.x, t = threadIdx.x, g = b * 256 + t;
    int v = (g < N_NODES) ? deg[g] : 0;
    s[t] = v;
    __syncthreads();
    for (int d = 1; d < 256; d <<= 1) {
        int o = (t >= d) ? s[t - d] : 0;
        __syncthreads();
        s[t] += o;
        __syncthreads();
    }
    if (g < N_NODES) off[g] = s[t] - v;
    if (t == 255) bsum[b] = s[t];
}

__global__ void scan2_kernel(int* __restrict__ bsum, int nb) {
    __shared__ int s[256];
    int t = threadIdx.x;
    int v = (t < nb) ? bsum[t] : 0;
    s[t] = v;
    __syncthreads();
    for (int d = 1; d < 256; d <<= 1) {
        int o = (t >= d) ? s[t - d] : 0;
        __syncthreads();
        s[t] += o;
        __syncthreads();
    }
    if (t < nb) bsum[t] = s[t] - v;
}

__global__ void scan3_kernel(int* __restrict__ off, const int* __restrict__ bsum,
                             int* __restrict__ cur) {
    int b = blockIdx.x, t = threadIdx.x, g = b * 256 + t;
    if (g < N_NODES) {
        int v = off[g] + bsum[b];
        off[g] = v;
        cur[g] = v;
    }
    if (g == 0) off[N_NODES] = E_TOT;
}

__global__ void scatter_kernel(const int* __restrict__ ei, int* __restrict__ cur,
                               int* __restrict__ ssrc) {
    int e = blockIdx.x * blockDim.x + threadIdx.x;
    if (e >= E_TOT) return;
    int s, d;
    if (e < N_EDGES) { s = ei[e]; d = ei[N_EDGES + e]; }
    else             { s = d = e - N_EDGES; }
    int pos = atomicAdd(&cur[d], 1);
    ssrc[pos] = s;
}

// ---------------- GEMM1 (tiled, 32x256 tile) + alpha epilogue, bf16 h1 out ---
#define FMA4(accv, av, bv)                                                     \
    accv.x = fmaf(av, bv.x, accv.x); accv.y = fmaf(av, bv.y, accv.y);          \
    accv.z = fmaf(av, bv.z, accv.z); accv.w = fmaf(av, bv.w, accv.w);

__global__ __launch_bounds__(256) void gemm1_tiled(
    const float* __restrict__ x, const float* __restrict__ W1,
    const float* __restrict__ att_s, const float* __restrict__ att_d,
    unsigned short* __restrict__ h1b, float* __restrict__ as1, float* __restrict__ ad1) {
    __shared__ float As[M_BLK1][IN_CH];   // 16 KB
    int t = threadIdx.x;
    int row0 = blockIdx.x * M_BLK1;
#pragma unroll
    for (int i = 0; i < 4; ++i) {
        int f = t + i * 256;
        int r = f >> 5, c4 = (f & 31) * 4;
        int gr = row0 + r; if (gr >= N_NODES) gr = N_NODES - 1;
        *(float4*)&As[r][c4] = *(const float4*)&x[(size_t)gr * IN_CH + c4];
    }
    __syncthreads();
    int col0 = (t & 63) * 4;
    int rbase = (t >> 6) * 8;
    float4 acc[8];
#pragma unroll
    for (int m = 0; m < 8; ++m) acc[m] = make_float4(0.f, 0.f, 0.f, 0.f);

    for (int k = 0; k < IN_CH; k += 4) {
        float4 b0 = *(const float4*)&W1[(k + 0) * 256 + col0];
        float4 b1 = *(const float4*)&W1[(k + 1) * 256 + col0];
        float4 b2 = *(const float4*)&W1[(k + 2) * 256 + col0];
        float4 b3 = *(const float4*)&W1[(k + 3) * 256 + col0];
#pragma unroll
        for (int m = 0; m < 8; ++m) {
            float4 a = *(const float4*)&As[rbase + m][k];
            FMA4(acc[m], a.x, b0);
            FMA4(acc[m], a.y, b1);
            FMA4(acc[m], a.z, b2);
            FMA4(acc[m], a.w, b3);
        }
    }

    float4 s4 = *(const float4*)&att_s[col0];
    float4 d4 = *(const float4*)&att_d[col0];
    int head = col0 >> 5;
#pragma unroll
    for (int m = 0; m < 8; ++m) {
        int gr = row0 + rbase + m;
        if (gr < N_NODES) {
            ushort4 hb;
            hb.x = f2bf(acc[m].x); hb.y = f2bf(acc[m].y);
            hb.z = f2bf(acc[m].z); hb.w = f2bf(acc[m].w);
            *(ushort4*)&h1b[(size_t)gr * 256 + col0] = hb;
            float p = acc[m].x * s4.x + acc[m].y * s4.y + acc[m].z * s4.z + acc[m].w * s4.w;
            float q = acc[m].x * d4.x + acc[m].y * d4.y + acc[m].z * d4.z + acc[m].w * d4.w;
            p += __shfl_xor(p, 1); p += __shfl_xor(p, 2); p += __shfl_xor(p, 4);
            q += __shfl_xor(q, 1); q += __shfl_xor(q, 2); q += __shfl_xor(q, 4);
            if ((t & 7) == 0) {
                as1[gr * HEADS + head] = p;
                ad1[gr * HEADS + head] = q;
            }
        }
    }
}

// ---------------- Aggregate layer 1: dual-edge wide gathers -----------------
__global__ __launch_bounds__(256) void agg1_kernel(
    const int* __restrict__ off, const int* __restrict__ ssrc,
    const unsigned short* __restrict__ h1b, const float* __restrict__ as1,
    const float* __restrict__ ad1, const float* __restrict__ b1,
    unsigned short* __restrict__ houtb) {
    int t = threadIdx.x;
    int lane = t & 63;
    int n = blockIdx.x * 4 + (t >> 6);
    int h    = lane >> 3;     // weight-phase head
    int e8   = lane & 7;      // weight-phase edge slot
    int c    = lane & 31;     // channel group: ushorts [c*8, c*8+8)
    int hh   = c >> 2;        // head of my channel group
    int half = lane >> 5;     // 0: even edges, 1: odd edges
    int start = off[n], end = off[n + 1];
    int last = end - 1;
    float ad_w = ad1[n * HEADS + e8];
    float acc[8];
#pragma unroll
    for (int j = 0; j < 8; ++j) acc[j] = 0.f;
    float den = 0.f;
    int sv = ssrc[min(start + e8, last)];
    int se = __shfl(sv, h);
    float av = as1[se * HEADS + e8];
    for (int i = start; i < end; i += 8) {
        int inext = i + 8;
        int sv_n = ssrc[min(inext + e8, last)];          // prefetch next batch
        int se_n = __shfl(sv_n, h);
        float av_n = as1[se_n * HEADS + e8];
        float wv = explrelu(av + ad_w);                  // 64 weights, one chain
#pragma unroll
        for (int k = 0; k < 4; ++k) {
            int me = 2 * k + half;                       // my edge this step
            float wj = __shfl(wv, me * 8 + hh);
            int   sj = __shfl(sv, me);
            wj = (i + me < end) ? wj : 0.f;              // mask tail (exact)
            uint4 u = *(const uint4*)&h1b[(unsigned)sj * 256 + c * 8];
            den += wj;
            acc[0] = fmaf(wj, bflo(u.x), acc[0]);
            acc[1] = fmaf(wj, bfhi(u.x), acc[1]);
            acc[2] = fmaf(wj, bflo(u.y), acc[2]);
            acc[3] = fmaf(wj, bfhi(u.y), acc[3]);
            acc[4] = fmaf(wj, bflo(u.z), acc[4]);
            acc[5] = fmaf(wj, bfhi(u.z), acc[5]);
            acc[6] = fmaf(wj, bflo(u.w), acc[6]);
            acc[7] = fmaf(wj, bfhi(u.w), acc[7]);
        }
        sv = sv_n; av = av_n;
    }
#pragma unroll
    for (int j = 0; j < 8; ++j) acc[j] += __shfl_xor(acc[j], 32);
    den += __shfl_xor(den, 32);
    if (lane < 32) {
        float r = __builtin_amdgcn_rcpf(den);
        float4 b0 = *(const float4*)&b1[c * 8];
        float4 b4 = *(const float4*)&b1[c * 8 + 4];
        float v0 = fmaf(acc[0], r, b0.x);
        float v1 = fmaf(acc[1], r, b0.y);
        float v2 = fmaf(acc[2], r, b0.z);
        float v3 = fmaf(acc[3], r, b0.w);
        float v4 = fmaf(acc[4], r, b4.x);
        float v5 = fmaf(acc[5], r, b4.y);
        float v6 = fmaf(acc[6], r, b4.z);
        float v7 = fmaf(acc[7], r, b4.w);
        v0 = v0 > 0.f ? v0 : expm1f(v0);
        v1 = v1 > 0.f ? v1 : expm1f(v1);
        v2 = v2 > 0.f ? v2 : expm1f(v2);
        v3 = v3 > 0.f ? v3 : expm1f(v3);
        v4 = v4 > 0.f ? v4 : expm1f(v4);
        v5 = v5 > 0.f ? v5 : expm1f(v5);
        v6 = v6 > 0.f ? v6 : expm1f(v6);
        v7 = v7 > 0.f ? v7 : expm1f(v7);
        uint4 ob;
        ob.x = (unsigned)f2bf(v0) | ((unsigned)f2bf(v1) << 16);
        ob.y = (unsigned)f2bf(v2) | ((unsigned)f2bf(v3) << 16);
        ob.z = (unsigned)f2bf(v4) | ((unsigned)f2bf(v5) << 16);
        ob.w = (unsigned)f2bf(v6) | ((unsigned)f2bf(v7) << 16);
        *(uint4*)&houtb[(unsigned)n * 256 + c * 8] = ob;
    }
}

// ---------------- GEMM2 (tiled, 64x64 tile, bf16 in, 4x4 blocking) ----------
__global__ __launch_bounds__(256) void gemm2_tiled(
    const unsigned short* __restrict__ hinb, const float* __restrict__ W2,
    const float* __restrict__ att_s2, const float* __restrict__ att_d2,
    unsigned short* __restrict__ h2b, float* __restrict__ as2, float* __restrict__ ad2) {
    __shared__ float As[M_BLK][256];   // 64 KB
    int t = threadIdx.x;
    int row0 = blockIdx.x * M_BLK;
#pragma unroll
    for (int i = 0; i < 16; ++i) {
        int f = t + i * 256;
        int r = f >> 6, c4 = (f & 63) * 4;
        int gr = row0 + r; if (gr >= N_NODES) gr = N_NODES - 1;
        ushort4 u = *(const ushort4*)&hinb[(size_t)gr * 256 + c4];
        float4 v = make_float4(bf2f(u.x), bf2f(u.y), bf2f(u.z), bf2f(u.w));
        *(float4*)&As[r][c4] = v;
    }
    __syncthreads();
    int col0 = (t & 15) * 4;
    int rbase = (t >> 4) * 4;
    float4 acc[4];
#pragma unroll
    for (int m = 0; m < 4; ++m) acc[m] = make_float4(0.f, 0.f, 0.f, 0.f);

    for (int k = 0; k < 256; k += 4) {
        float4 b0 = *(const float4*)&W2[(k + 0) * 64 + col0];
        float4 b1 = *(const float4*)&W2[(k + 1) * 64 + col0];
        float4 b2 = *(const float4*)&W2[(k + 2) * 64 + col0];
        float4 b3 = *(const float4*)&W2[(k + 3) * 64 + col0];
#pragma unroll
        for (int m = 0; m < 4; ++m) {
            float4 a = *(const float4*)&As[rbase + m][k];
            FMA4(acc[m], a.x, b0);
            FMA4(acc[m], a.y, b1);
            FMA4(acc[m], a.z, b2);
            FMA4(acc[m], a.w, b3);
        }
    }

    float4 s4 = *(const float4*)&att_s2[col0];
    float4 d4 = *(const float4*)&att_d2[col0];
#pragma unroll
    for (int m = 0; m < 4; ++m) {
        int gr = row0 + rbase + m;
        if (gr < N_NODES) {
            ushort4 hb;
            hb.x = f2bf(acc[m].x); hb.y = f2bf(acc[m].y);
            hb.z = f2bf(acc[m].z); hb.w = f2bf(acc[m].w);
            *(ushort4*)&h2b[(size_t)gr * 64 + col0] = hb;
            float p = acc[m].x * s4.x + acc[m].y * s4.y + acc[m].z * s4.z + acc[m].w * s4.w;
            float q = acc[m].x * d4.x + acc[m].y * d4.y + acc[m].z * d4.z + acc[m].w * d4.w;
            p += __shfl_xor(p, 1); q += __shfl_xor(q, 1);
            p += __shfl_xor(p, 2); q += __shfl_xor(q, 2);
            p += __shfl_xor(p, 4); q += __shfl_xor(q, 4);
            p += __shfl_xor(p, 8); q += __shfl_xor(q, 8);
            if ((t & 15) == 0) { as2[gr] = p; ad2[gr] = q; }
        }
    }
}

// ---------------- Aggregate layer 2: quad-edge wide gathers -----------------
__global__ __launch_bounds__(256) void agg2_kernel(
    const int* __restrict__ off, const int* __restrict__ ssrc,
    const unsigned short* __restrict__ h2b, const float* __restrict__ as2,
    const float* __restrict__ ad2, const float* __restrict__ b2,
    float* __restrict__ out) {
    int t = threadIdx.x;
    int lane = t & 63;
    int e8 = lane & 7;
    int q = lane & 15;        // channels [q*4, q*4+4)
    int quarter = lane >> 4;  // which edge of the 4 per step
    int n = blockIdx.x * 4 + (t >> 6);
    int start = off[n], end = off[n + 1];
    int last = end - 1;
    float adv = ad2[n];
    float acc[4];
#pragma unroll
    for (int j = 0; j < 4; ++j) acc[j] = 0.f;
    float den = 0.f;
    int sv = ssrc[min(start + e8, last)];
    float av = as2[sv];
    for (int i = start; i < end; i += 8) {
        int inext = i + 8;
        int sv_n = ssrc[min(inext + e8, last)];
        float av_n = as2[sv_n];
        float wv = explrelu(av + adv);                   // wv[l] = w(edge l&7)
#pragma unroll
        for (int k = 0; k < 2; ++k) {
            int me = 4 * k + quarter;
            float wj = __shfl(wv, me);
            int   sj = __shfl(sv, me);
            wj = (i + me < end) ? wj : 0.f;              // mask tail (exact)
            uint2 u = *(const uint2*)&h2b[(unsigned)sj * 64 + q * 4];
            den += wj;
            acc[0] = fmaf(wj, bflo(u.x), acc[0]);
            acc[1] = fmaf(wj, bfhi(u.x), acc[1]);
            acc[2] = fmaf(wj, bflo(u.y), acc[2]);
            acc[3] = fmaf(wj, bfhi(u.y), acc[3]);
        }
        sv = sv_n; av = av_n;
    }
#pragma unroll
    for (int j = 0; j < 4; ++j) {
        acc[j] += __shfl_xor(acc[j], 16);
        acc[j] += __shfl_xor(acc[j], 32);
    }
    den += __shfl_xor(den, 16);
    den += __shfl_xor(den, 32);
    if (lane < 16) {
        float r = __builtin_amdgcn_rcpf(den);
        float4 bv = *(const float4*)&b2[q * 4];
        float4 o;
        o.x = fmaf(acc[0], r, bv.x);
        o.y = fmaf(acc[1], r, bv.y);
        o.z = fmaf(acc[2], r, bv.z);
        o.w = fmaf(acc[3], r, bv.w);
        *(float4*)&out[(unsigned)n * 64 + q * 4] = o;
    }
}

extern "C" void kernel_launch(void* const* d_in, const int* in_sizes, int n_in,
                              void* d_out, int out_size, void* d_ws, size_t ws_size,
                              hipStream_t stream) {
    const float* x    = (const float*)d_in[0];
    const int*   ei   = (const int*)d_in[1];
    const float* W1   = (const float*)d_in[2];
    const float* ats1 = (const float*)d_in[3];
    const float* atd1 = (const float*)d_in[4];
    const float* b1   = (const float*)d_in[5];
    const float* W2   = (const float*)d_in[6];
    const float* ats2 = (const float*)d_in[7];
    const float* atd2 = (const float*)d_in[8];
    const float* b2   = (const float*)d_in[9];
    float* out = (float*)d_out;

    char* ws = (char*)d_ws;
    size_t o = 0;
    auto alloc = [&](size_t bytes) { size_t r = o; o = (o + bytes + 255) & ~255UL; return r; };
    unsigned short* h1b   = (unsigned short*)(ws + alloc((size_t)N_NODES * 256 * 2));
    unsigned short* h2inb = (unsigned short*)(ws + alloc((size_t)N_NODES * 256 * 2));
    unsigned short* h2b   = (unsigned short*)(ws + alloc((size_t)N_NODES * 64 * 2));
    float* as1  = (float*)(ws + alloc((size_t)N_NODES * HEADS * 4));
    float* ad1  = (float*)(ws + alloc((size_t)N_NODES * HEADS * 4));
    float* as2  = (float*)(ws + alloc((size_t)N_NODES * 4));
    float* ad2  = (float*)(ws + alloc((size_t)N_NODES * 4));
    int*   deg  = (int*)(ws + alloc((size_t)N_NODES * 4));
    int*   off  = (int*)(ws + alloc((size_t)(N_NODES + 1) * 4));
    int*   cur  = (int*)(ws + alloc((size_t)N_NODES * 4));
    int*   bsum = (int*)(ws + alloc(256 * 4));
    int*   ssrc = (int*)(ws + alloc((size_t)E_TOT * 4));

    (void)hipMemsetAsync(deg, 0, (size_t)N_NODES * 4, stream);
    int eblk = (E_TOT + 255) / 256;
    hist_kernel<<<eblk, 256, 0, stream>>>(ei, deg);
    scan1_kernel<<<NBLK, 256, 0, stream>>>(deg, off, bsum);
    scan2_kernel<<<1, 256, 0, stream>>>(bsum, NBLK);
    scan3_kernel<<<NBLK, 256, 0, stream>>>(off, bsum, cur);
    scatter_kernel<<<eblk, 256, 0, stream>>>(ei, cur, ssrc);

    gemm1_tiled<<<G1BLK, 256, 0, stream>>>(x, W1, ats1, atd1, h1b, as1, ad1);
    agg1_kernel<<<ABLK, 256, 0, stream>>>(off, ssrc, h1b, as1, ad1, b1, h2inb);

    gemm2_tiled<<<GBLK, 256, 0, stream>>>(h2inb, W2, ats2, atd2, h2b, as2, ad2);
    agg2_kernel<<<ABLK, 256, 0, stream>>>(off, ssrc, h2b, as2, ad2, b2, out);
}

// Round 16
// 286.361 us; speedup vs baseline: 1.1664x; 1.0059x over previous
//
#include <hip/hip_runtime.h>
#include <hip/hip_bf16.h>
#include <math.h>

#define N_NODES 50000
#define N_EDGES 800000
#define E_TOT   (N_EDGES + N_NODES)   // 850000 (with self-loops)
#define IN_CH 128
#define HID 32
#define HEADS 8
#define OUT_CH 64
#define NEG_SLOPE 0.2f
#define NBLK 196                      // ceil(50000/256)
#define M_BLK1 32
#define G1BLK 1563                    // ceil(50000/32)
#define M_BLK 64
#define GBLK 782                      // ceil(50000/64)
#define ABLK 12500                    // 50000/4 nodes per 256-thread block
#define LOG2E 1.4426950408889634f

__device__ __forceinline__ float lrelu(float x) { return x > 0.f ? x : NEG_SLOPE * x; }
// exp(lrelu(z)) = exp2(max(z*L, z*0.2L))  (branchless; valid since L>0)
__device__ __forceinline__ float explrelu(float z) {
    return exp2f(fmaxf(z * LOG2E, z * (NEG_SLOPE * LOG2E)));
}

__device__ __forceinline__ unsigned short f2bf(float f) {
    unsigned int u = __float_as_uint(f);
    unsigned int r = (u + 0x7FFFu + ((u >> 16) & 1u)) >> 16;   // round-nearest-even
    return (unsigned short)r;
}
__device__ __forceinline__ float bf2f(unsigned short u) {
    return __uint_as_float(((unsigned int)u) << 16);
}
__device__ __forceinline__ float bflo(unsigned int u) {       // low ushort -> float
    return __uint_as_float(u << 16);
}
__device__ __forceinline__ float bfhi(unsigned int u) {       // high ushort -> float
    return __uint_as_float(u & 0xFFFF0000u);
}

// ---------------- CSR build ----------------
__global__ void hist_kernel(const int* __restrict__ ei, int* __restrict__ deg) {
    int e = blockIdx.x * blockDim.x + threadIdx.x;
    if (e >= E_TOT) return;
    int d = (e < N_EDGES) ? ei[N_EDGES + e] : (e - N_EDGES);
    atomicAdd(&deg[d], 1);
}

__global__ void scan1_kernel(const int* __restrict__ deg, int* __restrict__ off,
                             int* __restrict__ bsum) {
    __shared__ int s[256];
    int b = blockIdx.x, t = threadIdx.x, g = b * 256 + t;
    int v = (g < N_NODES) ? deg[g] : 0;
    s[t] = v;
    __syncthreads();
    for (int d = 1; d < 256; d <<= 1) {
        int o = (t >= d) ? s[t - d] : 0;
        __syncthreads();
        s[t] += o;
        __syncthreads();
    }
    if (g < N_NODES) off[g] = s[t] - v;
    if (t == 255) bsum[b] = s[t];
}

__global__ void scan2_kernel(int* __restrict__ bsum, int nb) {
    __shared__ int s[256];
    int t = threadIdx.x;
    int v = (t < nb) ? bsum[t] : 0;
    s[t] = v;
    __syncthreads();
    for (int d = 1; d < 256; d <<= 1) {
        int o = (t >= d) ? s[t - d] : 0;
        __syncthreads();
        s[t] += o;
        __syncthreads();
    }
    if (t < nb) bsum[t] = s[t] - v;
}

__global__ void scan3_kernel(int* __restrict__ off, const int* __restrict__ bsum,
                             int* __restrict__ cur) {
    int b = blockIdx.x, t = threadIdx.x, g = b * 256 + t;
    if (g < N_NODES) {
        int v = off[g] + bsum[b];
        off[g] = v;
        cur[g] = v;
    }
    if (g == 0) off[N_NODES] = E_TOT;
}

__global__ void scatter_kernel(const int* __restrict__ ei, int* __restrict__ cur,
                               int* __restrict__ ssrc) {
    int e = blockIdx.x * blockDim.x + threadIdx.x;
    if (e >= E_TOT) return;
    int s, d;
    if (e < N_EDGES) { s = ei[e]; d = ei[N_EDGES + e]; }
    else             { s = d = e - N_EDGES; }
    int pos = atomicAdd(&cur[d], 1);
    ssrc[pos] = s;
}

// ---------------- GEMM1 (tiled, 32x256 tile) + alpha epilogue, bf16 h1 out ---
#define FMA4(accv, av, bv)                                                     \
    accv.x = fmaf(av, bv.x, accv.x); accv.y = fmaf(av, bv.y, accv.y);          \
    accv.z = fmaf(av, bv.z, accv.z); accv.w = fmaf(av, bv.w, accv.w);

__global__ __launch_bounds__(256) void gemm1_tiled(
    const float* __restrict__ x, const float* __restrict__ W1,
    const float* __restrict__ att_s, const float* __restrict__ att_d,
    unsigned short* __restrict__ h1b, float* __restrict__ as1, float* __restrict__ ad1) {
    __shared__ float As[M_BLK1][IN_CH];   // 16 KB
    int t = threadIdx.x;
    int row0 = blockIdx.x * M_BLK1;
#pragma unroll
    for (int i = 0; i < 4; ++i) {
        int f = t + i * 256;
        int r = f >> 5, c4 = (f & 31) * 4;
        int gr = row0 + r; if (gr >= N_NODES) gr = N_NODES - 1;
        *(float4*)&As[r][c4] = *(const float4*)&x[(size_t)gr * IN_CH + c4];
    }
    __syncthreads();
    int col0 = (t & 63) * 4;
    int rbase = (t >> 6) * 8;
    float4 acc[8];
#pragma unroll
    for (int m = 0; m < 8; ++m) acc[m] = make_float4(0.f, 0.f, 0.f, 0.f);

    for (int k = 0; k < IN_CH; k += 4) {
        float4 b0 = *(const float4*)&W1[(k + 0) * 256 + col0];
        float4 b1 = *(const float4*)&W1[(k + 1) * 256 + col0];
        float4 b2 = *(const float4*)&W1[(k + 2) * 256 + col0];
        float4 b3 = *(const float4*)&W1[(k + 3) * 256 + col0];
#pragma unroll
        for (int m = 0; m < 8; ++m) {
            float4 a = *(const float4*)&As[rbase + m][k];
            FMA4(acc[m], a.x, b0);
            FMA4(acc[m], a.y, b1);
            FMA4(acc[m], a.z, b2);
            FMA4(acc[m], a.w, b3);
        }
    }

    float4 s4 = *(const float4*)&att_s[col0];
    float4 d4 = *(const float4*)&att_d[col0];
    int head = col0 >> 5;
#pragma unroll
    for (int m = 0; m < 8; ++m) {
        int gr = row0 + rbase + m;
        if (gr < N_NODES) {
            ushort4 hb;
            hb.x = f2bf(acc[m].x); hb.y = f2bf(acc[m].y);
            hb.z = f2bf(acc[m].z); hb.w = f2bf(acc[m].w);
            *(ushort4*)&h1b[(size_t)gr * 256 + col0] = hb;
            float p = acc[m].x * s4.x + acc[m].y * s4.y + acc[m].z * s4.z + acc[m].w * s4.w;
            float q = acc[m].x * d4.x + acc[m].y * d4.y + acc[m].z * d4.z + acc[m].w * d4.w;
            p += __shfl_xor(p, 1); p += __shfl_xor(p, 2); p += __shfl_xor(p, 4);
            q += __shfl_xor(q, 1); q += __shfl_xor(q, 2); q += __shfl_xor(q, 4);
            if ((t & 7) == 0) {
                as1[gr * HEADS + head] = p;
                ad1[gr * HEADS + head] = q;
            }
        }
    }
}

// ---------------- Aggregate layer 1: dual-edge wide gathers, 2-deep pipe ----
// Batch i's four uint4 gathers are issued one batch AHEAD (addresses depend
// only on prefetched sv), so FMAs always consume loads issued a full batch
// earlier. Weights masked to 0 for tail slots (exact).
__global__ __launch_bounds__(256) void agg1_kernel(
    const int* __restrict__ off, const int* __restrict__ ssrc,
    const unsigned short* __restrict__ h1b, const float* __restrict__ as1,
    const float* __restrict__ ad1, const float* __restrict__ b1,
    unsigned short* __restrict__ houtb) {
    int t = threadIdx.x;
    int lane = t & 63;
    int n = blockIdx.x * 4 + (t >> 6);
    int h    = lane >> 3;     // weight-phase head
    int e8   = lane & 7;      // weight-phase edge slot
    int c    = lane & 31;     // channel group: ushorts [c*8, c*8+8)
    int hh   = c >> 2;        // head of my channel group
    int half = lane >> 5;     // 0: even edges, 1: odd edges
    int start = off[n], end = off[n + 1];
    int last = end - 1;
    float ad_w = ad1[n * HEADS + e8];
    float acc[8];
#pragma unroll
    for (int j = 0; j < 8; ++j) acc[j] = 0.f;
    float den = 0.f;
    // batch 0 state + its gathers
    int sv = ssrc[min(start + e8, last)];
    int se = __shfl(sv, h);
    float av = as1[se * HEADS + e8];
    const unsigned short* base = h1b + c * 8;
    uint4 g0 = *(const uint4*)&base[(unsigned)__shfl(sv, 0 + half) * 256];
    uint4 g1 = *(const uint4*)&base[(unsigned)__shfl(sv, 2 + half) * 256];
    uint4 g2 = *(const uint4*)&base[(unsigned)__shfl(sv, 4 + half) * 256];
    uint4 g3 = *(const uint4*)&base[(unsigned)__shfl(sv, 6 + half) * 256];
    for (int i = start; i < end; i += 8) {
        int inext = i + 8;
        // prefetch next batch's srcs + alpha
        int sv_n = ssrc[min(inext + e8, last)];
        int se_n = __shfl(sv_n, h);
        float av_n = as1[se_n * HEADS + e8];
        // issue next batch's gathers now (addresses independent of wv)
        uint4 n0 = *(const uint4*)&base[(unsigned)__shfl(sv_n, 0 + half) * 256];
        uint4 n1 = *(const uint4*)&base[(unsigned)__shfl(sv_n, 2 + half) * 256];
        uint4 n2 = *(const uint4*)&base[(unsigned)__shfl(sv_n, 4 + half) * 256];
        uint4 n3 = *(const uint4*)&base[(unsigned)__shfl(sv_n, 6 + half) * 256];
        // weights for current batch
        float wv = explrelu(av + ad_w);                  // 64 weights, one chain
        float w0 = __shfl(wv, (0 + half) * 8 + hh);
        float w1 = __shfl(wv, (2 + half) * 8 + hh);
        float w2 = __shfl(wv, (4 + half) * 8 + hh);
        float w3 = __shfl(wv, (6 + half) * 8 + hh);
        w0 = (i + 0 + half < end) ? w0 : 0.f;            // mask tail (exact)
        w1 = (i + 2 + half < end) ? w1 : 0.f;
        w2 = (i + 4 + half < end) ? w2 : 0.f;
        w3 = (i + 6 + half < end) ? w3 : 0.f;
        den += w0 + w1 + w2 + w3;
        acc[0] = fmaf(w0, bflo(g0.x), acc[0]); acc[1] = fmaf(w0, bfhi(g0.x), acc[1]);
        acc[2] = fmaf(w0, bflo(g0.y), acc[2]); acc[3] = fmaf(w0, bfhi(g0.y), acc[3]);
        acc[4] = fmaf(w0, bflo(g0.z), acc[4]); acc[5] = fmaf(w0, bfhi(g0.z), acc[5]);
        acc[6] = fmaf(w0, bflo(g0.w), acc[6]); acc[7] = fmaf(w0, bfhi(g0.w), acc[7]);
        acc[0] = fmaf(w1, bflo(g1.x), acc[0]); acc[1] = fmaf(w1, bfhi(g1.x), acc[1]);
        acc[2] = fmaf(w1, bflo(g1.y), acc[2]); acc[3] = fmaf(w1, bfhi(g1.y), acc[3]);
        acc[4] = fmaf(w1, bflo(g1.z), acc[4]); acc[5] = fmaf(w1, bfhi(g1.z), acc[5]);
        acc[6] = fmaf(w1, bflo(g1.w), acc[6]); acc[7] = fmaf(w1, bfhi(g1.w), acc[7]);
        acc[0] = fmaf(w2, bflo(g2.x), acc[0]); acc[1] = fmaf(w2, bfhi(g2.x), acc[1]);
        acc[2] = fmaf(w2, bflo(g2.y), acc[2]); acc[3] = fmaf(w2, bfhi(g2.y), acc[3]);
        acc[4] = fmaf(w2, bflo(g2.z), acc[4]); acc[5] = fmaf(w2, bfhi(g2.z), acc[5]);
        acc[6] = fmaf(w2, bflo(g2.w), acc[6]); acc[7] = fmaf(w2, bfhi(g2.w), acc[7]);
        acc[0] = fmaf(w3, bflo(g3.x), acc[0]); acc[1] = fmaf(w3, bfhi(g3.x), acc[1]);
        acc[2] = fmaf(w3, bflo(g3.y), acc[2]); acc[3] = fmaf(w3, bfhi(g3.y), acc[3]);
        acc[4] = fmaf(w3, bflo(g3.z), acc[4]); acc[5] = fmaf(w3, bfhi(g3.z), acc[5]);
        acc[6] = fmaf(w3, bflo(g3.w), acc[6]); acc[7] = fmaf(w3, bfhi(g3.w), acc[7]);
        g0 = n0; g1 = n1; g2 = n2; g3 = n3;
        sv = sv_n; av = av_n;
    }
#pragma unroll
    for (int j = 0; j < 8; ++j) acc[j] += __shfl_xor(acc[j], 32);
    den += __shfl_xor(den, 32);
    if (lane < 32) {
        float r = __builtin_amdgcn_rcpf(den);
        float4 b0 = *(const float4*)&b1[c * 8];
        float4 b4 = *(const float4*)&b1[c * 8 + 4];
        float v0 = fmaf(acc[0], r, b0.x);
        float v1 = fmaf(acc[1], r, b0.y);
        float v2 = fmaf(acc[2], r, b0.z);
        float v3 = fmaf(acc[3], r, b0.w);
        float v4 = fmaf(acc[4], r, b4.x);
        float v5 = fmaf(acc[5], r, b4.y);
        float v6 = fmaf(acc[6], r, b4.z);
        float v7 = fmaf(acc[7], r, b4.w);
        v0 = v0 > 0.f ? v0 : expm1f(v0);
        v1 = v1 > 0.f ? v1 : expm1f(v1);
        v2 = v2 > 0.f ? v2 : expm1f(v2);
        v3 = v3 > 0.f ? v3 : expm1f(v3);
        v4 = v4 > 0.f ? v4 : expm1f(v4);
        v5 = v5 > 0.f ? v5 : expm1f(v5);
        v6 = v6 > 0.f ? v6 : expm1f(v6);
        v7 = v7 > 0.f ? v7 : expm1f(v7);
        uint4 ob;
        ob.x = (unsigned)f2bf(v0) | ((unsigned)f2bf(v1) << 16);
        ob.y = (unsigned)f2bf(v2) | ((unsigned)f2bf(v3) << 16);
        ob.z = (unsigned)f2bf(v4) | ((unsigned)f2bf(v5) << 16);
        ob.w = (unsigned)f2bf(v6) | ((unsigned)f2bf(v7) << 16);
        *(uint4*)&houtb[(unsigned)n * 256 + c * 8] = ob;
    }
}

// ---------------- GEMM2 (64x64 tile, bf16 LDS = 32 KB, 4x4 blocking) --------
__global__ __launch_bounds__(256) void gemm2_tiled(
    const unsigned short* __restrict__ hinb, const float* __restrict__ W2,
    const float* __restrict__ att_s2, const float* __restrict__ att_d2,
    unsigned short* __restrict__ h2b, float* __restrict__ as2, float* __restrict__ ad2) {
    __shared__ unsigned short As[M_BLK][256];   // 32 KB (raw bf16 copy)
    int t = threadIdx.x;
    int row0 = blockIdx.x * M_BLK;
#pragma unroll
    for (int i = 0; i < 8; ++i) {
        int f = t + i * 256;
        int r = f >> 5, ck = (f & 31) * 8;      // uint4 chunk: 8 ushorts
        int gr = row0 + r; if (gr >= N_NODES) gr = N_NODES - 1;
        *(uint4*)&As[r][ck] = *(const uint4*)&hinb[(size_t)gr * 256 + ck];
    }
    __syncthreads();
    int col0 = (t & 15) * 4;
    int rbase = (t >> 4) * 4;
    float4 acc[4];
#pragma unroll
    for (int m = 0; m < 4; ++m) acc[m] = make_float4(0.f, 0.f, 0.f, 0.f);

    for (int k = 0; k < 256; k += 4) {
        float4 b0 = *(const float4*)&W2[(k + 0) * 64 + col0];
        float4 b1 = *(const float4*)&W2[(k + 1) * 64 + col0];
        float4 b2 = *(const float4*)&W2[(k + 2) * 64 + col0];
        float4 b3 = *(const float4*)&W2[(k + 3) * 64 + col0];
#pragma unroll
        for (int m = 0; m < 4; ++m) {
            uint2 a = *(const uint2*)&As[rbase + m][k];
            float ax = bflo(a.x), ay = bfhi(a.x);
            float az = bflo(a.y), aw = bfhi(a.y);
            FMA4(acc[m], ax, b0);
            FMA4(acc[m], ay, b1);
            FMA4(acc[m], az, b2);
            FMA4(acc[m], aw, b3);
        }
    }

    float4 s4 = *(const float4*)&att_s2[col0];
    float4 d4 = *(const float4*)&att_d2[col0];
#pragma unroll
    for (int m = 0; m < 4; ++m) {
        int gr = row0 + rbase + m;
        if (gr < N_NODES) {
            ushort4 hb;
            hb.x = f2bf(acc[m].x); hb.y = f2bf(acc[m].y);
            hb.z = f2bf(acc[m].z); hb.w = f2bf(acc[m].w);
            *(ushort4*)&h2b[(size_t)gr * 64 + col0] = hb;
            float p = acc[m].x * s4.x + acc[m].y * s4.y + acc[m].z * s4.z + acc[m].w * s4.w;
            float q = acc[m].x * d4.x + acc[m].y * d4.y + acc[m].z * d4.z + acc[m].w * d4.w;
            p += __shfl_xor(p, 1); q += __shfl_xor(q, 1);
            p += __shfl_xor(p, 2); q += __shfl_xor(q, 2);
            p += __shfl_xor(p, 4); q += __shfl_xor(q, 4);
            p += __shfl_xor(p, 8); q += __shfl_xor(q, 8);
            if ((t & 15) == 0) { as2[gr] = p; ad2[gr] = q; }
        }
    }
}

// ---------------- Aggregate layer 2: quad-edge wide gathers -----------------
__global__ __launch_bounds__(256) void agg2_kernel(
    const int* __restrict__ off, const int* __restrict__ ssrc,
    const unsigned short* __restrict__ h2b, const float* __restrict__ as2,
    const float* __restrict__ ad2, const float* __restrict__ b2,
    float* __restrict__ out) {
    int t = threadIdx.x;
    int lane = t & 63;
    int e8 = lane & 7;
    int q = lane & 15;        // channels [q*4, q*4+4)
    int quarter = lane >> 4;  // which edge of the 4 per step
    int n = blockIdx.x * 4 + (t >> 6);
    int start = off[n], end = off[n + 1];
    int last = end - 1;
    float adv = ad2[n];
    float acc[4];
#pragma unroll
    for (int j = 0; j < 4; ++j) acc[j] = 0.f;
    float den = 0.f;
    int sv = ssrc[min(start + e8, last)];
    float av = as2[sv];
    for (int i = start; i < end; i += 8) {
        int inext = i + 8;
        int sv_n = ssrc[min(inext + e8, last)];
        float av_n = as2[sv_n];
        float wv = explrelu(av + adv);                   // wv[l] = w(edge l&7)
#pragma unroll
        for (int k = 0; k < 2; ++k) {
            int me = 4 * k + quarter;
            float wj = __shfl(wv, me);
            int   sj = __shfl(sv, me);
            wj = (i + me < end) ? wj : 0.f;              // mask tail (exact)
            uint2 u = *(const uint2*)&h2b[(unsigned)sj * 64 + q * 4];
            den += wj;
            acc[0] = fmaf(wj, bflo(u.x), acc[0]);
            acc[1] = fmaf(wj, bfhi(u.x), acc[1]);
            acc[2] = fmaf(wj, bflo(u.y), acc[2]);
            acc[3] = fmaf(wj, bfhi(u.y), acc[3]);
        }
        sv = sv_n; av = av_n;
    }
#pragma unroll
    for (int j = 0; j < 4; ++j) {
        acc[j] += __shfl_xor(acc[j], 16);
        acc[j] += __shfl_xor(acc[j], 32);
    }
    den += __shfl_xor(den, 16);
    den += __shfl_xor(den, 32);
    if (lane < 16) {
        float r = __builtin_amdgcn_rcpf(den);
        float4 bv = *(const float4*)&b2[q * 4];
        float4 o;
        o.x = fmaf(acc[0], r, bv.x);
        o.y = fmaf(acc[1], r, bv.y);
        o.z = fmaf(acc[2], r, bv.z);
        o.w = fmaf(acc[3], r, bv.w);
        *(float4*)&out[(unsigned)n * 64 + q * 4] = o;
    }
}

extern "C" void kernel_launch(void* const* d_in, const int* in_sizes, int n_in,
                              void* d_out, int out_size, void* d_ws, size_t ws_size,
                              hipStream_t stream) {
    const float* x    = (const float*)d_in[0];
    const int*   ei   = (const int*)d_in[1];
    const float* W1   = (const float*)d_in[2];
    const float* ats1 = (const float*)d_in[3];
    const float* atd1 = (const float*)d_in[4];
    const float* b1   = (const float*)d_in[5];
    const float* W2   = (const float*)d_in[6];
    const float* ats2 = (const float*)d_in[7];
    const float* atd2 = (const float*)d_in[8];
    const float* b2   = (const float*)d_in[9];
    float* out = (float*)d_out;

    char* ws = (char*)d_ws;
    size_t o = 0;
    auto alloc = [&](size_t bytes) { size_t r = o; o = (o + bytes + 255) & ~255UL; return r; };
    unsigned short* h1b   = (unsigned short*)(ws + alloc((size_t)N_NODES * 256 * 2));
    unsigned short* h2inb = (unsigned short*)(ws + alloc((size_t)N_NODES * 256 * 2));
    unsigned short* h2b   = (unsigned short*)(ws + alloc((size_t)N_NODES * 64 * 2));
    float* as1  = (float*)(ws + alloc((size_t)N_NODES * HEADS * 4));
    float* ad1  = (float*)(ws + alloc((size_t)N_NODES * HEADS * 4));
    float* as2  = (float*)(ws + alloc((size_t)N_NODES * 4));
    float* ad2  = (float*)(ws + alloc((size_t)N_NODES * 4));
    int*   deg  = (int*)(ws + alloc((size_t)N_NODES * 4));
    int*   off  = (int*)(ws + alloc((size_t)(N_NODES + 1) * 4));
    int*   cur  = (int*)(ws + alloc((size_t)N_NODES * 4));
    int*   bsum = (int*)(ws + alloc(256 * 4));
    int*   ssrc = (int*)(ws + alloc((size_t)E_TOT * 4));

    (void)hipMemsetAsync(deg, 0, (size_t)N_NODES * 4, stream);
    int eblk = (E_TOT + 255) / 256;
    hist_kernel<<<eblk, 256, 0, stream>>>(ei, deg);
    scan1_kernel<<<NBLK, 256, 0, stream>>>(deg, off, bsum);
    scan2_kernel<<<1, 256, 0, stream>>>(bsum, NBLK);
    scan3_kernel<<<NBLK, 256, 0, stream>>>(off, bsum, cur);
    scatter_kernel<<<eblk, 256, 0, stream>>>(ei, cur, ssrc);

    gemm1_tiled<<<G1BLK, 256, 0, stream>>>(x, W1, ats1, atd1, h1b, as1, ad1);
    agg1_kernel<<<ABLK, 256, 0, stream>>>(off, ssrc, h1b, as1, ad1, b1, h2inb);

    gemm2_tiled<<<GBLK, 256, 0, stream>>>(h2inb, W2, ats2, atd2, h2b, as2, ad2);
    agg2_kernel<<<ABLK, 256, 0, stream>>>(off, ssrc, h2b, as2, ad2, b2, out);
}

// Round 17
// 280.792 us; speedup vs baseline: 1.1895x; 1.0198x over previous
//
#include <hip/hip_runtime.h>
#include <hip/hip_bf16.h>
#include <math.h>

#define N_NODES 50000
#define N_EDGES 800000
#define E_TOT   (N_EDGES + N_NODES)   // 850000 (with self-loops)
#define IN_CH 128
#define HID 32
#define HEADS 8
#define OUT_CH 64
#define NEG_SLOPE 0.2f
#define NBLK 196                      // ceil(50000/256)
#define G1BLK 3125                    // 50000/16 rows per MFMA block
#define M_BLK 64
#define GBLK 782                      // ceil(50000/64)
#define ABLK 12500                    // 50000/4 nodes per 256-thread block
#define LOG2E 1.4426950408889634f

typedef __attribute__((ext_vector_type(8))) short bf16x8;
typedef __attribute__((ext_vector_type(4))) float f32x4;

__device__ __forceinline__ float lrelu(float x) { return x > 0.f ? x : NEG_SLOPE * x; }
// exp(lrelu(z)) = exp2(max(z*L, z*0.2L))  (branchless; valid since L>0)
__device__ __forceinline__ float explrelu(float z) {
    return exp2f(fmaxf(z * LOG2E, z * (NEG_SLOPE * LOG2E)));
}

__device__ __forceinline__ unsigned short f2bf(float f) {
    unsigned int u = __float_as_uint(f);
    unsigned int r = (u + 0x7FFFu + ((u >> 16) & 1u)) >> 16;   // round-nearest-even
    return (unsigned short)r;
}
__device__ __forceinline__ float bf2f(unsigned short u) {
    return __uint_as_float(((unsigned int)u) << 16);
}
__device__ __forceinline__ float bflo(unsigned int u) {       // low ushort -> float
    return __uint_as_float(u << 16);
}
__device__ __forceinline__ float bfhi(unsigned int u) {       // high ushort -> float
    return __uint_as_float(u & 0xFFFF0000u);
}

// ---------------- CSR build ----------------
__global__ void hist_kernel(const int* __restrict__ ei, int* __restrict__ deg) {
    int e = blockIdx.x * blockDim.x + threadIdx.x;
    if (e >= E_TOT) return;
    int d = (e < N_EDGES) ? ei[N_EDGES + e] : (e - N_EDGES);
    atomicAdd(&deg[d], 1);
}

__global__ void scan1_kernel(const int* __restrict__ deg, int* __restrict__ off,
                             int* __restrict__ bsum) {
    __shared__ int s[256];
    int b = blockIdx.x, t = threadIdx.x, g = b * 256 + t;
    int v = (g < N_NODES) ? deg[g] : 0;
    s[t] = v;
    __syncthreads();
    for (int d = 1; d < 256; d <<= 1) {
        int o = (t >= d) ? s[t - d] : 0;
        __syncthreads();
        s[t] += o;
        __syncthreads();
    }
    if (g < N_NODES) off[g] = s[t] - v;
    if (t == 255) bsum[b] = s[t];
}

__global__ void scan2_kernel(int* __restrict__ bsum, int nb) {
    __shared__ int s[256];
    int t = threadIdx.x;
    int v = (t < nb) ? bsum[t] : 0;
    s[t] = v;
    __syncthreads();
    for (int d = 1; d < 256; d <<= 1) {
        int o = (t >= d) ? s[t - d] : 0;
        __syncthreads();
        s[t] += o;
        __syncthreads();
    }
    if (t < nb) bsum[t] = s[t] - v;
}

__global__ void scan3_kernel(int* __restrict__ off, const int* __restrict__ bsum,
                             int* __restrict__ cur) {
    int b = blockIdx.x, t = threadIdx.x, g = b * 256 + t;
    if (g < N_NODES) {
        int v = off[g] + bsum[b];
        off[g] = v;
        cur[g] = v;
    }
    if (g == 0) off[N_NODES] = E_TOT;
}

__global__ void scatter_kernel(const int* __restrict__ ei, int* __restrict__ cur,
                               int* __restrict__ ssrc) {
    int e = blockIdx.x * blockDim.x + threadIdx.x;
    if (e >= E_TOT) return;
    int s, d;
    if (e < N_EDGES) { s = ei[e]; d = ei[N_EDGES + e]; }
    else             { s = d = e - N_EDGES; }
    int pos = atomicAdd(&cur[d], 1);
    ssrc[pos] = s;
}

// ---------------- W1 transpose + bf16 cast: W1t[col][k] ----------------------
__global__ void w1cast_kernel(const float* __restrict__ W1,
                              unsigned short* __restrict__ W1t) {
    int i = blockIdx.x * 256 + threadIdx.x;    // 32768 elems
    int col = i >> 7, k = i & 127;
    W1t[i] = f2bf(W1[k * 256 + col]);
}

// ---------------- GEMM1 via MFMA (bf16 in, fp32 acc) + alpha epilogue -------
// Block: 4 waves, 16 rows x 256 cols. Wave w: cols [w*64, w*64+64).
// A-frag: lane holds x[row0 + (l&15)][ks*32 + (l>>4)*8 + j]  (fp32->bf16)
// B-frag: lane holds W1t[col][same k range]  (k-contiguous, 16B load)
// D: col = lane&15 (+tile base), row = (lane>>4)*4 + r   [verified mapping]
__global__ __launch_bounds__(256) void gemm1_mfma(
    const float* __restrict__ x, const unsigned short* __restrict__ W1t,
    const float* __restrict__ att_s, const float* __restrict__ att_d,
    unsigned short* __restrict__ h1b, float* __restrict__ as1, float* __restrict__ ad1) {
    int t = threadIdx.x;
    int lane = t & 63;
    int w = t >> 6;
    int lrow = lane & 15;
    int kg = lane >> 4;
    int row0 = blockIdx.x * 16;
    int gr = row0 + lrow;                      // 3125*16 = 50000 exactly
    f32x4 acc0 = {0.f, 0.f, 0.f, 0.f};
    f32x4 acc1 = {0.f, 0.f, 0.f, 0.f};
    f32x4 acc2 = {0.f, 0.f, 0.f, 0.f};
    f32x4 acc3 = {0.f, 0.f, 0.f, 0.f};
#pragma unroll
    for (int ks = 0; ks < 4; ++ks) {
        const float* ap = &x[(size_t)gr * IN_CH + ks * 32 + kg * 8];
        float4 a0 = *(const float4*)ap;
        float4 a1 = *(const float4*)(ap + 4);
        union { bf16x8 v; unsigned int u[4]; } A;
        A.u[0] = ((unsigned)f2bf(a0.y) << 16) | f2bf(a0.x);
        A.u[1] = ((unsigned)f2bf(a0.w) << 16) | f2bf(a0.z);
        A.u[2] = ((unsigned)f2bf(a1.y) << 16) | f2bf(a1.x);
        A.u[3] = ((unsigned)f2bf(a1.w) << 16) | f2bf(a1.z);
        union { bf16x8 v; uint4 u; } B0, B1, B2, B3;
        int kb = ks * 32 + kg * 8;
        B0.u = *(const uint4*)&W1t[(size_t)(w * 64 + 0 * 16 + lrow) * IN_CH + kb];
        B1.u = *(const uint4*)&W1t[(size_t)(w * 64 + 1 * 16 + lrow) * IN_CH + kb];
        B2.u = *(const uint4*)&W1t[(size_t)(w * 64 + 2 * 16 + lrow) * IN_CH + kb];
        B3.u = *(const uint4*)&W1t[(size_t)(w * 64 + 3 * 16 + lrow) * IN_CH + kb];
        acc0 = __builtin_amdgcn_mfma_f32_16x16x32_bf16(A.v, B0.v, acc0, 0, 0, 0);
        acc1 = __builtin_amdgcn_mfma_f32_16x16x32_bf16(A.v, B1.v, acc1, 0, 0, 0);
        acc2 = __builtin_amdgcn_mfma_f32_16x16x32_bf16(A.v, B2.v, acc2, 0, 0, 0);
        acc3 = __builtin_amdgcn_mfma_f32_16x16x32_bf16(A.v, B3.v, acc3, 0, 0, 0);
    }
    // att vectors at my 4 columns
    float s0 = att_s[w * 64 + 0 * 16 + lrow], d0 = att_d[w * 64 + 0 * 16 + lrow];
    float s1 = att_s[w * 64 + 1 * 16 + lrow], d1 = att_d[w * 64 + 1 * 16 + lrow];
    float s2 = att_s[w * 64 + 2 * 16 + lrow], d2 = att_d[w * 64 + 2 * 16 + lrow];
    float s3 = att_s[w * 64 + 3 * 16 + lrow], d3 = att_d[w * 64 + 3 * 16 + lrow];
#pragma unroll
    for (int r = 0; r < 4; ++r) {
        int orow = row0 + kg * 4 + r;
        // h1b stores
        h1b[(size_t)orow * 256 + w * 64 +  0 + lrow] = f2bf(acc0[r]);
        h1b[(size_t)orow * 256 + w * 64 + 16 + lrow] = f2bf(acc1[r]);
        h1b[(size_t)orow * 256 + w * 64 + 32 + lrow] = f2bf(acc2[r]);
        h1b[(size_t)orow * 256 + w * 64 + 48 + lrow] = f2bf(acc3[r]);
        // alpha partials: head 2w from tiles 0,1 ; head 2w+1 from tiles 2,3
        float p0 = acc0[r] * s0 + acc1[r] * s1;
        float q0 = acc0[r] * d0 + acc1[r] * d1;
        float p1 = acc2[r] * s2 + acc3[r] * s3;
        float q1 = acc2[r] * d2 + acc3[r] * d3;
        p0 += __shfl_xor(p0, 1); q0 += __shfl_xor(q0, 1);
        p1 += __shfl_xor(p1, 1); q1 += __shfl_xor(q1, 1);
        p0 += __shfl_xor(p0, 2); q0 += __shfl_xor(q0, 2);
        p1 += __shfl_xor(p1, 2); q1 += __shfl_xor(q1, 2);
        p0 += __shfl_xor(p0, 4); q0 += __shfl_xor(q0, 4);
        p1 += __shfl_xor(p1, 4); q1 += __shfl_xor(q1, 4);
        p0 += __shfl_xor(p0, 8); q0 += __shfl_xor(q0, 8);
        p1 += __shfl_xor(p1, 8); q1 += __shfl_xor(q1, 8);
        if (lrow == 0) {
            as1[orow * HEADS + 2 * w]     = p0;
            ad1[orow * HEADS + 2 * w]     = q0;
            as1[orow * HEADS + 2 * w + 1] = p1;
            ad1[orow * HEADS + 2 * w + 1] = q1;
        }
    }
}

// ---------------- Aggregate layer 1: dual-edge wide gathers, 2-deep pipe ----
__global__ __launch_bounds__(256) void agg1_kernel(
    const int* __restrict__ off, const int* __restrict__ ssrc,
    const unsigned short* __restrict__ h1b, const float* __restrict__ as1,
    const float* __restrict__ ad1, const float* __restrict__ b1,
    unsigned short* __restrict__ houtb) {
    int t = threadIdx.x;
    int lane = t & 63;
    int n = blockIdx.x * 4 + (t >> 6);
    int h    = lane >> 3;     // weight-phase head
    int e8   = lane & 7;      // weight-phase edge slot
    int c    = lane & 31;     // channel group: ushorts [c*8, c*8+8)
    int hh   = c >> 2;        // head of my channel group
    int half = lane >> 5;     // 0: even edges, 1: odd edges
    int start = off[n], end = off[n + 1];
    int last = end - 1;
    float ad_w = ad1[n * HEADS + e8];
    float acc[8];
#pragma unroll
    for (int j = 0; j < 8; ++j) acc[j] = 0.f;
    float den = 0.f;
    int sv = ssrc[min(start + e8, last)];
    int se = __shfl(sv, h);
    float av = as1[se * HEADS + e8];
    const unsigned short* base = h1b + c * 8;
    uint4 g0 = *(const uint4*)&base[(unsigned)__shfl(sv, 0 + half) * 256];
    uint4 g1 = *(const uint4*)&base[(unsigned)__shfl(sv, 2 + half) * 256];
    uint4 g2 = *(const uint4*)&base[(unsigned)__shfl(sv, 4 + half) * 256];
    uint4 g3 = *(const uint4*)&base[(unsigned)__shfl(sv, 6 + half) * 256];
    for (int i = start; i < end; i += 8) {
        int inext = i + 8;
        int sv_n = ssrc[min(inext + e8, last)];
        int se_n = __shfl(sv_n, h);
        float av_n = as1[se_n * HEADS + e8];
        uint4 n0 = *(const uint4*)&base[(unsigned)__shfl(sv_n, 0 + half) * 256];
        uint4 n1 = *(const uint4*)&base[(unsigned)__shfl(sv_n, 2 + half) * 256];
        uint4 n2 = *(const uint4*)&base[(unsigned)__shfl(sv_n, 4 + half) * 256];
        uint4 n3 = *(const uint4*)&base[(unsigned)__shfl(sv_n, 6 + half) * 256];
        float wv = explrelu(av + ad_w);
        float w0 = __shfl(wv, (0 + half) * 8 + hh);
        float w1 = __shfl(wv, (2 + half) * 8 + hh);
        float w2 = __shfl(wv, (4 + half) * 8 + hh);
        float w3 = __shfl(wv, (6 + half) * 8 + hh);
        w0 = (i + 0 + half < end) ? w0 : 0.f;
        w1 = (i + 2 + half < end) ? w1 : 0.f;
        w2 = (i + 4 + half < end) ? w2 : 0.f;
        w3 = (i + 6 + half < end) ? w3 : 0.f;
        den += w0 + w1 + w2 + w3;
        acc[0] = fmaf(w0, bflo(g0.x), acc[0]); acc[1] = fmaf(w0, bfhi(g0.x), acc[1]);
        acc[2] = fmaf(w0, bflo(g0.y), acc[2]); acc[3] = fmaf(w0, bfhi(g0.y), acc[3]);
        acc[4] = fmaf(w0, bflo(g0.z), acc[4]); acc[5] = fmaf(w0, bfhi(g0.z), acc[5]);
        acc[6] = fmaf(w0, bflo(g0.w), acc[6]); acc[7] = fmaf(w0, bfhi(g0.w), acc[7]);
        acc[0] = fmaf(w1, bflo(g1.x), acc[0]); acc[1] = fmaf(w1, bfhi(g1.x), acc[1]);
        acc[2] = fmaf(w1, bflo(g1.y), acc[2]); acc[3] = fmaf(w1, bfhi(g1.y), acc[3]);
        acc[4] = fmaf(w1, bflo(g1.z), acc[4]); acc[5] = fmaf(w1, bfhi(g1.z), acc[5]);
        acc[6] = fmaf(w1, bflo(g1.w), acc[6]); acc[7] = fmaf(w1, bfhi(g1.w), acc[7]);
        acc[0] = fmaf(w2, bflo(g2.x), acc[0]); acc[1] = fmaf(w2, bfhi(g2.x), acc[1]);
        acc[2] = fmaf(w2, bflo(g2.y), acc[2]); acc[3] = fmaf(w2, bfhi(g2.y), acc[3]);
        acc[4] = fmaf(w2, bflo(g2.z), acc[4]); acc[5] = fmaf(w2, bfhi(g2.z), acc[5]);
        acc[6] = fmaf(w2, bflo(g2.w), acc[6]); acc[7] = fmaf(w2, bfhi(g2.w), acc[7]);
        acc[0] = fmaf(w3, bflo(g3.x), acc[0]); acc[1] = fmaf(w3, bfhi(g3.x), acc[1]);
        acc[2] = fmaf(w3, bflo(g3.y), acc[2]); acc[3] = fmaf(w3, bfhi(g3.y), acc[3]);
        acc[4] = fmaf(w3, bflo(g3.z), acc[4]); acc[5] = fmaf(w3, bfhi(g3.z), acc[5]);
        acc[6] = fmaf(w3, bflo(g3.w), acc[6]); acc[7] = fmaf(w3, bfhi(g3.w), acc[7]);
        g0 = n0; g1 = n1; g2 = n2; g3 = n3;
        sv = sv_n; av = av_n;
    }
#pragma unroll
    for (int j = 0; j < 8; ++j) acc[j] += __shfl_xor(acc[j], 32);
    den += __shfl_xor(den, 32);
    if (lane < 32) {
        float r = __builtin_amdgcn_rcpf(den);
        float4 b0 = *(const float4*)&b1[c * 8];
        float4 b4 = *(const float4*)&b1[c * 8 + 4];
        float v0 = fmaf(acc[0], r, b0.x);
        float v1 = fmaf(acc[1], r, b0.y);
        float v2 = fmaf(acc[2], r, b0.z);
        float v3 = fmaf(acc[3], r, b0.w);
        float v4 = fmaf(acc[4], r, b4.x);
        float v5 = fmaf(acc[5], r, b4.y);
        float v6 = fmaf(acc[6], r, b4.z);
        float v7 = fmaf(acc[7], r, b4.w);
        v0 = v0 > 0.f ? v0 : expm1f(v0);
        v1 = v1 > 0.f ? v1 : expm1f(v1);
        v2 = v2 > 0.f ? v2 : expm1f(v2);
        v3 = v3 > 0.f ? v3 : expm1f(v3);
        v4 = v4 > 0.f ? v4 : expm1f(v4);
        v5 = v5 > 0.f ? v5 : expm1f(v5);
        v6 = v6 > 0.f ? v6 : expm1f(v6);
        v7 = v7 > 0.f ? v7 : expm1f(v7);
        uint4 ob;
        ob.x = (unsigned)f2bf(v0) | ((unsigned)f2bf(v1) << 16);
        ob.y = (unsigned)f2bf(v2) | ((unsigned)f2bf(v3) << 16);
        ob.z = (unsigned)f2bf(v4) | ((unsigned)f2bf(v5) << 16);
        ob.w = (unsigned)f2bf(v6) | ((unsigned)f2bf(v7) << 16);
        *(uint4*)&houtb[(unsigned)n * 256 + c * 8] = ob;
    }
}

// ---------------- GEMM2 (64x64 tile, bf16 LDS = 32 KB, 4x4 blocking) --------
#define FMA4(accv, av, bv)                                                     \
    accv.x = fmaf(av, bv.x, accv.x); accv.y = fmaf(av, bv.y, accv.y);          \
    accv.z = fmaf(av, bv.z, accv.z); accv.w = fmaf(av, bv.w, accv.w);

__global__ __launch_bounds__(256) void gemm2_tiled(
    const unsigned short* __restrict__ hinb, const float* __restrict__ W2,
    const float* __restrict__ att_s2, const float* __restrict__ att_d2,
    unsigned short* __restrict__ h2b, float* __restrict__ as2, float* __restrict__ ad2) {
    __shared__ unsigned short As[M_BLK][256];   // 32 KB (raw bf16 copy)
    int t = threadIdx.x;
    int row0 = blockIdx.x * M_BLK;
#pragma unroll
    for (int i = 0; i < 8; ++i) {
        int f = t + i * 256;
        int r = f >> 5, ck = (f & 31) * 8;
        int gr = row0 + r; if (gr >= N_NODES) gr = N_NODES - 1;
        *(uint4*)&As[r][ck] = *(const uint4*)&hinb[(size_t)gr * 256 + ck];
    }
    __syncthreads();
    int col0 = (t & 15) * 4;
    int rbase = (t >> 4) * 4;
    float4 acc[4];
#pragma unroll
    for (int m = 0; m < 4; ++m) acc[m] = make_float4(0.f, 0.f, 0.f, 0.f);

    for (int k = 0; k < 256; k += 4) {
        float4 b0 = *(const float4*)&W2[(k + 0) * 64 + col0];
        float4 b1 = *(const float4*)&W2[(k + 1) * 64 + col0];
        float4 b2 = *(const float4*)&W2[(k + 2) * 64 + col0];
        float4 b3 = *(const float4*)&W2[(k + 3) * 64 + col0];
#pragma unroll
        for (int m = 0; m < 4; ++m) {
            uint2 a = *(const uint2*)&As[rbase + m][k];
            float ax = bflo(a.x), ay = bfhi(a.x);
            float az = bflo(a.y), aw = bfhi(a.y);
            FMA4(acc[m], ax, b0);
            FMA4(acc[m], ay, b1);
            FMA4(acc[m], az, b2);
            FMA4(acc[m], aw, b3);
        }
    }

    float4 s4 = *(const float4*)&att_s2[col0];
    float4 d4 = *(const float4*)&att_d2[col0];
#pragma unroll
    for (int m = 0; m < 4; ++m) {
        int gr = row0 + rbase + m;
        if (gr < N_NODES) {
            ushort4 hb;
            hb.x = f2bf(acc[m].x); hb.y = f2bf(acc[m].y);
            hb.z = f2bf(acc[m].z); hb.w = f2bf(acc[m].w);
            *(ushort4*)&h2b[(size_t)gr * 64 + col0] = hb;
            float p = acc[m].x * s4.x + acc[m].y * s4.y + acc[m].z * s4.z + acc[m].w * s4.w;
            float q = acc[m].x * d4.x + acc[m].y * d4.y + acc[m].z * d4.z + acc[m].w * d4.w;
            p += __shfl_xor(p, 1); q += __shfl_xor(q, 1);
            p += __shfl_xor(p, 2); q += __shfl_xor(q, 2);
            p += __shfl_xor(p, 4); q += __shfl_xor(q, 4);
            p += __shfl_xor(p, 8); q += __shfl_xor(q, 8);
            if ((t & 15) == 0) { as2[gr] = p; ad2[gr] = q; }
        }
    }
}

// ---------------- Aggregate layer 2: quad-edge wide gathers -----------------
__global__ __launch_bounds__(256) void agg2_kernel(
    const int* __restrict__ off, const int* __restrict__ ssrc,
    const unsigned short* __restrict__ h2b, const float* __restrict__ as2,
    const float* __restrict__ ad2, const float* __restrict__ b2,
    float* __restrict__ out) {
    int t = threadIdx.x;
    int lane = t & 63;
    int e8 = lane & 7;
    int q = lane & 15;
    int quarter = lane >> 4;
    int n = blockIdx.x * 4 + (t >> 6);
    int start = off[n], end = off[n + 1];
    int last = end - 1;
    float adv = ad2[n];
    float acc[4];
#pragma unroll
    for (int j = 0; j < 4; ++j) acc[j] = 0.f;
    float den = 0.f;
    int sv = ssrc[min(start + e8, last)];
    float av = as2[sv];
    for (int i = start; i < end; i += 8) {
        int inext = i + 8;
        int sv_n = ssrc[min(inext + e8, last)];
        float av_n = as2[sv_n];
        float wv = explrelu(av + adv);
#pragma unroll
        for (int k = 0; k < 2; ++k) {
            int me = 4 * k + quarter;
            float wj = __shfl(wv, me);
            int   sj = __shfl(sv, me);
            wj = (i + me < end) ? wj : 0.f;
            uint2 u = *(const uint2*)&h2b[(unsigned)sj * 64 + q * 4];
            den += wj;
            acc[0] = fmaf(wj, bflo(u.x), acc[0]);
            acc[1] = fmaf(wj, bfhi(u.x), acc[1]);
            acc[2] = fmaf(wj, bflo(u.y), acc[2]);
            acc[3] = fmaf(wj, bfhi(u.y), acc[3]);
        }
        sv = sv_n; av = av_n;
    }
#pragma unroll
    for (int j = 0; j < 4; ++j) {
        acc[j] += __shfl_xor(acc[j], 16);
        acc[j] += __shfl_xor(acc[j], 32);
    }
    den += __shfl_xor(den, 16);
    den += __shfl_xor(den, 32);
    if (lane < 16) {
        float r = __builtin_amdgcn_rcpf(den);
        float4 bv = *(const float4*)&b2[q * 4];
        float4 o;
        o.x = fmaf(acc[0], r, bv.x);
        o.y = fmaf(acc[1], r, bv.y);
        o.z = fmaf(acc[2], r, bv.z);
        o.w = fmaf(acc[3], r, bv.w);
        *(float4*)&out[(unsigned)n * 64 + q * 4] = o;
    }
}

extern "C" void kernel_launch(void* const* d_in, const int* in_sizes, int n_in,
                              void* d_out, int out_size, void* d_ws, size_t ws_size,
                              hipStream_t stream) {
    const float* x    = (const float*)d_in[0];
    const int*   ei   = (const int*)d_in[1];
    const float* W1   = (const float*)d_in[2];
    const float* ats1 = (const float*)d_in[3];
    const float* atd1 = (const float*)d_in[4];
    const float* b1   = (const float*)d_in[5];
    const float* W2   = (const float*)d_in[6];
    const float* ats2 = (const float*)d_in[7];
    const float* atd2 = (const float*)d_in[8];
    const float* b2   = (const float*)d_in[9];
    float* out = (float*)d_out;

    char* ws = (char*)d_ws;
    size_t o = 0;
    auto alloc = [&](size_t bytes) { size_t r = o; o = (o + bytes + 255) & ~255UL; return r; };
    unsigned short* h1b   = (unsigned short*)(ws + alloc((size_t)N_NODES * 256 * 2));
    unsigned short* h2inb = (unsigned short*)(ws + alloc((size_t)N_NODES * 256 * 2));
    unsigned short* h2b   = (unsigned short*)(ws + alloc((size_t)N_NODES * 64 * 2));
    unsigned short* W1t   = (unsigned short*)(ws + alloc((size_t)256 * 128 * 2));
    float* as1  = (float*)(ws + alloc((size_t)N_NODES * HEADS * 4));
    float* ad1  = (float*)(ws + alloc((size_t)N_NODES * HEADS * 4));
    float* as2  = (float*)(ws + alloc((size_t)N_NODES * 4));
    float* ad2  = (float*)(ws + alloc((size_t)N_NODES * 4));
    int*   deg  = (int*)(ws + alloc((size_t)N_NODES * 4));
    int*   off  = (int*)(ws + alloc((size_t)(N_NODES + 1) * 4));
    int*   cur  = (int*)(ws + alloc((size_t)N_NODES * 4));
    int*   bsum = (int*)(ws + alloc(256 * 4));
    int*   ssrc = (int*)(ws + alloc((size_t)E_TOT * 4));

    (void)hipMemsetAsync(deg, 0, (size_t)N_NODES * 4, stream);
    int eblk = (E_TOT + 255) / 256;
    hist_kernel<<<eblk, 256, 0, stream>>>(ei, deg);
    scan1_kernel<<<NBLK, 256, 0, stream>>>(deg, off, bsum);
    scan2_kernel<<<1, 256, 0, stream>>>(bsum, NBLK);
    scan3_kernel<<<NBLK, 256, 0, stream>>>(off, bsum, cur);
    scatter_kernel<<<eblk, 256, 0, stream>>>(ei, cur, ssrc);

    w1cast_kernel<<<128, 256, 0, stream>>>(W1, W1t);
    gemm1_mfma<<<G1BLK, 256, 0, stream>>>(x, W1t, ats1, atd1, h1b, as1, ad1);
    agg1_kernel<<<ABLK, 256, 0, stream>>>(off, ssrc, h1b, as1, ad1, b1, h2inb);

    gemm2_tiled<<<GBLK, 256, 0, stream>>>(h2inb, W2, ats2, atd2, h2b, as2, ad2);
    agg2_kernel<<<ABLK, 256, 0, stream>>>(off, ssrc, h2b, as2, ad2, b2, out);
}

// Round 18
// 269.379 us; speedup vs baseline: 1.2399x; 1.0424x over previous
//
#include <hip/hip_runtime.h>
#include <hip/hip_bf16.h>
#include <math.h>

#define N_NODES 50000
#define N_EDGES 800000
#define E_TOT   (N_EDGES + N_NODES)   // 850000 (with self-loops)
#define IN_CH 128
#define HID 32
#define HEADS 8
#define OUT_CH 64
#define NEG_SLOPE 0.2f
#define NBLK 196                      // ceil(50000/256)
#define G1BLK 3125                    // 50000/16 rows per MFMA block
#define G2BLK 782                     // ceil(50000/64)
#define ABLK 12500                    // 50000/4 nodes per 256-thread block
#define LOG2E 1.4426950408889634f

typedef __attribute__((ext_vector_type(8))) short bf16x8;
typedef __attribute__((ext_vector_type(4))) float f32x4;

__device__ __forceinline__ float lrelu(float x) { return x > 0.f ? x : NEG_SLOPE * x; }
// exp(lrelu(z)) = exp2(max(z*L, z*0.2L))  (branchless; valid since L>0)
__device__ __forceinline__ float explrelu(float z) {
    return exp2f(fmaxf(z * LOG2E, z * (NEG_SLOPE * LOG2E)));
}

__device__ __forceinline__ unsigned short f2bf(float f) {
    unsigned int u = __float_as_uint(f);
    unsigned int r = (u + 0x7FFFu + ((u >> 16) & 1u)) >> 16;   // round-nearest-even
    return (unsigned short)r;
}
__device__ __forceinline__ float bf2f(unsigned short u) {
    return __uint_as_float(((unsigned int)u) << 16);
}
__device__ __forceinline__ float bflo(unsigned int u) {       // low ushort -> float
    return __uint_as_float(u << 16);
}
__device__ __forceinline__ float bfhi(unsigned int u) {       // high ushort -> float
    return __uint_as_float(u & 0xFFFF0000u);
}

// ---------------- CSR build ----------------
__global__ void hist_kernel(const int* __restrict__ ei, int* __restrict__ deg) {
    int e = blockIdx.x * blockDim.x + threadIdx.x;
    if (e >= E_TOT) return;
    int d = (e < N_EDGES) ? ei[N_EDGES + e] : (e - N_EDGES);
    atomicAdd(&deg[d], 1);
}

__global__ void scan1_kernel(const int* __restrict__ deg, int* __restrict__ off,
                             int* __restrict__ bsum) {
    __shared__ int s[256];
    int b = blockIdx.x, t = threadIdx.x, g = b * 256 + t;
    int v = (g < N_NODES) ? deg[g] : 0;
    s[t] = v;
    __syncthreads();
    for (int d = 1; d < 256; d <<= 1) {
        int o = (t >= d) ? s[t - d] : 0;
        __syncthreads();
        s[t] += o;
        __syncthreads();
    }
    if (g < N_NODES) off[g] = s[t] - v;
    if (t == 255) bsum[b] = s[t];
}

__global__ void scan2_kernel(int* __restrict__ bsum, int nb) {
    __shared__ int s[256];
    int t = threadIdx.x;
    int v = (t < nb) ? bsum[t] : 0;
    s[t] = v;
    __syncthreads();
    for (int d = 1; d < 256; d <<= 1) {
        int o = (t >= d) ? s[t - d] : 0;
        __syncthreads();
        s[t] += o;
        __syncthreads();
    }
    if (t < nb) bsum[t] = s[t] - v;
}

__global__ void scan3_kernel(int* __restrict__ off, const int* __restrict__ bsum,
                             int* __restrict__ cur) {
    int b = blockIdx.x, t = threadIdx.x, g = b * 256 + t;
    if (g < N_NODES) {
        int v = off[g] + bsum[b];
        off[g] = v;
        cur[g] = v;
    }
    if (g == 0) off[N_NODES] = E_TOT;
}

__global__ void scatter_kernel(const int* __restrict__ ei, int* __restrict__ cur,
                               int* __restrict__ ssrc) {
    int e = blockIdx.x * blockDim.x + threadIdx.x;
    if (e >= E_TOT) return;
    int s, d;
    if (e < N_EDGES) { s = ei[e]; d = ei[N_EDGES + e]; }
    else             { s = d = e - N_EDGES; }
    int pos = atomicAdd(&cur[d], 1);
    ssrc[pos] = s;
}

// ---------------- W1 transpose + bf16 cast: W1t[col][k] ----------------------
__global__ void w1cast_kernel(const float* __restrict__ W1,
                              unsigned short* __restrict__ W1t) {
    int i = blockIdx.x * 256 + threadIdx.x;    // 32768 elems
    int col = i >> 7, k = i & 127;
    W1t[i] = f2bf(W1[k * 256 + col]);
}

// ---------------- W2 transpose + bf16 cast: W2t[col][k] ----------------------
__global__ void w2cast_kernel(const float* __restrict__ W2,
                              unsigned short* __restrict__ W2t) {
    int i = blockIdx.x * 256 + threadIdx.x;    // 16384 elems
    int col = i >> 8, k = i & 255;
    W2t[i] = f2bf(W2[k * 64 + col]);
}

// ---------------- GEMM1 via MFMA (bf16 in, fp32 acc) + alpha epilogue -------
__global__ __launch_bounds__(256) void gemm1_mfma(
    const float* __restrict__ x, const unsigned short* __restrict__ W1t,
    const float* __restrict__ att_s, const float* __restrict__ att_d,
    unsigned short* __restrict__ h1b, float* __restrict__ as1, float* __restrict__ ad1) {
    int t = threadIdx.x;
    int lane = t & 63;
    int w = t >> 6;
    int lrow = lane & 15;
    int kg = lane >> 4;
    int row0 = blockIdx.x * 16;
    int gr = row0 + lrow;                      // 3125*16 = 50000 exactly
    f32x4 acc0 = {0.f, 0.f, 0.f, 0.f};
    f32x4 acc1 = {0.f, 0.f, 0.f, 0.f};
    f32x4 acc2 = {0.f, 0.f, 0.f, 0.f};
    f32x4 acc3 = {0.f, 0.f, 0.f, 0.f};
#pragma unroll
    for (int ks = 0; ks < 4; ++ks) {
        const float* ap = &x[(size_t)gr * IN_CH + ks * 32 + kg * 8];
        float4 a0 = *(const float4*)ap;
        float4 a1 = *(const float4*)(ap + 4);
        union { bf16x8 v; unsigned int u[4]; } A;
        A.u[0] = ((unsigned)f2bf(a0.y) << 16) | f2bf(a0.x);
        A.u[1] = ((unsigned)f2bf(a0.w) << 16) | f2bf(a0.z);
        A.u[2] = ((unsigned)f2bf(a1.y) << 16) | f2bf(a1.x);
        A.u[3] = ((unsigned)f2bf(a1.w) << 16) | f2bf(a1.z);
        union { bf16x8 v; uint4 u; } B0, B1, B2, B3;
        int kb = ks * 32 + kg * 8;
        B0.u = *(const uint4*)&W1t[(size_t)(w * 64 + 0 * 16 + lrow) * IN_CH + kb];
        B1.u = *(const uint4*)&W1t[(size_t)(w * 64 + 1 * 16 + lrow) * IN_CH + kb];
        B2.u = *(const uint4*)&W1t[(size_t)(w * 64 + 2 * 16 + lrow) * IN_CH + kb];
        B3.u = *(const uint4*)&W1t[(size_t)(w * 64 + 3 * 16 + lrow) * IN_CH + kb];
        acc0 = __builtin_amdgcn_mfma_f32_16x16x32_bf16(A.v, B0.v, acc0, 0, 0, 0);
        acc1 = __builtin_amdgcn_mfma_f32_16x16x32_bf16(A.v, B1.v, acc1, 0, 0, 0);
        acc2 = __builtin_amdgcn_mfma_f32_16x16x32_bf16(A.v, B2.v, acc2, 0, 0, 0);
        acc3 = __builtin_amdgcn_mfma_f32_16x16x32_bf16(A.v, B3.v, acc3, 0, 0, 0);
    }
    float s0 = att_s[w * 64 + 0 * 16 + lrow], d0 = att_d[w * 64 + 0 * 16 + lrow];
    float s1 = att_s[w * 64 + 1 * 16 + lrow], d1 = att_d[w * 64 + 1 * 16 + lrow];
    float s2 = att_s[w * 64 + 2 * 16 + lrow], d2 = att_d[w * 64 + 2 * 16 + lrow];
    float s3 = att_s[w * 64 + 3 * 16 + lrow], d3 = att_d[w * 64 + 3 * 16 + lrow];
#pragma unroll
    for (int r = 0; r < 4; ++r) {
        int orow = row0 + kg * 4 + r;
        h1b[(size_t)orow * 256 + w * 64 +  0 + lrow] = f2bf(acc0[r]);
        h1b[(size_t)orow * 256 + w * 64 + 16 + lrow] = f2bf(acc1[r]);
        h1b[(size_t)orow * 256 + w * 64 + 32 + lrow] = f2bf(acc2[r]);
        h1b[(size_t)orow * 256 + w * 64 + 48 + lrow] = f2bf(acc3[r]);
        float p0 = acc0[r] * s0 + acc1[r] * s1;
        float q0 = acc0[r] * d0 + acc1[r] * d1;
        float p1 = acc2[r] * s2 + acc3[r] * s3;
        float q1 = acc2[r] * d2 + acc3[r] * d3;
        p0 += __shfl_xor(p0, 1); q0 += __shfl_xor(q0, 1);
        p1 += __shfl_xor(p1, 1); q1 += __shfl_xor(q1, 1);
        p0 += __shfl_xor(p0, 2); q0 += __shfl_xor(q0, 2);
        p1 += __shfl_xor(p1, 2); q1 += __shfl_xor(q1, 2);
        p0 += __shfl_xor(p0, 4); q0 += __shfl_xor(q0, 4);
        p1 += __shfl_xor(p1, 4); q1 += __shfl_xor(q1, 4);
        p0 += __shfl_xor(p0, 8); q0 += __shfl_xor(q0, 8);
        p1 += __shfl_xor(p1, 8); q1 += __shfl_xor(q1, 8);
        if (lrow == 0) {
            as1[orow * HEADS + 2 * w]     = p0;
            ad1[orow * HEADS + 2 * w]     = q0;
            as1[orow * HEADS + 2 * w + 1] = p1;
            ad1[orow * HEADS + 2 * w + 1] = q1;
        }
    }
}

// ---------------- Aggregate layer 1: dual-edge wide gathers, 2-deep pipe ----
__global__ __launch_bounds__(256) void agg1_kernel(
    const int* __restrict__ off, const int* __restrict__ ssrc,
    const unsigned short* __restrict__ h1b, const float* __restrict__ as1,
    const float* __restrict__ ad1, const float* __restrict__ b1,
    unsigned short* __restrict__ houtb) {
    int t = threadIdx.x;
    int lane = t & 63;
    int n = blockIdx.x * 4 + (t >> 6);
    int h    = lane >> 3;     // weight-phase head
    int e8   = lane & 7;      // weight-phase edge slot
    int c    = lane & 31;     // channel group: ushorts [c*8, c*8+8)
    int hh   = c >> 2;        // head of my channel group
    int half = lane >> 5;     // 0: even edges, 1: odd edges
    int start = off[n], end = off[n + 1];
    int last = end - 1;
    float ad_w = ad1[n * HEADS + e8];
    float acc[8];
#pragma unroll
    for (int j = 0; j < 8; ++j) acc[j] = 0.f;
    float den = 0.f;
    int sv = ssrc[min(start + e8, last)];
    int se = __shfl(sv, h);
    float av = as1[se * HEADS + e8];
    const unsigned short* base = h1b + c * 8;
    uint4 g0 = *(const uint4*)&base[(unsigned)__shfl(sv, 0 + half) * 256];
    uint4 g1 = *(const uint4*)&base[(unsigned)__shfl(sv, 2 + half) * 256];
    uint4 g2 = *(const uint4*)&base[(unsigned)__shfl(sv, 4 + half) * 256];
    uint4 g3 = *(const uint4*)&base[(unsigned)__shfl(sv, 6 + half) * 256];
    for (int i = start; i < end; i += 8) {
        int inext = i + 8;
        int sv_n = ssrc[min(inext + e8, last)];
        int se_n = __shfl(sv_n, h);
        float av_n = as1[se_n * HEADS + e8];
        uint4 n0 = *(const uint4*)&base[(unsigned)__shfl(sv_n, 0 + half) * 256];
        uint4 n1 = *(const uint4*)&base[(unsigned)__shfl(sv_n, 2 + half) * 256];
        uint4 n2 = *(const uint4*)&base[(unsigned)__shfl(sv_n, 4 + half) * 256];
        uint4 n3 = *(const uint4*)&base[(unsigned)__shfl(sv_n, 6 + half) * 256];
        float wv = explrelu(av + ad_w);
        float w0 = __shfl(wv, (0 + half) * 8 + hh);
        float w1 = __shfl(wv, (2 + half) * 8 + hh);
        float w2 = __shfl(wv, (4 + half) * 8 + hh);
        float w3 = __shfl(wv, (6 + half) * 8 + hh);
        w0 = (i + 0 + half < end) ? w0 : 0.f;
        w1 = (i + 2 + half < end) ? w1 : 0.f;
        w2 = (i + 4 + half < end) ? w2 : 0.f;
        w3 = (i + 6 + half < end) ? w3 : 0.f;
        den += w0 + w1 + w2 + w3;
        acc[0] = fmaf(w0, bflo(g0.x), acc[0]); acc[1] = fmaf(w0, bfhi(g0.x), acc[1]);
        acc[2] = fmaf(w0, bflo(g0.y), acc[2]); acc[3] = fmaf(w0, bfhi(g0.y), acc[3]);
        acc[4] = fmaf(w0, bflo(g0.z), acc[4]); acc[5] = fmaf(w0, bfhi(g0.z), acc[5]);
        acc[6] = fmaf(w0, bflo(g0.w), acc[6]); acc[7] = fmaf(w0, bfhi(g0.w), acc[7]);
        acc[0] = fmaf(w1, bflo(g1.x), acc[0]); acc[1] = fmaf(w1, bfhi(g1.x), acc[1]);
        acc[2] = fmaf(w1, bflo(g1.y), acc[2]); acc[3] = fmaf(w1, bfhi(g1.y), acc[3]);
        acc[4] = fmaf(w1, bflo(g1.z), acc[4]); acc[5] = fmaf(w1, bfhi(g1.z), acc[5]);
        acc[6] = fmaf(w1, bflo(g1.w), acc[6]); acc[7] = fmaf(w1, bfhi(g1.w), acc[7]);
        acc[0] = fmaf(w2, bflo(g2.x), acc[0]); acc[1] = fmaf(w2, bfhi(g2.x), acc[1]);
        acc[2] = fmaf(w2, bflo(g2.y), acc[2]); acc[3] = fmaf(w2, bfhi(g2.y), acc[3]);
        acc[4] = fmaf(w2, bflo(g2.z), acc[4]); acc[5] = fmaf(w2, bfhi(g2.z), acc[5]);
        acc[6] = fmaf(w2, bflo(g2.w), acc[6]); acc[7] = fmaf(w2, bfhi(g2.w), acc[7]);
        acc[0] = fmaf(w3, bflo(g3.x), acc[0]); acc[1] = fmaf(w3, bfhi(g3.x), acc[1]);
        acc[2] = fmaf(w3, bflo(g3.y), acc[2]); acc[3] = fmaf(w3, bfhi(g3.y), acc[3]);
        acc[4] = fmaf(w3, bflo(g3.z), acc[4]); acc[5] = fmaf(w3, bfhi(g3.z), acc[5]);
        acc[6] = fmaf(w3, bflo(g3.w), acc[6]); acc[7] = fmaf(w3, bfhi(g3.w), acc[7]);
        g0 = n0; g1 = n1; g2 = n2; g3 = n3;
        sv = sv_n; av = av_n;
    }
#pragma unroll
    for (int j = 0; j < 8; ++j) acc[j] += __shfl_xor(acc[j], 32);
    den += __shfl_xor(den, 32);
    if (lane < 32) {
        float r = __builtin_amdgcn_rcpf(den);
        float4 b0 = *(const float4*)&b1[c * 8];
        float4 b4 = *(const float4*)&b1[c * 8 + 4];
        float v0 = fmaf(acc[0], r, b0.x);
        float v1 = fmaf(acc[1], r, b0.y);
        float v2 = fmaf(acc[2], r, b0.z);
        float v3 = fmaf(acc[3], r, b0.w);
        float v4 = fmaf(acc[4], r, b4.x);
        float v5 = fmaf(acc[5], r, b4.y);
        float v6 = fmaf(acc[6], r, b4.z);
        float v7 = fmaf(acc[7], r, b4.w);
        v0 = v0 > 0.f ? v0 : expm1f(v0);
        v1 = v1 > 0.f ? v1 : expm1f(v1);
        v2 = v2 > 0.f ? v2 : expm1f(v2);
        v3 = v3 > 0.f ? v3 : expm1f(v3);
        v4 = v4 > 0.f ? v4 : expm1f(v4);
        v5 = v5 > 0.f ? v5 : expm1f(v5);
        v6 = v6 > 0.f ? v6 : expm1f(v6);
        v7 = v7 > 0.f ? v7 : expm1f(v7);
        uint4 ob;
        ob.x = (unsigned)f2bf(v0) | ((unsigned)f2bf(v1) << 16);
        ob.y = (unsigned)f2bf(v2) | ((unsigned)f2bf(v3) << 16);
        ob.z = (unsigned)f2bf(v4) | ((unsigned)f2bf(v5) << 16);
        ob.w = (unsigned)f2bf(v6) | ((unsigned)f2bf(v7) << 16);
        *(uint4*)&houtb[(unsigned)n * 256 + c * 8] = ob;
    }
}

// ---------------- GEMM2 via MFMA (bf16 in, fp32 acc) + alpha epilogue -------
// Block: 4 waves; wave w owns rows [blk*64 + w*16, +16), all 64 cols (4 tiles).
// A-frag: lane holds hinb[row][ks*32 + (l>>4)*8 + j] (already bf16).
// B-frag: W2t[col][k] k-contiguous. D: col=lane&15, row=(lane>>4)*4+r.
__global__ __launch_bounds__(256) void gemm2_mfma(
    const unsigned short* __restrict__ hinb, const unsigned short* __restrict__ W2t,
    const float* __restrict__ att_s2, const float* __restrict__ att_d2,
    unsigned short* __restrict__ h2b, float* __restrict__ as2, float* __restrict__ ad2) {
    int t = threadIdx.x;
    int lane = t & 63;
    int w = t >> 6;
    int lrow = lane & 15;
    int kg = lane >> 4;
    int row0 = blockIdx.x * 64 + w * 16;
    int gr = min(row0 + lrow, N_NODES - 1);    // clamp loads (last block partial)
    f32x4 acc0 = {0.f, 0.f, 0.f, 0.f};
    f32x4 acc1 = {0.f, 0.f, 0.f, 0.f};
    f32x4 acc2 = {0.f, 0.f, 0.f, 0.f};
    f32x4 acc3 = {0.f, 0.f, 0.f, 0.f};
#pragma unroll
    for (int ks = 0; ks < 8; ++ks) {
        int kb = ks * 32 + kg * 8;
        union { bf16x8 v; uint4 u; } A, B0, B1, B2, B3;
        A.u  = *(const uint4*)&hinb[(size_t)gr * 256 + kb];
        B0.u = *(const uint4*)&W2t[(size_t)(0 * 16 + lrow) * 256 + kb];
        B1.u = *(const uint4*)&W2t[(size_t)(1 * 16 + lrow) * 256 + kb];
        B2.u = *(const uint4*)&W2t[(size_t)(2 * 16 + lrow) * 256 + kb];
        B3.u = *(const uint4*)&W2t[(size_t)(3 * 16 + lrow) * 256 + kb];
        acc0 = __builtin_amdgcn_mfma_f32_16x16x32_bf16(A.v, B0.v, acc0, 0, 0, 0);
        acc1 = __builtin_amdgcn_mfma_f32_16x16x32_bf16(A.v, B1.v, acc1, 0, 0, 0);
        acc2 = __builtin_amdgcn_mfma_f32_16x16x32_bf16(A.v, B2.v, acc2, 0, 0, 0);
        acc3 = __builtin_amdgcn_mfma_f32_16x16x32_bf16(A.v, B3.v, acc3, 0, 0, 0);
    }
    float s0 = att_s2[ 0 + lrow], d0 = att_d2[ 0 + lrow];
    float s1 = att_s2[16 + lrow], d1 = att_d2[16 + lrow];
    float s2 = att_s2[32 + lrow], d2 = att_d2[32 + lrow];
    float s3 = att_s2[48 + lrow], d3 = att_d2[48 + lrow];
#pragma unroll
    for (int r = 0; r < 4; ++r) {
        int orow = row0 + kg * 4 + r;
        float p = acc0[r] * s0 + acc1[r] * s1 + acc2[r] * s2 + acc3[r] * s3;
        float q = acc0[r] * d0 + acc1[r] * d1 + acc2[r] * d2 + acc3[r] * d3;
        p += __shfl_xor(p, 1); q += __shfl_xor(q, 1);
        p += __shfl_xor(p, 2); q += __shfl_xor(q, 2);
        p += __shfl_xor(p, 4); q += __shfl_xor(q, 4);
        p += __shfl_xor(p, 8); q += __shfl_xor(q, 8);
        if (orow < N_NODES) {
            h2b[(size_t)orow * 64 +  0 + lrow] = f2bf(acc0[r]);
            h2b[(size_t)orow * 64 + 16 + lrow] = f2bf(acc1[r]);
            h2b[(size_t)orow * 64 + 32 + lrow] = f2bf(acc2[r]);
            h2b[(size_t)orow * 64 + 48 + lrow] = f2bf(acc3[r]);
            if (lrow == 0) { as2[orow] = p; ad2[orow] = q; }
        }
    }
}

// ---------------- Aggregate layer 2: quad-edge wide gathers -----------------
__global__ __launch_bounds__(256) void agg2_kernel(
    const int* __restrict__ off, const int* __restrict__ ssrc,
    const unsigned short* __restrict__ h2b, const float* __restrict__ as2,
    const float* __restrict__ ad2, const float* __restrict__ b2,
    float* __restrict__ out) {
    int t = threadIdx.x;
    int lane = t & 63;
    int e8 = lane & 7;
    int q = lane & 15;
    int quarter = lane >> 4;
    int n = blockIdx.x * 4 + (t >> 6);
    int start = off[n], end = off[n + 1];
    int last = end - 1;
    float adv = ad2[n];
    float acc[4];
#pragma unroll
    for (int j = 0; j < 4; ++j) acc[j] = 0.f;
    float den = 0.f;
    int sv = ssrc[min(start + e8, last)];
    float av = as2[sv];
    for (int i = start; i < end; i += 8) {
        int inext = i + 8;
        int sv_n = ssrc[min(inext + e8, last)];
        float av_n = as2[sv_n];
        float wv = explrelu(av + adv);
#pragma unroll
        for (int k = 0; k < 2; ++k) {
            int me = 4 * k + quarter;
            float wj = __shfl(wv, me);
            int   sj = __shfl(sv, me);
            wj = (i + me < end) ? wj : 0.f;
            uint2 u = *(const uint2*)&h2b[(unsigned)sj * 64 + q * 4];
            den += wj;
            acc[0] = fmaf(wj, bflo(u.x), acc[0]);
            acc[1] = fmaf(wj, bfhi(u.x), acc[1]);
            acc[2] = fmaf(wj, bflo(u.y), acc[2]);
            acc[3] = fmaf(wj, bfhi(u.y), acc[3]);
        }
        sv = sv_n; av = av_n;
    }
#pragma unroll
    for (int j = 0; j < 4; ++j) {
        acc[j] += __shfl_xor(acc[j], 16);
        acc[j] += __shfl_xor(acc[j], 32);
    }
    den += __shfl_xor(den, 16);
    den += __shfl_xor(den, 32);
    if (lane < 16) {
        float r = __builtin_amdgcn_rcpf(den);
        float4 bv = *(const float4*)&b2[q * 4];
        float4 o;
        o.x = fmaf(acc[0], r, bv.x);
        o.y = fmaf(acc[1], r, bv.y);
        o.z = fmaf(acc[2], r, bv.z);
        o.w = fmaf(acc[3], r, bv.w);
        *(float4*)&out[(unsigned)n * 64 + q * 4] = o;
    }
}

extern "C" void kernel_launch(void* const* d_in, const int* in_sizes, int n_in,
                              void* d_out, int out_size, void* d_ws, size_t ws_size,
                              hipStream_t stream) {
    const float* x    = (const float*)d_in[0];
    const int*   ei   = (const int*)d_in[1];
    const float* W1   = (const float*)d_in[2];
    const float* ats1 = (const float*)d_in[3];
    const float* atd1 = (const float*)d_in[4];
    const float* b1   = (const float*)d_in[5];
    const float* W2   = (const float*)d_in[6];
    const float* ats2 = (const float*)d_in[7];
    const float* atd2 = (const float*)d_in[8];
    const float* b2   = (const float*)d_in[9];
    float* out = (float*)d_out;

    char* ws = (char*)d_ws;
    size_t o = 0;
    auto alloc = [&](size_t bytes) { size_t r = o; o = (o + bytes + 255) & ~255UL; return r; };
    unsigned short* h1b   = (unsigned short*)(ws + alloc((size_t)N_NODES * 256 * 2));
    unsigned short* h2inb = (unsigned short*)(ws + alloc((size_t)N_NODES * 256 * 2));
    unsigned short* h2b   = (unsigned short*)(ws + alloc((size_t)N_NODES * 64 * 2));
    unsigned short* W1t   = (unsigned short*)(ws + alloc((size_t)256 * 128 * 2));
    unsigned short* W2t   = (unsigned short*)(ws + alloc((size_t)64 * 256 * 2));
    float* as1  = (float*)(ws + alloc((size_t)N_NODES * HEADS * 4));
    float* ad1  = (float*)(ws + alloc((size_t)N_NODES * HEADS * 4));
    float* as2  = (float*)(ws + alloc((size_t)N_NODES * 4));
    float* ad2  = (float*)(ws + alloc((size_t)N_NODES * 4));
    int*   deg  = (int*)(ws + alloc((size_t)N_NODES * 4));
    int*   off  = (int*)(ws + alloc((size_t)(N_NODES + 1) * 4));
    int*   cur  = (int*)(ws + alloc((size_t)N_NODES * 4));
    int*   bsum = (int*)(ws + alloc(256 * 4));
    int*   ssrc = (int*)(ws + alloc((size_t)E_TOT * 4));

    (void)hipMemsetAsync(deg, 0, (size_t)N_NODES * 4, stream);
    int eblk = (E_TOT + 255) / 256;
    hist_kernel<<<eblk, 256, 0, stream>>>(ei, deg);
    scan1_kernel<<<NBLK, 256, 0, stream>>>(deg, off, bsum);
    scan2_kernel<<<1, 256, 0, stream>>>(bsum, NBLK);
    scan3_kernel<<<NBLK, 256, 0, stream>>>(off, bsum, cur);
    scatter_kernel<<<eblk, 256, 0, stream>>>(ei, cur, ssrc);

    w1cast_kernel<<<128, 256, 0, stream>>>(W1, W1t);
    gemm1_mfma<<<G1BLK, 256, 0, stream>>>(x, W1t, ats1, atd1, h1b, as1, ad1);
    agg1_kernel<<<ABLK, 256, 0, stream>>>(off, ssrc, h1b, as1, ad1, b1, h2inb);

    w2cast_kernel<<<64, 256, 0, stream>>>(W2, W2t);
    gemm2_mfma<<<G2BLK, 256, 0, stream>>>(h2inb, W2t, ats2, atd2, h2b, as2, ad2);
    agg2_kernel<<<ABLK, 256, 0, stream>>>(off, ssrc, h2b, as2, ad2, b2, out);
}

// Round 19
// 225.119 us; speedup vs baseline: 1.4837x; 1.1966x over previous
//
#include <hip/hip_runtime.h>
#include <hip/hip_bf16.h>
#include <math.h>

#define N_NODES 50000
#define N_EDGES 800000
#define E_TOT   (N_EDGES + N_NODES)   // 850000 (with self-loops)
#define IN_CH 128
#define HID 32
#define HEADS 8
#define OUT_CH 64
#define NEG_SLOPE 0.2f
#define NBLK 196                      // ceil(50000/256)
#define G1BLK 3125                    // 50000/16 rows per MFMA block
#define G2BLK 782                     // ceil(50000/64)
#define ABLK 12500                    // 50000/4 nodes per 256-thread block
#define LOG2E 1.4426950408889634f

typedef __attribute__((ext_vector_type(8))) short bf16x8;
typedef __attribute__((ext_vector_type(4))) float f32x4;

__device__ __forceinline__ float lrelu(float x) { return x > 0.f ? x : NEG_SLOPE * x; }
// exp(lrelu(z)) = exp2(max(z*L, z*0.2L))  (branchless; valid since L>0)
__device__ __forceinline__ float explrelu(float z) {
    return exp2f(fmaxf(z * LOG2E, z * (NEG_SLOPE * LOG2E)));
}

__device__ __forceinline__ unsigned short f2bf(float f) {
    unsigned int u = __float_as_uint(f);
    unsigned int r = (u + 0x7FFFu + ((u >> 16) & 1u)) >> 16;   // round-nearest-even
    return (unsigned short)r;
}
__device__ __forceinline__ float bf2f(unsigned short u) {
    return __uint_as_float(((unsigned int)u) << 16);
}
__device__ __forceinline__ float bflo(unsigned int u) {       // low ushort -> float
    return __uint_as_float(u << 16);
}
__device__ __forceinline__ float bfhi(unsigned int u) {       // high ushort -> float
    return __uint_as_float(u & 0xFFFF0000u);
}

// ---------------- CSR build (single atomic pass) ----------------------------
// rank_kernel: deg histogram AND per-edge rank in ONE atomic pass.
__global__ void rank_kernel(const int* __restrict__ ei, int* __restrict__ deg,
                            int* __restrict__ rank) {
    int e = blockIdx.x * blockDim.x + threadIdx.x;
    if (e >= E_TOT) return;
    int d = (e < N_EDGES) ? ei[N_EDGES + e] : (e - N_EDGES);
    rank[e] = atomicAdd(&deg[d], 1);
}

__global__ void scan1_kernel(const int* __restrict__ deg, int* __restrict__ off,
                             int* __restrict__ bsum) {
    __shared__ int s[256];
    int b = blockIdx.x, t = threadIdx.x, g = b * 256 + t;
    int v = (g < N_NODES) ? deg[g] : 0;
    s[t] = v;
    __syncthreads();
    for (int d = 1; d < 256; d <<= 1) {
        int o = (t >= d) ? s[t - d] : 0;
        __syncthreads();
        s[t] += o;
        __syncthreads();
    }
    if (g < N_NODES) off[g] = s[t] - v;
    if (t == 255) bsum[b] = s[t];
}

__global__ void scan2_kernel(int* __restrict__ bsum, int nb) {
    __shared__ int s[256];
    int t = threadIdx.x;
    int v = (t < nb) ? bsum[t] : 0;
    s[t] = v;
    __syncthreads();
    for (int d = 1; d < 256; d <<= 1) {
        int o = (t >= d) ? s[t - d] : 0;
        __syncthreads();
        s[t] += o;
        __syncthreads();
    }
    if (t < nb) bsum[t] = s[t] - v;
}

__global__ void scan3_kernel(int* __restrict__ off, const int* __restrict__ bsum) {
    int b = blockIdx.x, t = threadIdx.x, g = b * 256 + t;
    if (g < N_NODES) off[g] += bsum[b];
    if (g == 0) off[N_NODES] = E_TOT;
}

// place_kernel: non-atomic placement using precomputed rank.
__global__ void place_kernel(const int* __restrict__ ei, const int* __restrict__ off,
                             const int* __restrict__ rank, int* __restrict__ ssrc) {
    int e = blockIdx.x * blockDim.x + threadIdx.x;
    if (e >= E_TOT) return;
    int s, d;
    if (e < N_EDGES) { s = ei[e]; d = ei[N_EDGES + e]; }
    else             { s = d = e - N_EDGES; }
    ssrc[off[d] + rank[e]] = s;
}

// ---------------- W1 transpose + bf16 cast: W1t[col][k] ----------------------
__global__ void w1cast_kernel(const float* __restrict__ W1,
                              unsigned short* __restrict__ W1t) {
    int i = blockIdx.x * 256 + threadIdx.x;    // 32768 elems
    int col = i >> 7, k = i & 127;
    W1t[i] = f2bf(W1[k * 256 + col]);
}

// ---------------- W2 transpose + bf16 cast: W2t[col][k] ----------------------
__global__ void w2cast_kernel(const float* __restrict__ W2,
                              unsigned short* __restrict__ W2t) {
    int i = blockIdx.x * 256 + threadIdx.x;    // 16384 elems
    int col = i >> 8, k = i & 255;
    W2t[i] = f2bf(W2[k * 64 + col]);
}

// ---------------- GEMM1 via MFMA (bf16 in, fp32 acc) + alpha epilogue -------
__global__ __launch_bounds__(256) void gemm1_mfma(
    const float* __restrict__ x, const unsigned short* __restrict__ W1t,
    const float* __restrict__ att_s, const float* __restrict__ att_d,
    unsigned short* __restrict__ h1b, float* __restrict__ as1, float* __restrict__ ad1) {
    int t = threadIdx.x;
    int lane = t & 63;
    int w = t >> 6;
    int lrow = lane & 15;
    int kg = lane >> 4;
    int row0 = blockIdx.x * 16;
    int gr = row0 + lrow;                      // 3125*16 = 50000 exactly
    f32x4 acc0 = {0.f, 0.f, 0.f, 0.f};
    f32x4 acc1 = {0.f, 0.f, 0.f, 0.f};
    f32x4 acc2 = {0.f, 0.f, 0.f, 0.f};
    f32x4 acc3 = {0.f, 0.f, 0.f, 0.f};
#pragma unroll
    for (int ks = 0; ks < 4; ++ks) {
        const float* ap = &x[(size_t)gr * IN_CH + ks * 32 + kg * 8];
        float4 a0 = *(const float4*)ap;
        float4 a1 = *(const float4*)(ap + 4);
        union { bf16x8 v; unsigned int u[4]; } A;
        A.u[0] = ((unsigned)f2bf(a0.y) << 16) | f2bf(a0.x);
        A.u[1] = ((unsigned)f2bf(a0.w) << 16) | f2bf(a0.z);
        A.u[2] = ((unsigned)f2bf(a1.y) << 16) | f2bf(a1.x);
        A.u[3] = ((unsigned)f2bf(a1.w) << 16) | f2bf(a1.z);
        union { bf16x8 v; uint4 u; } B0, B1, B2, B3;
        int kb = ks * 32 + kg * 8;
        B0.u = *(const uint4*)&W1t[(size_t)(w * 64 + 0 * 16 + lrow) * IN_CH + kb];
        B1.u = *(const uint4*)&W1t[(size_t)(w * 64 + 1 * 16 + lrow) * IN_CH + kb];
        B2.u = *(const uint4*)&W1t[(size_t)(w * 64 + 2 * 16 + lrow) * IN_CH + kb];
        B3.u = *(const uint4*)&W1t[(size_t)(w * 64 + 3 * 16 + lrow) * IN_CH + kb];
        acc0 = __builtin_amdgcn_mfma_f32_16x16x32_bf16(A.v, B0.v, acc0, 0, 0, 0);
        acc1 = __builtin_amdgcn_mfma_f32_16x16x32_bf16(A.v, B1.v, acc1, 0, 0, 0);
        acc2 = __builtin_amdgcn_mfma_f32_16x16x32_bf16(A.v, B2.v, acc2, 0, 0, 0);
        acc3 = __builtin_amdgcn_mfma_f32_16x16x32_bf16(A.v, B3.v, acc3, 0, 0, 0);
    }
    float s0 = att_s[w * 64 + 0 * 16 + lrow], d0 = att_d[w * 64 + 0 * 16 + lrow];
    float s1 = att_s[w * 64 + 1 * 16 + lrow], d1 = att_d[w * 64 + 1 * 16 + lrow];
    float s2 = att_s[w * 64 + 2 * 16 + lrow], d2 = att_d[w * 64 + 2 * 16 + lrow];
    float s3 = att_s[w * 64 + 3 * 16 + lrow], d3 = att_d[w * 64 + 3 * 16 + lrow];
#pragma unroll
    for (int r = 0; r < 4; ++r) {
        int orow = row0 + kg * 4 + r;
        h1b[(size_t)orow * 256 + w * 64 +  0 + lrow] = f2bf(acc0[r]);
        h1b[(size_t)orow * 256 + w * 64 + 16 + lrow] = f2bf(acc1[r]);
        h1b[(size_t)orow * 256 + w * 64 + 32 + lrow] = f2bf(acc2[r]);
        h1b[(size_t)orow * 256 + w * 64 + 48 + lrow] = f2bf(acc3[r]);
        float p0 = acc0[r] * s0 + acc1[r] * s1;
        float q0 = acc0[r] * d0 + acc1[r] * d1;
        float p1 = acc2[r] * s2 + acc3[r] * s3;
        float q1 = acc2[r] * d2 + acc3[r] * d3;
        p0 += __shfl_xor(p0, 1); q0 += __shfl_xor(q0, 1);
        p1 += __shfl_xor(p1, 1); q1 += __shfl_xor(q1, 1);
        p0 += __shfl_xor(p0, 2); q0 += __shfl_xor(q0, 2);
        p1 += __shfl_xor(p1, 2); q1 += __shfl_xor(q1, 2);
        p0 += __shfl_xor(p0, 4); q0 += __shfl_xor(q0, 4);
        p1 += __shfl_xor(p1, 4); q1 += __shfl_xor(q1, 4);
        p0 += __shfl_xor(p0, 8); q0 += __shfl_xor(q0, 8);
        p1 += __shfl_xor(p1, 8); q1 += __shfl_xor(q1, 8);
        if (lrow == 0) {
            as1[orow * HEADS + 2 * w]     = p0;
            ad1[orow * HEADS + 2 * w]     = q0;
            as1[orow * HEADS + 2 * w + 1] = p1;
            ad1[orow * HEADS + 2 * w + 1] = q1;
        }
    }
}

// ---------------- Aggregate layer 1: dual-edge wide gathers, 2-deep pipe ----
__global__ __launch_bounds__(256) void agg1_kernel(
    const int* __restrict__ off, const int* __restrict__ ssrc,
    const unsigned short* __restrict__ h1b, const float* __restrict__ as1,
    const float* __restrict__ ad1, const float* __restrict__ b1,
    unsigned short* __restrict__ houtb) {
    int t = threadIdx.x;
    int lane = t & 63;
    int n = blockIdx.x * 4 + (t >> 6);
    int h    = lane >> 3;     // weight-phase head
    int e8   = lane & 7;      // weight-phase edge slot
    int c    = lane & 31;     // channel group: ushorts [c*8, c*8+8)
    int hh   = c >> 2;        // head of my channel group
    int half = lane >> 5;     // 0: even edges, 1: odd edges
    int start = off[n], end = off[n + 1];
    int last = end - 1;
    float ad_w = ad1[n * HEADS + e8];
    float acc[8];
#pragma unroll
    for (int j = 0; j < 8; ++j) acc[j] = 0.f;
    float den = 0.f;
    int sv = ssrc[min(start + e8, last)];
    int se = __shfl(sv, h);
    float av = as1[se * HEADS + e8];
    const unsigned short* base = h1b + c * 8;
    uint4 g0 = *(const uint4*)&base[(unsigned)__shfl(sv, 0 + half) * 256];
    uint4 g1 = *(const uint4*)&base[(unsigned)__shfl(sv, 2 + half) * 256];
    uint4 g2 = *(const uint4*)&base[(unsigned)__shfl(sv, 4 + half) * 256];
    uint4 g3 = *(const uint4*)&base[(unsigned)__shfl(sv, 6 + half) * 256];
    for (int i = start; i < end; i += 8) {
        int inext = i + 8;
        int sv_n = ssrc[min(inext + e8, last)];
        int se_n = __shfl(sv_n, h);
        float av_n = as1[se_n * HEADS + e8];
        uint4 n0 = *(const uint4*)&base[(unsigned)__shfl(sv_n, 0 + half) * 256];
        uint4 n1 = *(const uint4*)&base[(unsigned)__shfl(sv_n, 2 + half) * 256];
        uint4 n2 = *(const uint4*)&base[(unsigned)__shfl(sv_n, 4 + half) * 256];
        uint4 n3 = *(const uint4*)&base[(unsigned)__shfl(sv_n, 6 + half) * 256];
        float wv = explrelu(av + ad_w);
        float w0 = __shfl(wv, (0 + half) * 8 + hh);
        float w1 = __shfl(wv, (2 + half) * 8 + hh);
        float w2 = __shfl(wv, (4 + half) * 8 + hh);
        float w3 = __shfl(wv, (6 + half) * 8 + hh);
        w0 = (i + 0 + half < end) ? w0 : 0.f;
        w1 = (i + 2 + half < end) ? w1 : 0.f;
        w2 = (i + 4 + half < end) ? w2 : 0.f;
        w3 = (i + 6 + half < end) ? w3 : 0.f;
        den += w0 + w1 + w2 + w3;
        acc[0] = fmaf(w0, bflo(g0.x), acc[0]); acc[1] = fmaf(w0, bfhi(g0.x), acc[1]);
        acc[2] = fmaf(w0, bflo(g0.y), acc[2]); acc[3] = fmaf(w0, bfhi(g0.y), acc[3]);
        acc[4] = fmaf(w0, bflo(g0.z), acc[4]); acc[5] = fmaf(w0, bfhi(g0.z), acc[5]);
        acc[6] = fmaf(w0, bflo(g0.w), acc[6]); acc[7] = fmaf(w0, bfhi(g0.w), acc[7]);
        acc[0] = fmaf(w1, bflo(g1.x), acc[0]); acc[1] = fmaf(w1, bfhi(g1.x), acc[1]);
        acc[2] = fmaf(w1, bflo(g1.y), acc[2]); acc[3] = fmaf(w1, bfhi(g1.y), acc[3]);
        acc[4] = fmaf(w1, bflo(g1.z), acc[4]); acc[5] = fmaf(w1, bfhi(g1.z), acc[5]);
        acc[6] = fmaf(w1, bflo(g1.w), acc[6]); acc[7] = fmaf(w1, bfhi(g1.w), acc[7]);
        acc[0] = fmaf(w2, bflo(g2.x), acc[0]); acc[1] = fmaf(w2, bfhi(g2.x), acc[1]);
        acc[2] = fmaf(w2, bflo(g2.y), acc[2]); acc[3] = fmaf(w2, bfhi(g2.y), acc[3]);
        acc[4] = fmaf(w2, bflo(g2.z), acc[4]); acc[5] = fmaf(w2, bfhi(g2.z), acc[5]);
        acc[6] = fmaf(w2, bflo(g2.w), acc[6]); acc[7] = fmaf(w2, bfhi(g2.w), acc[7]);
        acc[0] = fmaf(w3, bflo(g3.x), acc[0]); acc[1] = fmaf(w3, bfhi(g3.x), acc[1]);
        acc[2] = fmaf(w3, bflo(g3.y), acc[2]); acc[3] = fmaf(w3, bfhi(g3.y), acc[3]);
        acc[4] = fmaf(w3, bflo(g3.z), acc[4]); acc[5] = fmaf(w3, bfhi(g3.z), acc[5]);
        acc[6] = fmaf(w3, bflo(g3.w), acc[6]); acc[7] = fmaf(w3, bfhi(g3.w), acc[7]);
        g0 = n0; g1 = n1; g2 = n2; g3 = n3;
        sv = sv_n; av = av_n;
    }
#pragma unroll
    for (int j = 0; j < 8; ++j) acc[j] += __shfl_xor(acc[j], 32);
    den += __shfl_xor(den, 32);
    if (lane < 32) {
        float r = __builtin_amdgcn_rcpf(den);
        float4 b0 = *(const float4*)&b1[c * 8];
        float4 b4 = *(const float4*)&b1[c * 8 + 4];
        float v0 = fmaf(acc[0], r, b0.x);
        float v1 = fmaf(acc[1], r, b0.y);
        float v2 = fmaf(acc[2], r, b0.z);
        float v3 = fmaf(acc[3], r, b0.w);
        float v4 = fmaf(acc[4], r, b4.x);
        float v5 = fmaf(acc[5], r, b4.y);
        float v6 = fmaf(acc[6], r, b4.z);
        float v7 = fmaf(acc[7], r, b4.w);
        v0 = v0 > 0.f ? v0 : expm1f(v0);
        v1 = v1 > 0.f ? v1 : expm1f(v1);
        v2 = v2 > 0.f ? v2 : expm1f(v2);
        v3 = v3 > 0.f ? v3 : expm1f(v3);
        v4 = v4 > 0.f ? v4 : expm1f(v4);
        v5 = v5 > 0.f ? v5 : expm1f(v5);
        v6 = v6 > 0.f ? v6 : expm1f(v6);
        v7 = v7 > 0.f ? v7 : expm1f(v7);
        uint4 ob;
        ob.x = (unsigned)f2bf(v0) | ((unsigned)f2bf(v1) << 16);
        ob.y = (unsigned)f2bf(v2) | ((unsigned)f2bf(v3) << 16);
        ob.z = (unsigned)f2bf(v4) | ((unsigned)f2bf(v5) << 16);
        ob.w = (unsigned)f2bf(v6) | ((unsigned)f2bf(v7) << 16);
        *(uint4*)&houtb[(unsigned)n * 256 + c * 8] = ob;
    }
}

// ---------------- GEMM2 via MFMA (bf16 in, fp32 acc) + alpha epilogue -------
__global__ __launch_bounds__(256) void gemm2_mfma(
    const unsigned short* __restrict__ hinb, const unsigned short* __restrict__ W2t,
    const float* __restrict__ att_s2, const float* __restrict__ att_d2,
    unsigned short* __restrict__ h2b, float* __restrict__ as2, float* __restrict__ ad2) {
    int t = threadIdx.x;
    int lane = t & 63;
    int w = t >> 6;
    int lrow = lane & 15;
    int kg = lane >> 4;
    int row0 = blockIdx.x * 64 + w * 16;
    int gr = min(row0 + lrow, N_NODES - 1);    // clamp loads (last block partial)
    f32x4 acc0 = {0.f, 0.f, 0.f, 0.f};
    f32x4 acc1 = {0.f, 0.f, 0.f, 0.f};
    f32x4 acc2 = {0.f, 0.f, 0.f, 0.f};
    f32x4 acc3 = {0.f, 0.f, 0.f, 0.f};
#pragma unroll
    for (int ks = 0; ks < 8; ++ks) {
        int kb = ks * 32 + kg * 8;
        union { bf16x8 v; uint4 u; } A, B0, B1, B2, B3;
        A.u  = *(const uint4*)&hinb[(size_t)gr * 256 + kb];
        B0.u = *(const uint4*)&W2t[(size_t)(0 * 16 + lrow) * 256 + kb];
        B1.u = *(const uint4*)&W2t[(size_t)(1 * 16 + lrow) * 256 + kb];
        B2.u = *(const uint4*)&W2t[(size_t)(2 * 16 + lrow) * 256 + kb];
        B3.u = *(const uint4*)&W2t[(size_t)(3 * 16 + lrow) * 256 + kb];
        acc0 = __builtin_amdgcn_mfma_f32_16x16x32_bf16(A.v, B0.v, acc0, 0, 0, 0);
        acc1 = __builtin_amdgcn_mfma_f32_16x16x32_bf16(A.v, B1.v, acc1, 0, 0, 0);
        acc2 = __builtin_amdgcn_mfma_f32_16x16x32_bf16(A.v, B2.v, acc2, 0, 0, 0);
        acc3 = __builtin_amdgcn_mfma_f32_16x16x32_bf16(A.v, B3.v, acc3, 0, 0, 0);
    }
    float s0 = att_s2[ 0 + lrow], d0 = att_d2[ 0 + lrow];
    float s1 = att_s2[16 + lrow], d1 = att_d2[16 + lrow];
    float s2 = att_s2[32 + lrow], d2 = att_d2[32 + lrow];
    float s3 = att_s2[48 + lrow], d3 = att_d2[48 + lrow];
#pragma unroll
    for (int r = 0; r < 4; ++r) {
        int orow = row0 + kg * 4 + r;
        float p = acc0[r] * s0 + acc1[r] * s1 + acc2[r] * s2 + acc3[r] * s3;
        float q = acc0[r] * d0 + acc1[r] * d1 + acc2[r] * d2 + acc3[r] * d3;
        p += __shfl_xor(p, 1); q += __shfl_xor(q, 1);
        p += __shfl_xor(p, 2); q += __shfl_xor(q, 2);
        p += __shfl_xor(p, 4); q += __shfl_xor(q, 4);
        p += __shfl_xor(p, 8); q += __shfl_xor(q, 8);
        if (orow < N_NODES) {
            h2b[(size_t)orow * 64 +  0 + lrow] = f2bf(acc0[r]);
            h2b[(size_t)orow * 64 + 16 + lrow] = f2bf(acc1[r]);
            h2b[(size_t)orow * 64 + 32 + lrow] = f2bf(acc2[r]);
            h2b[(size_t)orow * 64 + 48 + lrow] = f2bf(acc3[r]);
            if (lrow == 0) { as2[orow] = p; ad2[orow] = q; }
        }
    }
}

// ---------------- Aggregate layer 2: quad-edge wide gathers -----------------
__global__ __launch_bounds__(256) void agg2_kernel(
    const int* __restrict__ off, const int* __restrict__ ssrc,
    const unsigned short* __restrict__ h2b, const float* __restrict__ as2,
    const float* __restrict__ ad2, const float* __restrict__ b2,
    float* __restrict__ out) {
    int t = threadIdx.x;
    int lane = t & 63;
    int e8 = lane & 7;
    int q = lane & 15;
    int quarter = lane >> 4;
    int n = blockIdx.x * 4 + (t >> 6);
    int start = off[n], end = off[n + 1];
    int last = end - 1;
    float adv = ad2[n];
    float acc[4];
#pragma unroll
    for (int j = 0; j < 4; ++j) acc[j] = 0.f;
    float den = 0.f;
    int sv = ssrc[min(start + e8, last)];
    float av = as2[sv];
    for (int i = start; i < end; i += 8) {
        int inext = i + 8;
        int sv_n = ssrc[min(inext + e8, last)];
        float av_n = as2[sv_n];
        float wv = explrelu(av + adv);
#pragma unroll
        for (int k = 0; k < 2; ++k) {
            int me = 4 * k + quarter;
            float wj = __shfl(wv, me);
            int   sj = __shfl(sv, me);
            wj = (i + me < end) ? wj : 0.f;
            uint2 u = *(const uint2*)&h2b[(unsigned)sj * 64 + q * 4];
            den += wj;
            acc[0] = fmaf(wj, bflo(u.x), acc[0]);
            acc[1] = fmaf(wj, bfhi(u.x), acc[1]);
            acc[2] = fmaf(wj, bflo(u.y), acc[2]);
            acc[3] = fmaf(wj, bfhi(u.y), acc[3]);
        }
        sv = sv_n; av = av_n;
    }
#pragma unroll
    for (int j = 0; j < 4; ++j) {
        acc[j] += __shfl_xor(acc[j], 16);
        acc[j] += __shfl_xor(acc[j], 32);
    }
    den += __shfl_xor(den, 16);
    den += __shfl_xor(den, 32);
    if (lane < 16) {
        float r = __builtin_amdgcn_rcpf(den);
        float4 bv = *(const float4*)&b2[q * 4];
        float4 o;
        o.x = fmaf(acc[0], r, bv.x);
        o.y = fmaf(acc[1], r, bv.y);
        o.z = fmaf(acc[2], r, bv.z);
        o.w = fmaf(acc[3], r, bv.w);
        *(float4*)&out[(unsigned)n * 64 + q * 4] = o;
    }
}

extern "C" void kernel_launch(void* const* d_in, const int* in_sizes, int n_in,
                              void* d_out, int out_size, void* d_ws, size_t ws_size,
                              hipStream_t stream) {
    const float* x    = (const float*)d_in[0];
    const int*   ei   = (const int*)d_in[1];
    const float* W1   = (const float*)d_in[2];
    const float* ats1 = (const float*)d_in[3];
    const float* atd1 = (const float*)d_in[4];
    const float* b1   = (const float*)d_in[5];
    const float* W2   = (const float*)d_in[6];
    const float* ats2 = (const float*)d_in[7];
    const float* atd2 = (const float*)d_in[8];
    const float* b2   = (const float*)d_in[9];
    float* out = (float*)d_out;

    char* ws = (char*)d_ws;
    size_t o = 0;
    auto alloc = [&](size_t bytes) { size_t r = o; o = (o + bytes + 255) & ~255UL; return r; };
    unsigned short* h1b   = (unsigned short*)(ws + alloc((size_t)N_NODES * 256 * 2));
    unsigned short* h2inb = (unsigned short*)(ws + alloc((size_t)N_NODES * 256 * 2));
    unsigned short* h2b   = (unsigned short*)(ws + alloc((size_t)N_NODES * 64 * 2));
    unsigned short* W1t   = (unsigned short*)(ws + alloc((size_t)256 * 128 * 2));
    unsigned short* W2t   = (unsigned short*)(ws + alloc((size_t)64 * 256 * 2));
    float* as1  = (float*)(ws + alloc((size_t)N_NODES * HEADS * 4));
    float* ad1  = (float*)(ws + alloc((size_t)N_NODES * HEADS * 4));
    float* as2  = (float*)(ws + alloc((size_t)N_NODES * 4));
    float* ad2  = (float*)(ws + alloc((size_t)N_NODES * 4));
    int*   deg  = (int*)(ws + alloc((size_t)N_NODES * 4));
    int*   off  = (int*)(ws + alloc((size_t)(N_NODES + 1) * 4));
    int*   bsum = (int*)(ws + alloc(256 * 4));
    int*   rank = (int*)(ws + alloc((size_t)E_TOT * 4));
    int*   ssrc = (int*)(ws + alloc((size_t)E_TOT * 4));

    (void)hipMemsetAsync(deg, 0, (size_t)N_NODES * 4, stream);
    int eblk = (E_TOT + 255) / 256;
    rank_kernel<<<eblk, 256, 0, stream>>>(ei, deg, rank);
    scan1_kernel<<<NBLK, 256, 0, stream>>>(deg, off, bsum);
    scan2_kernel<<<1, 256, 0, stream>>>(bsum, NBLK);
    scan3_kernel<<<NBLK, 256, 0, stream>>>(off, bsum);
    place_kernel<<<eblk, 256, 0, stream>>>(ei, off, rank, ssrc);

    w1cast_kernel<<<128, 256, 0, stream>>>(W1, W1t);
    gemm1_mfma<<<G1BLK, 256, 0, stream>>>(x, W1t, ats1, atd1, h1b, as1, ad1);
    agg1_kernel<<<ABLK, 256, 0, stream>>>(off, ssrc, h1b, as1, ad1, b1, h2inb);

    w2cast_kernel<<<64, 256, 0, stream>>>(W2, W2t);
    gemm2_mfma<<<G2BLK, 256, 0, stream>>>(h2inb, W2t, ats2, atd2, h2b, as2, ad2);
    agg2_kernel<<<ABLK, 256, 0, stream>>>(off, ssrc, h2b, as2, ad2, b2, out);
}

// Round 20
// 218.975 us; speedup vs baseline: 1.5253x; 1.0281x over previous
//
#include <hip/hip_runtime.h>
#include <hip/hip_bf16.h>
#include <math.h>

#define N_NODES 50000
#define N_EDGES 800000
#define E_TOT   (N_EDGES + N_NODES)   // 850000 (with self-loops)
#define IN_CH 128
#define HID 32
#define HEADS 8
#define OUT_CH 64
#define NEG_SLOPE 0.2f
#define NBLK 196                      // ceil(50000/256)
#define RBLK 3321                     // ceil(850000/256) rank blocks
#define G1BLK 3125                    // 50000/16 rows per MFMA block
#define G2BLK 782                     // ceil(50000/64)
#define ABLK 12500                    // 50000/4 nodes per 256-thread block
#define LOG2E 1.4426950408889634f

typedef __attribute__((ext_vector_type(8))) short bf16x8;
typedef __attribute__((ext_vector_type(4))) float f32x4;

__device__ __forceinline__ float lrelu(float x) { return x > 0.f ? x : NEG_SLOPE * x; }
// exp(lrelu(z)) = exp2(max(z*L, z*0.2L))  (branchless; valid since L>0)
__device__ __forceinline__ float explrelu(float z) {
    return exp2f(fmaxf(z * LOG2E, z * (NEG_SLOPE * LOG2E)));
}

__device__ __forceinline__ unsigned short f2bf(float f) {
    unsigned int u = __float_as_uint(f);
    unsigned int r = (u + 0x7FFFu + ((u >> 16) & 1u)) >> 16;   // round-nearest-even
    return (unsigned short)r;
}
__device__ __forceinline__ float bf2f(unsigned short u) {
    return __uint_as_float(((unsigned int)u) << 16);
}
__device__ __forceinline__ float bflo(unsigned int u) {       // low ushort -> float
    return __uint_as_float(u << 16);
}
__device__ __forceinline__ float bfhi(unsigned int u) {       // high ushort -> float
    return __uint_as_float(u & 0xFFFF0000u);
}

// ---------------- W1 transpose + bf16 cast: W1t[col][k] ----------------------
__global__ void w1cast_kernel(const float* __restrict__ W1,
                              unsigned short* __restrict__ W1t) {
    int i = blockIdx.x * 256 + threadIdx.x;    // 32768 elems
    int col = i >> 7, k = i & 127;
    W1t[i] = f2bf(W1[k * 256 + col]);
}

// ---------------- GEMM1 body (device fn, called from fused kernel) ----------
__device__ __forceinline__ void gemm1_body(
    int blk, int t,
    const float* __restrict__ x, const unsigned short* __restrict__ W1t,
    const float* __restrict__ att_s, const float* __restrict__ att_d,
    unsigned short* __restrict__ h1b, float* __restrict__ as1, float* __restrict__ ad1) {
    int lane = t & 63;
    int w = t >> 6;
    int lrow = lane & 15;
    int kg = lane >> 4;
    int row0 = blk * 16;
    int gr = row0 + lrow;                      // 3125*16 = 50000 exactly
    f32x4 acc0 = {0.f, 0.f, 0.f, 0.f};
    f32x4 acc1 = {0.f, 0.f, 0.f, 0.f};
    f32x4 acc2 = {0.f, 0.f, 0.f, 0.f};
    f32x4 acc3 = {0.f, 0.f, 0.f, 0.f};
#pragma unroll
    for (int ks = 0; ks < 4; ++ks) {
        const float* ap = &x[(size_t)gr * IN_CH + ks * 32 + kg * 8];
        float4 a0 = *(const float4*)ap;
        float4 a1 = *(const float4*)(ap + 4);
        union { bf16x8 v; unsigned int u[4]; } A;
        A.u[0] = ((unsigned)f2bf(a0.y) << 16) | f2bf(a0.x);
        A.u[1] = ((unsigned)f2bf(a0.w) << 16) | f2bf(a0.z);
        A.u[2] = ((unsigned)f2bf(a1.y) << 16) | f2bf(a1.x);
        A.u[3] = ((unsigned)f2bf(a1.w) << 16) | f2bf(a1.z);
        union { bf16x8 v; uint4 u; } B0, B1, B2, B3;
        int kb = ks * 32 + kg * 8;
        B0.u = *(const uint4*)&W1t[(size_t)(w * 64 + 0 * 16 + lrow) * IN_CH + kb];
        B1.u = *(const uint4*)&W1t[(size_t)(w * 64 + 1 * 16 + lrow) * IN_CH + kb];
        B2.u = *(const uint4*)&W1t[(size_t)(w * 64 + 2 * 16 + lrow) * IN_CH + kb];
        B3.u = *(const uint4*)&W1t[(size_t)(w * 64 + 3 * 16 + lrow) * IN_CH + kb];
        acc0 = __builtin_amdgcn_mfma_f32_16x16x32_bf16(A.v, B0.v, acc0, 0, 0, 0);
        acc1 = __builtin_amdgcn_mfma_f32_16x16x32_bf16(A.v, B1.v, acc1, 0, 0, 0);
        acc2 = __builtin_amdgcn_mfma_f32_16x16x32_bf16(A.v, B2.v, acc2, 0, 0, 0);
        acc3 = __builtin_amdgcn_mfma_f32_16x16x32_bf16(A.v, B3.v, acc3, 0, 0, 0);
    }
    float s0 = att_s[w * 64 + 0 * 16 + lrow], d0 = att_d[w * 64 + 0 * 16 + lrow];
    float s1 = att_s[w * 64 + 1 * 16 + lrow], d1 = att_d[w * 64 + 1 * 16 + lrow];
    float s2 = att_s[w * 64 + 2 * 16 + lrow], d2 = att_d[w * 64 + 2 * 16 + lrow];
    float s3 = att_s[w * 64 + 3 * 16 + lrow], d3 = att_d[w * 64 + 3 * 16 + lrow];
#pragma unroll
    for (int r = 0; r < 4; ++r) {
        int orow = row0 + kg * 4 + r;
        h1b[(size_t)orow * 256 + w * 64 +  0 + lrow] = f2bf(acc0[r]);
        h1b[(size_t)orow * 256 + w * 64 + 16 + lrow] = f2bf(acc1[r]);
        h1b[(size_t)orow * 256 + w * 64 + 32 + lrow] = f2bf(acc2[r]);
        h1b[(size_t)orow * 256 + w * 64 + 48 + lrow] = f2bf(acc3[r]);
        float p0 = acc0[r] * s0 + acc1[r] * s1;
        float q0 = acc0[r] * d0 + acc1[r] * d1;
        float p1 = acc2[r] * s2 + acc3[r] * s3;
        float q1 = acc2[r] * d2 + acc3[r] * d3;
        p0 += __shfl_xor(p0, 1); q0 += __shfl_xor(q0, 1);
        p1 += __shfl_xor(p1, 1); q1 += __shfl_xor(q1, 1);
        p0 += __shfl_xor(p0, 2); q0 += __shfl_xor(q0, 2);
        p1 += __shfl_xor(p1, 2); q1 += __shfl_xor(q1, 2);
        p0 += __shfl_xor(p0, 4); q0 += __shfl_xor(q0, 4);
        p1 += __shfl_xor(p1, 4); q1 += __shfl_xor(q1, 4);
        p0 += __shfl_xor(p0, 8); q0 += __shfl_xor(q0, 8);
        p1 += __shfl_xor(p1, 8); q1 += __shfl_xor(q1, 8);
        if (lrow == 0) {
            as1[orow * HEADS + 2 * w]     = p0;
            ad1[orow * HEADS + 2 * w]     = q0;
            as1[orow * HEADS + 2 * w + 1] = p1;
            ad1[orow * HEADS + 2 * w + 1] = q1;
        }
    }
}

// ---------------- Fused phase 1: rank (padded counters) + gemm1 + w2cast ----
// rank blocks are latency-bound (atomics); gemm1 blocks fill the compute gap.
// deg2 is padded to one counter per 64B cache line -> per-line atomic
// serialization drops from ~272 to ~17.
__global__ __launch_bounds__(256) void fused1_kernel(
    const int* __restrict__ ei, int* __restrict__ deg2, int* __restrict__ rank,
    const float* __restrict__ x, const unsigned short* __restrict__ W1t,
    const float* __restrict__ att_s, const float* __restrict__ att_d,
    unsigned short* __restrict__ h1b, float* __restrict__ as1, float* __restrict__ ad1,
    const float* __restrict__ W2, unsigned short* __restrict__ W2t) {
    int b = blockIdx.x;
    if (b < RBLK) {
        int e = b * 256 + threadIdx.x;
        if (e < E_TOT) {
            int d = (e < N_EDGES) ? ei[N_EDGES + e] : (e - N_EDGES);
            rank[e] = atomicAdd(&deg2[d * 16], 1);
        }
    } else if (b < RBLK + G1BLK) {
        gemm1_body(b - RBLK, threadIdx.x, x, W1t, att_s, att_d, h1b, as1, ad1);
    } else {
        int i = (b - RBLK - G1BLK) * 256 + threadIdx.x;   // 16384 elems, 64 blocks
        int col = i >> 8, k = i & 255;
        W2t[i] = f2bf(W2[k * 64 + col]);
    }
}

__global__ void scan1_kernel(const int* __restrict__ deg2, int* __restrict__ off,
                             int* __restrict__ bsum) {
    __shared__ int s[256];
    int b = blockIdx.x, t = threadIdx.x, g = b * 256 + t;
    int v = (g < N_NODES) ? deg2[g * 16] : 0;
    s[t] = v;
    __syncthreads();
    for (int d = 1; d < 256; d <<= 1) {
        int o = (t >= d) ? s[t - d] : 0;
        __syncthreads();
        s[t] += o;
        __syncthreads();
    }
    if (g < N_NODES) off[g] = s[t] - v;
    if (t == 255) bsum[b] = s[t];
}

__global__ void scan2_kernel(int* __restrict__ bsum, int nb) {
    __shared__ int s[256];
    int t = threadIdx.x;
    int v = (t < nb) ? bsum[t] : 0;
    s[t] = v;
    __syncthreads();
    for (int d = 1; d < 256; d <<= 1) {
        int o = (t >= d) ? s[t - d] : 0;
        __syncthreads();
        s[t] += o;
        __syncthreads();
    }
    if (t < nb) bsum[t] = s[t] - v;
}

__global__ void scan3_kernel(int* __restrict__ off, const int* __restrict__ bsum) {
    int b = blockIdx.x, t = threadIdx.x, g = b * 256 + t;
    if (g < N_NODES) off[g] += bsum[b];
    if (g == 0) off[N_NODES] = E_TOT;
}

// place_kernel: non-atomic placement using precomputed rank.
__global__ void place_kernel(const int* __restrict__ ei, const int* __restrict__ off,
                             const int* __restrict__ rank, int* __restrict__ ssrc) {
    int e = blockIdx.x * blockDim.x + threadIdx.x;
    if (e >= E_TOT) return;
    int s, d;
    if (e < N_EDGES) { s = ei[e]; d = ei[N_EDGES + e]; }
    else             { s = d = e - N_EDGES; }
    ssrc[off[d] + rank[e]] = s;
}

// ---------------- Aggregate layer 1: dual-edge wide gathers, 2-deep pipe ----
__global__ __launch_bounds__(256) void agg1_kernel(
    const int* __restrict__ off, const int* __restrict__ ssrc,
    const unsigned short* __restrict__ h1b, const float* __restrict__ as1,
    const float* __restrict__ ad1, const float* __restrict__ b1,
    unsigned short* __restrict__ houtb) {
    int t = threadIdx.x;
    int lane = t & 63;
    int n = blockIdx.x * 4 + (t >> 6);
    int h    = lane >> 3;     // weight-phase head
    int e8   = lane & 7;      // weight-phase edge slot
    int c    = lane & 31;     // channel group: ushorts [c*8, c*8+8)
    int hh   = c >> 2;        // head of my channel group
    int half = lane >> 5;     // 0: even edges, 1: odd edges
    int start = off[n], end = off[n + 1];
    int last = end - 1;
    float ad_w = ad1[n * HEADS + e8];
    float acc[8];
#pragma unroll
    for (int j = 0; j < 8; ++j) acc[j] = 0.f;
    float den = 0.f;
    int sv = ssrc[min(start + e8, last)];
    int se = __shfl(sv, h);
    float av = as1[se * HEADS + e8];
    const unsigned short* base = h1b + c * 8;
    uint4 g0 = *(const uint4*)&base[(unsigned)__shfl(sv, 0 + half) * 256];
    uint4 g1 = *(const uint4*)&base[(unsigned)__shfl(sv, 2 + half) * 256];
    uint4 g2 = *(const uint4*)&base[(unsigned)__shfl(sv, 4 + half) * 256];
    uint4 g3 = *(const uint4*)&base[(unsigned)__shfl(sv, 6 + half) * 256];
    for (int i = start; i < end; i += 8) {
        int inext = i + 8;
        int sv_n = ssrc[min(inext + e8, last)];
        int se_n = __shfl(sv_n, h);
        float av_n = as1[se_n * HEADS + e8];
        uint4 n0 = *(const uint4*)&base[(unsigned)__shfl(sv_n, 0 + half) * 256];
        uint4 n1 = *(const uint4*)&base[(unsigned)__shfl(sv_n, 2 + half) * 256];
        uint4 n2 = *(const uint4*)&base[(unsigned)__shfl(sv_n, 4 + half) * 256];
        uint4 n3 = *(const uint4*)&base[(unsigned)__shfl(sv_n, 6 + half) * 256];
        float wv = explrelu(av + ad_w);
        float w0 = __shfl(wv, (0 + half) * 8 + hh);
        float w1 = __shfl(wv, (2 + half) * 8 + hh);
        float w2 = __shfl(wv, (4 + half) * 8 + hh);
        float w3 = __shfl(wv, (6 + half) * 8 + hh);
        w0 = (i + 0 + half < end) ? w0 : 0.f;
        w1 = (i + 2 + half < end) ? w1 : 0.f;
        w2 = (i + 4 + half < end) ? w2 : 0.f;
        w3 = (i + 6 + half < end) ? w3 : 0.f;
        den += w0 + w1 + w2 + w3;
        acc[0] = fmaf(w0, bflo(g0.x), acc[0]); acc[1] = fmaf(w0, bfhi(g0.x), acc[1]);
        acc[2] = fmaf(w0, bflo(g0.y), acc[2]); acc[3] = fmaf(w0, bfhi(g0.y), acc[3]);
        acc[4] = fmaf(w0, bflo(g0.z), acc[4]); acc[5] = fmaf(w0, bfhi(g0.z), acc[5]);
        acc[6] = fmaf(w0, bflo(g0.w), acc[6]); acc[7] = fmaf(w0, bfhi(g0.w), acc[7]);
        acc[0] = fmaf(w1, bflo(g1.x), acc[0]); acc[1] = fmaf(w1, bfhi(g1.x), acc[1]);
        acc[2] = fmaf(w1, bflo(g1.y), acc[2]); acc[3] = fmaf(w1, bfhi(g1.y), acc[3]);
        acc[4] = fmaf(w1, bflo(g1.z), acc[4]); acc[5] = fmaf(w1, bfhi(g1.z), acc[5]);
        acc[6] = fmaf(w1, bflo(g1.w), acc[6]); acc[7] = fmaf(w1, bfhi(g1.w), acc[7]);
        acc[0] = fmaf(w2, bflo(g2.x), acc[0]); acc[1] = fmaf(w2, bfhi(g2.x), acc[1]);
        acc[2] = fmaf(w2, bflo(g2.y), acc[2]); acc[3] = fmaf(w2, bfhi(g2.y), acc[3]);
        acc[4] = fmaf(w2, bflo(g2.z), acc[4]); acc[5] = fmaf(w2, bfhi(g2.z), acc[5]);
        acc[6] = fmaf(w2, bflo(g2.w), acc[6]); acc[7] = fmaf(w2, bfhi(g2.w), acc[7]);
        acc[0] = fmaf(w3, bflo(g3.x), acc[0]); acc[1] = fmaf(w3, bfhi(g3.x), acc[1]);
        acc[2] = fmaf(w3, bflo(g3.y), acc[2]); acc[3] = fmaf(w3, bfhi(g3.y), acc[3]);
        acc[4] = fmaf(w3, bflo(g3.z), acc[4]); acc[5] = fmaf(w3, bfhi(g3.z), acc[5]);
        acc[6] = fmaf(w3, bflo(g3.w), acc[6]); acc[7] = fmaf(w3, bfhi(g3.w), acc[7]);
        g0 = n0; g1 = n1; g2 = n2; g3 = n3;
        sv = sv_n; av = av_n;
    }
#pragma unroll
    for (int j = 0; j < 8; ++j) acc[j] += __shfl_xor(acc[j], 32);
    den += __shfl_xor(den, 32);
    if (lane < 32) {
        float r = __builtin_amdgcn_rcpf(den);
        float4 b0 = *(const float4*)&b1[c * 8];
        float4 b4 = *(const float4*)&b1[c * 8 + 4];
        float v0 = fmaf(acc[0], r, b0.x);
        float v1 = fmaf(acc[1], r, b0.y);
        float v2 = fmaf(acc[2], r, b0.z);
        float v3 = fmaf(acc[3], r, b0.w);
        float v4 = fmaf(acc[4], r, b4.x);
        float v5 = fmaf(acc[5], r, b4.y);
        float v6 = fmaf(acc[6], r, b4.z);
        float v7 = fmaf(acc[7], r, b4.w);
        v0 = v0 > 0.f ? v0 : expm1f(v0);
        v1 = v1 > 0.f ? v1 : expm1f(v1);
        v2 = v2 > 0.f ? v2 : expm1f(v2);
        v3 = v3 > 0.f ? v3 : expm1f(v3);
        v4 = v4 > 0.f ? v4 : expm1f(v4);
        v5 = v5 > 0.f ? v5 : expm1f(v5);
        v6 = v6 > 0.f ? v6 : expm1f(v6);
        v7 = v7 > 0.f ? v7 : expm1f(v7);
        uint4 ob;
        ob.x = (unsigned)f2bf(v0) | ((unsigned)f2bf(v1) << 16);
        ob.y = (unsigned)f2bf(v2) | ((unsigned)f2bf(v3) << 16);
        ob.z = (unsigned)f2bf(v4) | ((unsigned)f2bf(v5) << 16);
        ob.w = (unsigned)f2bf(v6) | ((unsigned)f2bf(v7) << 16);
        *(uint4*)&houtb[(unsigned)n * 256 + c * 8] = ob;
    }
}

// ---------------- GEMM2 via MFMA (bf16 in, fp32 acc) + alpha epilogue -------
__global__ __launch_bounds__(256) void gemm2_mfma(
    const unsigned short* __restrict__ hinb, const unsigned short* __restrict__ W2t,
    const float* __restrict__ att_s2, const float* __restrict__ att_d2,
    unsigned short* __restrict__ h2b, float* __restrict__ as2, float* __restrict__ ad2) {
    int t = threadIdx.x;
    int lane = t & 63;
    int w = t >> 6;
    int lrow = lane & 15;
    int kg = lane >> 4;
    int row0 = blockIdx.x * 64 + w * 16;
    int gr = min(row0 + lrow, N_NODES - 1);    // clamp loads (last block partial)
    f32x4 acc0 = {0.f, 0.f, 0.f, 0.f};
    f32x4 acc1 = {0.f, 0.f, 0.f, 0.f};
    f32x4 acc2 = {0.f, 0.f, 0.f, 0.f};
    f32x4 acc3 = {0.f, 0.f, 0.f, 0.f};
#pragma unroll
    for (int ks = 0; ks < 8; ++ks) {
        int kb = ks * 32 + kg * 8;
        union { bf16x8 v; uint4 u; } A, B0, B1, B2, B3;
        A.u  = *(const uint4*)&hinb[(size_t)gr * 256 + kb];
        B0.u = *(const uint4*)&W2t[(size_t)(0 * 16 + lrow) * 256 + kb];
        B1.u = *(const uint4*)&W2t[(size_t)(1 * 16 + lrow) * 256 + kb];
        B2.u = *(const uint4*)&W2t[(size_t)(2 * 16 + lrow) * 256 + kb];
        B3.u = *(const uint4*)&W2t[(size_t)(3 * 16 + lrow) * 256 + kb];
        acc0 = __builtin_amdgcn_mfma_f32_16x16x32_bf16(A.v, B0.v, acc0, 0, 0, 0);
        acc1 = __builtin_amdgcn_mfma_f32_16x16x32_bf16(A.v, B1.v, acc1, 0, 0, 0);
        acc2 = __builtin_amdgcn_mfma_f32_16x16x32_bf16(A.v, B2.v, acc2, 0, 0, 0);
        acc3 = __builtin_amdgcn_mfma_f32_16x16x32_bf16(A.v, B3.v, acc3, 0, 0, 0);
    }
    float s0 = att_s2[ 0 + lrow], d0 = att_d2[ 0 + lrow];
    float s1 = att_s2[16 + lrow], d1 = att_d2[16 + lrow];
    float s2 = att_s2[32 + lrow], d2 = att_d2[32 + lrow];
    float s3 = att_s2[48 + lrow], d3 = att_d2[48 + lrow];
#pragma unroll
    for (int r = 0; r < 4; ++r) {
        int orow = row0 + kg * 4 + r;
        float p = acc0[r] * s0 + acc1[r] * s1 + acc2[r] * s2 + acc3[r] * s3;
        float q = acc0[r] * d0 + acc1[r] * d1 + acc2[r] * d2 + acc3[r] * d3;
        p += __shfl_xor(p, 1); q += __shfl_xor(q, 1);
        p += __shfl_xor(p, 2); q += __shfl_xor(q, 2);
        p += __shfl_xor(p, 4); q += __shfl_xor(q, 4);
        p += __shfl_xor(p, 8); q += __shfl_xor(q, 8);
        if (orow < N_NODES) {
            h2b[(size_t)orow * 64 +  0 + lrow] = f2bf(acc0[r]);
            h2b[(size_t)orow * 64 + 16 + lrow] = f2bf(acc1[r]);
            h2b[(size_t)orow * 64 + 32 + lrow] = f2bf(acc2[r]);
            h2b[(size_t)orow * 64 + 48 + lrow] = f2bf(acc3[r]);
            if (lrow == 0) { as2[orow] = p; ad2[orow] = q; }
        }
    }
}

// ---------------- Aggregate layer 2: quad-edge wide gathers -----------------
__global__ __launch_bounds__(256) void agg2_kernel(
    const int* __restrict__ off, const int* __restrict__ ssrc,
    const unsigned short* __restrict__ h2b, const float* __restrict__ as2,
    const float* __restrict__ ad2, const float* __restrict__ b2,
    float* __restrict__ out) {
    int t = threadIdx.x;
    int lane = t & 63;
    int e8 = lane & 7;
    int q = lane & 15;
    int quarter = lane >> 4;
    int n = blockIdx.x * 4 + (t >> 6);
    int start = off[n], end = off[n + 1];
    int last = end - 1;
    float adv = ad2[n];
    float acc[4];
#pragma unroll
    for (int j = 0; j < 4; ++j) acc[j] = 0.f;
    float den = 0.f;
    int sv = ssrc[min(start + e8, last)];
    float av = as2[sv];
    for (int i = start; i < end; i += 8) {
        int inext = i + 8;
        int sv_n = ssrc[min(inext + e8, last)];
        float av_n = as2[sv_n];
        float wv = explrelu(av + adv);
#pragma unroll
        for (int k = 0; k < 2; ++k) {
            int me = 4 * k + quarter;
            float wj = __shfl(wv, me);
            int   sj = __shfl(sv, me);
            wj = (i + me < end) ? wj : 0.f;
            uint2 u = *(const uint2*)&h2b[(unsigned)sj * 64 + q * 4];
            den += wj;
            acc[0] = fmaf(wj, bflo(u.x), acc[0]);
            acc[1] = fmaf(wj, bfhi(u.x), acc[1]);
            acc[2] = fmaf(wj, bflo(u.y), acc[2]);
            acc[3] = fmaf(wj, bfhi(u.y), acc[3]);
        }
        sv = sv_n; av = av_n;
    }
#pragma unroll
    for (int j = 0; j < 4; ++j) {
        acc[j] += __shfl_xor(acc[j], 16);
        acc[j] += __shfl_xor(acc[j], 32);
    }
    den += __shfl_xor(den, 16);
    den += __shfl_xor(den, 32);
    if (lane < 16) {
        float r = __builtin_amdgcn_rcpf(den);
        float4 bv = *(const float4*)&b2[q * 4];
        float4 o;
        o.x = fmaf(acc[0], r, bv.x);
        o.y = fmaf(acc[1], r, bv.y);
        o.z = fmaf(acc[2], r, bv.z);
        o.w = fmaf(acc[3], r, bv.w);
        *(float4*)&out[(unsigned)n * 64 + q * 4] = o;
    }
}

extern "C" void kernel_launch(void* const* d_in, const int* in_sizes, int n_in,
                              void* d_out, int out_size, void* d_ws, size_t ws_size,
                              hipStream_t stream) {
    const float* x    = (const float*)d_in[0];
    const int*   ei   = (const int*)d_in[1];
    const float* W1   = (const float*)d_in[2];
    const float* ats1 = (const float*)d_in[3];
    const float* atd1 = (const float*)d_in[4];
    const float* b1   = (const float*)d_in[5];
    const float* W2   = (const float*)d_in[6];
    const float* ats2 = (const float*)d_in[7];
    const float* atd2 = (const float*)d_in[8];
    const float* b2   = (const float*)d_in[9];
    float* out = (float*)d_out;

    char* ws = (char*)d_ws;
    size_t o = 0;
    auto alloc = [&](size_t bytes) { size_t r = o; o = (o + bytes + 255) & ~255UL; return r; };
    unsigned short* h1b   = (unsigned short*)(ws + alloc((size_t)N_NODES * 256 * 2));
    unsigned short* h2inb = (unsigned short*)(ws + alloc((size_t)N_NODES * 256 * 2));
    unsigned short* h2b   = (unsigned short*)(ws + alloc((size_t)N_NODES * 64 * 2));
    unsigned short* W1t   = (unsigned short*)(ws + alloc((size_t)256 * 128 * 2));
    unsigned short* W2t   = (unsigned short*)(ws + alloc((size_t)64 * 256 * 2));
    float* as1  = (float*)(ws + alloc((size_t)N_NODES * HEADS * 4));
    float* ad1  = (float*)(ws + alloc((size_t)N_NODES * HEADS * 4));
    float* as2  = (float*)(ws + alloc((size_t)N_NODES * 4));
    float* ad2  = (float*)(ws + alloc((size_t)N_NODES * 4));
    int*   deg2 = (int*)(ws + alloc((size_t)N_NODES * 16 * 4));   // 64B/counter
    int*   off  = (int*)(ws + alloc((size_t)(N_NODES + 1) * 4));
    int*   bsum = (int*)(ws + alloc(256 * 4));
    int*   rank = (int*)(ws + alloc((size_t)E_TOT * 4));
    int*   ssrc = (int*)(ws + alloc((size_t)E_TOT * 4));

    (void)hipMemsetAsync(deg2, 0, (size_t)N_NODES * 16 * 4, stream);
    int eblk = (E_TOT + 255) / 256;

    w1cast_kernel<<<128, 256, 0, stream>>>(W1, W1t);
    fused1_kernel<<<RBLK + G1BLK + 64, 256, 0, stream>>>(
        ei, deg2, rank, x, W1t, ats1, atd1, h1b, as1, ad1, W2, W2t);
    scan1_kernel<<<NBLK, 256, 0, stream>>>(deg2, off, bsum);
    scan2_kernel<<<1, 256, 0, stream>>>(bsum, NBLK);
    scan3_kernel<<<NBLK, 256, 0, stream>>>(off, bsum);
    place_kernel<<<eblk, 256, 0, stream>>>(ei, off, rank, ssrc);

    agg1_kernel<<<ABLK, 256, 0, stream>>>(off, ssrc, h1b, as1, ad1, b1, h2inb);

    gemm2_mfma<<<G2BLK, 256, 0, stream>>>(h2inb, W2t, ats2, atd2, h2b, as2, ad2);
    agg2_kernel<<<ABLK, 256, 0, stream>>>(off, ssrc, h2b, as2, ad2, b2, out);
}